// Round 17
// baseline (242.412 us; speedup 1.0000x reference)
//
#include <hip/hip_runtime.h>

// ---------------------------------------------------------------------------
// TransformerBlock: LN1 -> QKV proj (fused) -> reversed-causal attention
// (scale 1/sqrt(D)=1/32) -> residual -> LN2 -> GELU FFN -> residual.
// B=2 S=2048 D=1024 H=16 HD=64 R=32 F=4096. All d_in/d_out fp32; internal
// compute bf16 MFMA.
// R16: gemm4 — FFN kernels moved to the 2-blocks/CU regime: 128x128 tile,
// BK=64, 4 waves (2x2 of 64x64), 2 slots x 32KB = 64KB LDS (2 resident
// blocks/CU -> cross-block stage/compute overlap, the m114 mechanism that
// makes gemm_nt fast). R7 schedule, (row&7)<<4 swizzle, T1 block swizzle —
// all verified components, only the block geometry changed.
// ---------------------------------------------------------------------------

typedef unsigned short u16;
typedef __attribute__((ext_vector_type(4))) float f32x4;
typedef __attribute__((ext_vector_type(8))) __bf16 bf16x8;

#define B_ 2
#define S_ 2048
#define D_ 1024
#define H_ 16
#define HD_ 64
#define R_ 32
#define F_ 4096
#define M_ (B_ * S_)   // 4096 rows
#define NQKV 2560      // 1024 q + 1024 k + 512 vd
// (1/sqrt(D)) * log2(e): folded into Wq/bq so QK^T scores are exp2-ready
#define C2F 0.04508422002778011f

__device__ __forceinline__ u16 f2bf(float f) {
  union { float f; unsigned u; } v; v.f = f;
  unsigned u = v.u;
  return (u16)((u + 0x7FFFu + ((u >> 16) & 1u)) >> 16);  // RNE
}
__device__ __forceinline__ float bf2f(u16 h) {
  union { unsigned u; float f; } v; v.u = ((unsigned)h) << 16;
  return v.f;
}
__device__ __forceinline__ unsigned pk_bf16(float lo, float hi) {
  unsigned r;
  asm volatile("v_cvt_pk_bf16_f32 %0, %1, %2" : "=v"(r) : "v"(lo), "v"(hi));
  return r;
}

typedef __attribute__((address_space(1))) void gvoid;
typedef __attribute__((address_space(3))) void lvoid;
// async global->LDS, 16B/lane; lds base must be wave-uniform (lane*16 implicit)
__device__ __forceinline__ void gload_lds16(const void* g, void* l) {
  __builtin_amdgcn_global_load_lds((gvoid*)(void*)g, (lvoid*)l, 16, 0, 0);
}

__device__ __forceinline__ float gelu_f(float x) {
  float t = tanhf(0.7978845608028654f * (x + 0.044715f * x * x * x));
  return 0.5f * x * (1.0f + t);
}

// ---- fp32 [Rr,Cc] (batched) -> bf16 transposed [Cc,Rr], optional scale ----
__global__ __launch_bounds__(256) void wtrans(const float* __restrict__ in,
                                              u16* __restrict__ out,
                                              int Rr, int Cc, long ibs, long obs,
                                              float scale) {
  __shared__ float tile[32][33];
  const float* ip = in + (size_t)blockIdx.z * ibs;
  u16* op = out + (size_t)blockIdx.z * obs;
  int c0 = blockIdx.x * 32, r0 = blockIdx.y * 32;
  int tx = threadIdx.x & 31, ty = threadIdx.x >> 5;  // 32 x 8
#pragma unroll
  for (int j = 0; j < 32; j += 8)
    tile[ty + j][tx] = ip[(size_t)(r0 + ty + j) * Cc + c0 + tx];
  __syncthreads();
#pragma unroll
  for (int j = 0; j < 32; j += 8)
    op[(size_t)(c0 + ty + j) * Rr + r0 + tx] = f2bf(tile[tx][ty + j] * scale);
}

// ---- flat fp32 -> bf16 -----------------------------------------------------
__global__ __launch_bounds__(256) void wconv(const float* __restrict__ in,
                                             u16* __restrict__ out, int n) {
  int i = (blockIdx.x * 256 + threadIdx.x) * 4;
  if (i < n) {
    float4 v = *(const float4*)&in[i];
    ushort4 o;
    o.x = f2bf(v.x); o.y = f2bf(v.y); o.z = f2bf(v.z); o.w = f2bf(v.w);
    *(ushort4*)&out[i] = o;
  }
}

// ---- concat biases: [bq*C2F | bk | bvd] -> bqkv[2560] ----------------------
__global__ __launch_bounds__(256) void bconcat(const float* __restrict__ bq,
                                               const float* __restrict__ bk,
                                               const float* __restrict__ bvd,
                                               float* __restrict__ o) {
  int i = blockIdx.x * 256 + threadIdx.x;
  if (i < NQKV) {
    float v = (i < 1024) ? bq[i] * C2F : (i < 2048 ? bk[i - 1024] : bvd[i - 2048]);
    o[i] = v;
  }
}

// ---- LayerNorm (optionally fused residual add + x2 passthrough) -----------
__global__ __launch_bounds__(256) void ln_kernel(const float* __restrict__ xin,
                                                 const float* __restrict__ addin,
                                                 const float* __restrict__ gam,
                                                 const float* __restrict__ bet,
                                                 u16* __restrict__ hout,
                                                 float* __restrict__ x2out) {
  int row = blockIdx.x, tid = threadIdx.x;
  size_t base = (size_t)row * D_ + tid * 4;
  float4 v = *(const float4*)&xin[base];
  if (addin) {
    float4 a = *(const float4*)&addin[base];
    v.x += a.x; v.y += a.y; v.z += a.z; v.w += a.w;
  }
  if (x2out) *(float4*)&x2out[base] = v;
  float s = v.x + v.y + v.z + v.w;
  float ss = v.x * v.x + v.y * v.y + v.z * v.z + v.w * v.w;
#pragma unroll
  for (int off = 32; off > 0; off >>= 1) {
    s += __shfl_down(s, off);
    ss += __shfl_down(ss, off);
  }
  __shared__ float red[8];
  int wv = tid >> 6;
  if ((tid & 63) == 0) { red[wv] = s; red[4 + wv] = ss; }
  __syncthreads();
  if (tid == 0) {
    float s1 = red[0] + red[1] + red[2] + red[3];
    float s2 = red[4] + red[5] + red[6] + red[7];
    float mu = s1 * (1.0f / D_);
    red[0] = mu;
    red[1] = s2 * (1.0f / D_) - mu * mu;
  }
  __syncthreads();
  float mu = red[0];
  float rstd = rsqrtf(red[1] + 1e-5f);
  int ci = tid * 4;
  ushort4 o;
  o.x = f2bf((v.x - mu) * rstd * gam[ci + 0] + bet[ci + 0]);
  o.y = f2bf((v.y - mu) * rstd * gam[ci + 1] + bet[ci + 1]);
  o.z = f2bf((v.z - mu) * rstd * gam[ci + 2] + bet[ci + 2]);
  o.w = f2bf((v.w - mu) * rstd * gam[ci + 3] + bet[ci + 3]);
  *(ushort4*)&hout[base] = o;
}

// ---- NT GEMM (128x128, 2-phase dbuf): used for the fused QKV projection ---
// T1: XCD-aware block swizzle (nwg = 20*32 = 640, %8==0 -> bijective).
template <int MODE>
__global__ __launch_bounds__(256) void gemm_nt(const u16* __restrict__ A,
                                               const u16* __restrict__ Bt,
                                               int K, int lda, int ldb,
                                               const float* __restrict__ bias,
                                               const float* __restrict__ res,
                                               void* __restrict__ Cout,
                                               void* __restrict__ Cout2, int ldc) {
  __shared__ __align__(16) u16 As0[128 * 32];
  __shared__ __align__(16) u16 Bs0[128 * 32];
  __shared__ __align__(16) u16 As1[128 * 32];
  __shared__ __align__(16) u16 Bs1[128 * 32];
  int tid = threadIdx.x;
  int lane = tid & 63, wid = tid >> 6;
  int wm = wid >> 1, wn = wid & 1;
  int bid = blockIdx.x + gridDim.x * blockIdx.y;
  int nwg = gridDim.x * gridDim.y;
  int swz = (bid & 7) * (nwg >> 3) + (bid >> 3);
  int tbx = swz % gridDim.x, tby = swz / gridDim.x;
  int row0 = tby * 128, col0 = tbx * 128;
  int l15 = lane & 15, g = lane >> 4;
  int srow = lane >> 2, scol = (lane & 3) * 8;
  f32x4 acc[4][4] = {};
  const u16* Ap = A + (size_t)row0 * lda;
  const u16* Bp = Bt + (size_t)col0 * ldb;

  auto STAGE = [&](u16* AS, u16* BS, int kk) {
#pragma unroll
    for (int i = 0; i < 2; ++i) {
      int c = wid * 2 + i;
      gload_lds16(Ap + (size_t)(c * 16 + srow) * lda + kk + scol, &AS[c * 512]);
      gload_lds16(Bp + (size_t)(c * 16 + srow) * ldb + kk + scol, &BS[c * 512]);
    }
  };
  auto COMPUTE = [&](const u16* AS, const u16* BS) {
    bf16x8 af[4], bfr[4];
#pragma unroll
    for (int t = 0; t < 4; ++t) {
      af[t] = *(const bf16x8*)&AS[(wm * 64 + t * 16 + l15) * 32 + g * 8];
      bfr[t] = *(const bf16x8*)&BS[(wn * 64 + t * 16 + l15) * 32 + g * 8];
    }
#pragma unroll
    for (int mt = 0; mt < 4; ++mt)
#pragma unroll
      for (int nt = 0; nt < 4; ++nt)
        acc[mt][nt] = __builtin_amdgcn_mfma_f32_16x16x32_bf16(af[mt], bfr[nt],
                                                              acc[mt][nt], 0, 0, 0);
  };

  STAGE(As0, Bs0, 0);
  __syncthreads();
  for (int k0 = 0; k0 < K; k0 += 64) {
    if (k0 + 32 < K) STAGE(As1, Bs1, k0 + 32);
    COMPUTE(As0, Bs0);
    __syncthreads();
    if (k0 + 64 < K) STAGE(As0, Bs0, k0 + 64);
    COMPUTE(As1, Bs1);
    __syncthreads();
  }

#pragma unroll
  for (int mt = 0; mt < 4; ++mt) {
#pragma unroll
    for (int nt = 0; nt < 4; ++nt) {
      int cc = col0 + wn * 64 + nt * 16 + l15;
      float bv = bias ? bias[cc] : 0.0f;
#pragma unroll
      for (int j = 0; j < 4; ++j) {
        int rr = row0 + wm * 64 + mt * 16 + g * 4 + j;
        float v = acc[mt][nt][j] + bv;
        if (MODE == 1) v = gelu_f(v);
        if (MODE == 2) {
          ((float*)Cout)[(size_t)rr * ldc + cc] = v + res[(size_t)rr * ldc + cc];
        } else {
          ((u16*)Cout)[(size_t)rr * ldc + cc] = f2bf(v);
        }
      }
    }
  }
  (void)Cout2;
}

// ---- gemm4: 128x128, BK=64, 4 waves, 2 slots x 32KB LDS (2 blocks/CU) ------
// R7 schedule: per K-tile {ds_read kk0 | STAGE_A(next) | 32 MFMA |
// ds_read kk1 | STAGE_B(next) | 32 MFMA | vmcnt(0) | s_barrier}.
// Swizzle (row&7)<<4 both sides (128B rows, same algebra as gemm8,
// conflicts measured 0). T1 XCD swizzle per z-slice (nwg%8==0).
// MODE 1: bf16 gelu(v+bias) -> Cb. MODE 4: split-K, z=0 -> f32 RAW v to Cf;
// z=1..3 -> bf16 raw to P1/P2/P3 (bias/res applied in reduce2).
template <int MODE>
__global__ __launch_bounds__(256, 2) void gemm4(
    const u16* __restrict__ A, const u16* __restrict__ Bt,
    int lda, int ldb, int nk,
    const float* __restrict__ bias,
    float* __restrict__ Cf, u16* __restrict__ Cb,
    u16* __restrict__ P1, u16* __restrict__ P2, u16* __restrict__ P3,
    int ldc) {
  extern __shared__ __align__(16) char smem[];
  int tid = threadIdx.x;
  int lane = tid & 63, wid = tid >> 6;        // 4 waves
  int wm = wid >> 1, wn = wid & 1;            // 2x2 of 64x64
  int l15 = lane & 15, g = lane >> 4;
  int bid = blockIdx.x + gridDim.x * blockIdx.y;
  int nwg = gridDim.x * gridDim.y;
  int swz = (bid & 7) * (nwg >> 3) + (bid >> 3);
  int tbx = swz % gridDim.x, tby = swz / gridDim.x;
  int row0 = tby * 128, col0 = tbx * 128;
  int koff = (MODE == 4) ? blockIdx.z * (nk * 64) : 0;
  const u16* Ap = A + (size_t)row0 * lda + koff;
  const u16* Bp = Bt + (size_t)col0 * ldb + koff;
  int srow8 = lane >> 3;                               // 0..7 (row within 8)
  int sbyte = ((lane & 7) * 16) ^ ((srow8 & 7) << 4);  // pre-swizzled src byte
  int xr = (l15 & 7) << 4;                             // read-side XOR

  f32x4 acc[4][4] = {};

  // slot layout: slot*32768 | A[128][64] 16KB | B[128][64] 16KB
  // wave w's load l covers rows l*32 + w*8 .. +7 (8 rows x 128B = 1KB)
  auto STAGE_A = [&](int buf, int kt) {
#pragma unroll
    for (int l = 0; l < 4; ++l)
      gload_lds16((const char*)(Ap + (size_t)(l * 32 + wid * 8 + srow8) * lda + kt) + sbyte,
                  smem + buf * 32768 + (l * 32 + wid * 8) * 128);
  };
  auto STAGE_B = [&](int buf, int kt) {
#pragma unroll
    for (int l = 0; l < 4; ++l)
      gload_lds16((const char*)(Bp + (size_t)(l * 32 + wid * 8 + srow8) * ldb + kt) + sbyte,
                  smem + buf * 32768 + 16384 + (l * 32 + wid * 8) * 128);
  };

  STAGE_A(0, 0);
  STAGE_B(0, 0);
  asm volatile("s_waitcnt vmcnt(0)" ::: "memory");
  __builtin_amdgcn_sched_barrier(0);
  __builtin_amdgcn_s_barrier();

  int cur = 0;
  for (int it = 0; it < nk; ++it) {
    const char* Ab = smem + cur * 32768 + (size_t)(wm * 64 + l15) * 128;
    const char* Bb = smem + cur * 32768 + 16384 + (size_t)(wn * 64 + l15) * 128;
    bool nxt = (it + 1 < nk);
#pragma unroll
    for (int kk = 0; kk < 2; ++kk) {
      int kq = (kk * 64 + g * 16) ^ xr;
      bf16x8 af[4], bfr[4];
#pragma unroll
      for (int nt = 0; nt < 4; ++nt)
        bfr[nt] = *(const bf16x8*)(Bb + nt * 2048 + kq);
#pragma unroll
      for (int mt = 0; mt < 4; ++mt)
        af[mt] = *(const bf16x8*)(Ab + mt * 2048 + kq);
      if (nxt) {
        if (kk == 0) STAGE_A(cur ^ 1, (it + 1) * 64);
        else         STAGE_B(cur ^ 1, (it + 1) * 64);
      }
      __builtin_amdgcn_s_setprio(1);
#pragma unroll
      for (int mt = 0; mt < 4; ++mt)
#pragma unroll
        for (int nt = 0; nt < 4; ++nt)
          acc[mt][nt] = __builtin_amdgcn_mfma_f32_16x16x32_bf16(af[mt], bfr[nt],
                                                                acc[mt][nt], 0, 0, 0);
      __builtin_amdgcn_s_setprio(0);
    }
    asm volatile("s_waitcnt vmcnt(0)" ::: "memory");
    __builtin_amdgcn_sched_barrier(0);
    __builtin_amdgcn_s_barrier();
    cur ^= 1;
  }

  // epilogue: C/D layout col=lane&15, row=(lane>>4)*4+j
  u16* pp = (u16*)nullptr;
  if (MODE == 4 && blockIdx.z != 0)
    pp = (blockIdx.z == 1) ? P1 : (blockIdx.z == 2 ? P2 : P3);
#pragma unroll
  for (int mt = 0; mt < 4; ++mt) {
#pragma unroll
    for (int nt = 0; nt < 4; ++nt) {
      int cc = col0 + wn * 64 + nt * 16 + l15;
      float bv = (MODE == 1) ? bias[cc] : 0.0f;
#pragma unroll
      for (int j = 0; j < 4; ++j) {
        int rr = row0 + wm * 64 + mt * 16 + g * 4 + j;
        float v = acc[mt][nt][j] + bv;
        if (MODE == 1) {
          Cb[(size_t)rr * ldc + cc] = f2bf(gelu_f(v));
        } else {
          if (blockIdx.z == 0) Cf[(size_t)rr * ldc + cc] = v;
          else                 pp[(size_t)rr * ldc + cc] = f2bf(v);
        }
      }
    }
  }
}

// ---- split-K reduce: out += p1+p2+p3 (bf16) + b2[col] + x2 -----------------
__global__ __launch_bounds__(256) void reduce2(float* __restrict__ out,
                                               const u16* __restrict__ p1,
                                               const u16* __restrict__ p2,
                                               const u16* __restrict__ p3,
                                               const float* __restrict__ b2,
                                               const float* __restrict__ x2) {
  int i = (blockIdx.x * 256 + threadIdx.x) * 4;
  float4 o = *(float4*)&out[i];
  ushort4 a = *(const ushort4*)&p1[i];
  ushort4 b = *(const ushort4*)&p2[i];
  ushort4 c = *(const ushort4*)&p3[i];
  float4 r = *(const float4*)&x2[i];
  int cix = i & (D_ - 1);
  o.x += bf2f(a.x) + bf2f(b.x) + bf2f(c.x) + b2[cix + 0] + r.x;
  o.y += bf2f(a.y) + bf2f(b.y) + bf2f(c.y) + b2[cix + 1] + r.y;
  o.z += bf2f(a.z) + bf2f(b.z) + bf2f(c.z) + b2[cix + 2] + r.z;
  o.w += bf2f(a.w) + bf2f(b.w) + bf2f(c.w) + b2[cix + 3] + r.w;
  *(float4*)&out[i] = o;
}

// ---- low-rank V up-proj -> V^T [b,h][e][t] bf16 ----------------------------
__global__ __launch_bounds__(256) void vu_kernel(const u16* __restrict__ vd,
                                                 const u16* __restrict__ wvu,
                                                 const float* __restrict__ bvu,
                                                 u16* __restrict__ v_t) {
  int t0 = blockIdx.x * 64, h = blockIdx.y, b = blockIdx.z;
  __shared__ u16 vds[64][32];
  __shared__ u16 vt[64][65];
  int tid = threadIdx.x;
  {
    int rr2 = tid >> 2, c8 = (tid & 3) * 8;
    *(bf16x8*)&vds[rr2][c8] =
        *(const bf16x8*)&vd[(size_t)(b * S_ + t0 + rr2) * NQKV + 2048 + h * R_ + c8];
  }
  __syncthreads();
  int e = tid & 63, tg = (tid >> 6) * 16;
  float wcol[32];
#pragma unroll
  for (int r = 0; r < 32; ++r) wcol[r] = bf2f(wvu[((size_t)h * R_ + r) * HD_ + e]);
  float bb = bvu[h * HD_ + e];
  for (int i = 0; i < 16; ++i) {
    int t = tg + i;
    float acc = bb;
#pragma unroll
    for (int r = 0; r < 32; ++r) acc += bf2f(vds[t][r]) * wcol[r];
    vt[t][e] = f2bf(acc);
  }
  __syncthreads();
  for (int idx = tid; idx < 64 * 64; idx += 256) {
    int e2 = idx >> 6, t2 = idx & 63;
    v_t[((size_t)(b * H_ + h) * HD_ + e2) * S_ + t0 + t2] = vt[t2][e2];
  }
}

// ---- attention v4 (R11-verified): reversed-causal (key t >= query s) -------
// grid (H, B, 8). 8 waves, QBLK=128 triangle-paired (uniform 34 steps).
// Counted-vmcnt 3-buffer ring: one s_barrier + vmcnt(2) per step (vmcnt(0)
// last), STAGE(it+2) after the barrier.
__global__ __launch_bounds__(512, 2) void attn_kernel(const u16* __restrict__ cqkv,
                                                      const u16* __restrict__ v_t,
                                                      float* __restrict__ o) {
  extern __shared__ __align__(16) u16 kv[];  // 3 bufs x (K 4096 + V 4096) u16
  __shared__ u16 Pl[8][16 * 64];             // per-wave Q then P^T tile
  int tid = threadIdx.x;
  int lane = tid & 63, w = tid >> 6;
  int h = blockIdx.x, b = blockIdx.y;
  int bx = blockIdx.z;
  int r = lane & 15, g = lane >> 4;
  const u16* qp = cqkv + (size_t)(b * S_) * NQKV + h * HD_;
  const u16* kp = cqkv + (size_t)(b * S_) * NQKV + 1024 + h * HD_;
  const u16* vp = v_t + (size_t)(b * H_ + h) * HD_ * S_;
  u16* Pw = Pl[w];

  int srow = w * 8 + (lane >> 3);
  int ssw = ((lane & 7) * 16) ^ (((lane >> 3) & 7) << 4);  // pre-swz byte in row

  int xr = (r & 7) << 4;                // read-side XOR (rows = ..*16 + r)
  int kq0 = ((g * 16) ^ xr) >> 1;       // elem offset, k-group 0
  int kq1 = ((64 + g * 16) ^ xr) >> 1;  // elem offset, k-group 1

  auto STAGE = [&](int buf, int kt) {
    u16* base = kv + buf * 8192;
    gload_lds16((const char*)(kp + (size_t)(kt + srow) * NQKV) + ssw,
                base + w * 512);
    gload_lds16((const char*)(vp + (size_t)srow * S_ + kt) + ssw,
                base + 4096 + w * 512);
  };

#pragma unroll 1
  for (int half = 0; half < 2; ++half) {
    int qb = half ? (S_ - 128) - bx * 128 : bx * 128;
    int s0 = qb + w * 16;
    int qrow = s0 + r;

    gload_lds16((const char*)(qp + (size_t)(s0 + (lane >> 3)) * NQKV) + ssw, Pw);
    gload_lds16((const char*)(qp + (size_t)(s0 + 8 + (lane >> 3)) * NQKV) + ssw,
                Pw + 512);
    asm volatile("s_waitcnt vmcnt(0)" ::: "memory");
    __builtin_amdgcn_sched_barrier(0);
    __builtin_amdgcn_s_barrier();
    __builtin_amdgcn_sched_barrier(0);
    bf16x8 aq0 = *(const bf16x8*)&Pw[(r << 6) + kq0];
    bf16x8 aq1 = *(const bf16x8*)&Pw[(r << 6) + kq1];

    f32x4 oa[4] = {};
    float m_ = -1e30f, l_ = 0.0f;

    int nt = (S_ - qb) >> 6;
    STAGE(0, qb);
    STAGE(1, qb + 64);

    for (int it = 0; it < nt; ++it) {
      int kt = qb + it * 64;
      if (it + 1 < nt) {
        asm volatile("s_waitcnt vmcnt(2)" ::: "memory");
      } else {
        asm volatile("s_waitcnt vmcnt(0)" ::: "memory");
      }
      __builtin_amdgcn_sched_barrier(0);
      __builtin_amdgcn_s_barrier();
      __builtin_amdgcn_sched_barrier(0);
      if (it + 2 < nt) STAGE((it + 2) % 3, qb + (it + 2) * 64);

      if (kt + 64 > s0) {
        const u16* Kb = kv + (it % 3) * 8192;
        const u16* Vb = Kb + 4096;

        f32x4 sc[4] = {};
#pragma unroll
        for (int blk = 0; blk < 4; ++blk) {
          bf16x8 a0 = *(const bf16x8*)&Kb[((blk * 16 + r) << 6) + kq0];
          bf16x8 a1 = *(const bf16x8*)&Kb[((blk * 16 + r) << 6) + kq1];
          sc[blk] = __builtin_amdgcn_mfma_f32_16x16x32_bf16(a0, aq0, sc[blk], 0, 0, 0);
          sc[blk] = __builtin_amdgcn_mfma_f32_16x16x32_bf16(a1, aq1, sc[blk], 0, 0, 0);
        }

        float p[16];
        if ((qrow & ~63) == kt) {
#pragma unroll
          for (int blk = 0; blk < 4; ++blk)
#pragma unroll
            for (int j = 0; j < 4; ++j) {
              int kk = kt + blk * 16 + g * 4 + j;
              p[blk * 4 + j] = (kk < qrow) ? -1e30f : sc[blk][j];
            }
        } else {
#pragma unroll
          for (int blk = 0; blk < 4; ++blk)
#pragma unroll
            for (int j = 0; j < 4; ++j) p[blk * 4 + j] = sc[blk][j];
        }
        float mx = p[0];
#pragma unroll
        for (int i = 1; i < 16; ++i) mx = fmaxf(mx, p[i]);
        mx = fmaxf(mx, __shfl_xor(mx, 16));
        mx = fmaxf(mx, __shfl_xor(mx, 32));
        float mn = fmaxf(m_, mx);
        float scl = __builtin_amdgcn_exp2f(m_ - mn);
        m_ = mn;
        float sm = 0.0f;
#pragma unroll
        for (int i = 0; i < 16; ++i) {
          p[i] = __builtin_amdgcn_exp2f(p[i] - mn);
          sm += p[i];
        }
        sm += __shfl_xor(sm, 16);
        sm += __shfl_xor(sm, 32);
        l_ = l_ * scl + sm;
#pragma unroll
        for (int et = 0; et < 4; ++et) oa[et] *= scl;

#pragma unroll
        for (int blk = 0; blk < 4; ++blk) {
          uint2 pk;
          pk.x = pk_bf16(p[blk * 4 + 0], p[blk * 4 + 1]);
          pk.y = pk_bf16(p[blk * 4 + 2], p[blk * 4 + 3]);
          *(uint2*)&Pw[(r << 6) + ((((blk << 5) + (g << 3)) ^ xr) >> 1)] = pk;
        }
        asm volatile("s_waitcnt lgkmcnt(0)" ::: "memory");
        __builtin_amdgcn_sched_barrier(0);
        bf16x8 pb0 = *(const bf16x8*)&Pw[(r << 6) + kq0];
        bf16x8 pb1 = *(const bf16x8*)&Pw[(r << 6) + kq1];
#pragma unroll
        for (int et = 0; et < 4; ++et) {
          bf16x8 v0 = *(const bf16x8*)&Vb[((et * 16 + r) << 6) + kq0];
          bf16x8 v1 = *(const bf16x8*)&Vb[((et * 16 + r) << 6) + kq1];
          oa[et] = __builtin_amdgcn_mfma_f32_16x16x32_bf16(v0, pb0, oa[et], 0, 0, 0);
          oa[et] = __builtin_amdgcn_mfma_f32_16x16x32_bf16(v1, pb1, oa[et], 0, 0, 0);
        }
      }
    }

    float inv = 1.0f / l_;
#pragma unroll
    for (int et = 0; et < 4; ++et)
#pragma unroll
      for (int j = 0; j < 4; ++j)
        o[(size_t)(b * S_ + s0 + r) * D_ + h * HD_ + et * 16 + g * 4 + j] =
            oa[et][j] * inv;
  }
}

// one-time (dlopen) LDS-limit raise for dynamic-shared kernels
namespace {
struct GemmAttrInit {
  GemmAttrInit() {
    hipFuncSetAttribute((const void*)gemm4<1>,
                        hipFuncAttributeMaxDynamicSharedMemorySize, 65536);
    hipFuncSetAttribute((const void*)gemm4<4>,
                        hipFuncAttributeMaxDynamicSharedMemorySize, 65536);
    hipFuncSetAttribute((const void*)attn_kernel,
                        hipFuncAttributeMaxDynamicSharedMemorySize, 49152);
  }
};
GemmAttrInit _gemm_attr_init;
}  // namespace

extern "C" void kernel_launch(void* const* d_in, const int* in_sizes, int n_in,
                              void* d_out, int out_size, void* d_ws, size_t ws_size,
                              hipStream_t stream) {
  const float* x = (const float*)d_in[0];
  const float* ln1_g = (const float*)d_in[1];
  const float* ln1_b = (const float*)d_in[2];
  const float* Wq = (const float*)d_in[3];
  const float* bq = (const float*)d_in[4];
  const float* Wk = (const float*)d_in[5];
  const float* bk = (const float*)d_in[6];
  const float* Wvd = (const float*)d_in[7];
  const float* bvd = (const float*)d_in[8];
  const float* Wvu = (const float*)d_in[9];
  const float* bvu = (const float*)d_in[10];
  const float* ln2_g = (const float*)d_in[11];
  const float* ln2_b = (const float*)d_in[12];
  const float* W1 = (const float*)d_in[13];
  const float* b1 = (const float*)d_in[14];
  const float* W2 = (const float*)d_in[15];
  const float* b2 = (const float*)d_in[16];
  float* out = (float*)d_out;
  (void)in_sizes; (void)n_in; (void)out_size; (void)ws_size;

  char* ws = (char*)d_ws;
  const size_t MB = 1024 * 1024;
  const size_t KB = 1024;
  u16* wqkvT = (u16*)(ws + 0);                    // [2560x1024] bf16, 5 MB
  u16* wvuB = (u16*)(ws + 5 * MB);                // 64 KB
  float* bqkv = (float*)(ws + 5 * MB + 64 * KB);  // 10 KB
  u16* w1T = (u16*)(ws + 5 * MB + 384 * KB);      // 8 MB -> 13.375
  u16* w2T = (u16*)(ws + 13 * MB + 384 * KB);     // 8 MB -> 21.375
  u16* hbuf = (u16*)(ws + 21 * MB + 384 * KB);    // 8 MB -> 29.375
  u16* cqkv = (u16*)(ws + 29 * MB + 384 * KB);    // 20 MB -> 49.375
  u16* vT = (u16*)(ws + 49 * MB + 384 * KB);      // 8 MB -> 57.375
  float* ob = (float*)(ws + 57 * MB + 384 * KB);  // 16 MB -> 73.375
  float* x2 = (float*)(ws + 73 * MB + 384 * KB);  // 16 MB -> 89.375
  // lifetime-disjoint reuses:
  u16* ubuf = cqkv;            // 32 MB (cqkv+vT+ob[0:4MB]), dead by FFN1
  u16* p1 = (u16*)(ws + 0);    // 8 MB over wqkvT+..., dead by FFN2
  u16* p2 = (u16*)hbuf;        // 8 MB, hbuf dead after FFN1
  u16* p3 = (u16*)vT;          // 8 MB, vT dead after attention

  dim3 blk(256);
  wtrans<<<dim3(2, 32, 16), blk, 0, stream>>>(Wq, wqkvT, 1024, 64, 65536L, 65536L, C2F);
  wtrans<<<dim3(2, 32, 16), blk, 0, stream>>>(Wk, wqkvT + 1024 * 1024, 1024, 64,
                                              65536L, 65536L, 1.0f);
  wtrans<<<dim3(1, 32, 16), blk, 0, stream>>>(Wvd, wqkvT + 2048 * 1024, 1024, 32,
                                              32768L, 32768L, 1.0f);
  wconv<<<dim3(32), blk, 0, stream>>>(Wvu, wvuB, H_ * R_ * HD_);
  bconcat<<<dim3(10), blk, 0, stream>>>(bq, bk, bvd, bqkv);
  wtrans<<<dim3(128, 32, 1), blk, 0, stream>>>(W1, w1T, 1024, 4096, 0L, 0L, 1.0f);
  wtrans<<<dim3(32, 128, 1), blk, 0, stream>>>(W2, w2T, 4096, 1024, 0L, 0L, 1.0f);
  ln_kernel<<<dim3(M_), blk, 0, stream>>>(x, (const float*)nullptr, ln1_g, ln1_b,
                                          hbuf, (float*)nullptr);
  // fused QKV projection (2-phase 128² — 640 blocks, 2.5/CU, T1-swizzled)
  gemm_nt<0><<<dim3(20, 32), blk, 0, stream>>>(hbuf, wqkvT, 1024, 1024, 1024, bqkv,
                                               (const float*)nullptr, (void*)cqkv,
                                               (void*)nullptr, NQKV);
  vu_kernel<<<dim3(S_ / 64, H_, B_), blk, 0, stream>>>(cqkv, wvuB, bvu, vT);
  // attention v4: grid (H, B, 8), 512 threads, 48KB dynamic LDS
  attn_kernel<<<dim3(H_, B_, 8), dim3(512), 49152, stream>>>(cqkv, vT, ob);
  ln_kernel<<<dim3(M_), blk, 0, stream>>>(x, ob, ln2_g, ln2_b, hbuf, x2);
  // FFN1: gemm4, grid 32x32 = 1024 blocks (2 resident/CU), nk=16
  gemm4<1><<<dim3(32, 32, 1), dim3(256), 65536, stream>>>(
      hbuf, w1T, 1024, 1024, 16, b1, (float*)nullptr, ubuf,
      (u16*)nullptr, (u16*)nullptr, (u16*)nullptr, 4096);
  // FFN2: gemm4 split-K=4, grid 8x32x4 = 1024 blocks; z=0 -> raw f32 into out
  gemm4<4><<<dim3(8, 32, 4), dim3(256), 65536, stream>>>(
      ubuf, w2T, 4096, 4096, 16, (const float*)nullptr, out, (u16*)nullptr,
      p1, p2, p3, 1024);
  // out += p1+p2+p3 + b2 + x2
  reduce2<<<dim3(M_ * D_ / 1024), blk, 0, stream>>>(out, p1, p2, p3, b2, x2);
}

// Round 18
// 227.331 us; speedup vs baseline: 1.0663x; 1.0663x over previous
//
#include <hip/hip_runtime.h>

// ---------------------------------------------------------------------------
// TransformerBlock: LN1 -> QKV proj (fused) -> reversed-causal attention
// (scale 1/sqrt(D)=1/32) -> residual -> LN2 -> GELU FFN -> residual.
// B=2 S=2048 D=1024 H=16 HD=64 R=32 F=4096. All d_in/d_out fp32; internal
// compute bf16 MFMA.
// R17: revert to the R16 best composite (227.4us). gemm4 (128-tile FFN)
// regressed (FETCH 37->70MB: halved tile halves arithmetic intensity;
// reuse > occupancy-overlap at this shape). Composite: attn v4
// (counted-vmcnt ring), gemm8 256x256 R7-schedule for FFN1/FFN2(split-K=4),
// gemm_nt 128x128 for QKV, T1 XCD swizzles, unfused reduce2.
// ---------------------------------------------------------------------------

typedef unsigned short u16;
typedef __attribute__((ext_vector_type(4))) float f32x4;
typedef __attribute__((ext_vector_type(8))) __bf16 bf16x8;

#define B_ 2
#define S_ 2048
#define D_ 1024
#define H_ 16
#define HD_ 64
#define R_ 32
#define F_ 4096
#define M_ (B_ * S_)   // 4096 rows
#define NQKV 2560      // 1024 q + 1024 k + 512 vd
// (1/sqrt(D)) * log2(e): folded into Wq/bq so QK^T scores are exp2-ready
#define C2F 0.04508422002778011f

__device__ __forceinline__ u16 f2bf(float f) {
  union { float f; unsigned u; } v; v.f = f;
  unsigned u = v.u;
  return (u16)((u + 0x7FFFu + ((u >> 16) & 1u)) >> 16);  // RNE
}
__device__ __forceinline__ float bf2f(u16 h) {
  union { unsigned u; float f; } v; v.u = ((unsigned)h) << 16;
  return v.f;
}
__device__ __forceinline__ unsigned pk_bf16(float lo, float hi) {
  unsigned r;
  asm volatile("v_cvt_pk_bf16_f32 %0, %1, %2" : "=v"(r) : "v"(lo), "v"(hi));
  return r;
}

typedef __attribute__((address_space(1))) void gvoid;
typedef __attribute__((address_space(3))) void lvoid;
// async global->LDS, 16B/lane; lds base must be wave-uniform (lane*16 implicit)
__device__ __forceinline__ void gload_lds16(const void* g, void* l) {
  __builtin_amdgcn_global_load_lds((gvoid*)(void*)g, (lvoid*)l, 16, 0, 0);
}

__device__ __forceinline__ float gelu_f(float x) {
  float t = tanhf(0.7978845608028654f * (x + 0.044715f * x * x * x));
  return 0.5f * x * (1.0f + t);
}

// ---- fp32 [Rr,Cc] (batched) -> bf16 transposed [Cc,Rr], optional scale ----
__global__ __launch_bounds__(256) void wtrans(const float* __restrict__ in,
                                              u16* __restrict__ out,
                                              int Rr, int Cc, long ibs, long obs,
                                              float scale) {
  __shared__ float tile[32][33];
  const float* ip = in + (size_t)blockIdx.z * ibs;
  u16* op = out + (size_t)blockIdx.z * obs;
  int c0 = blockIdx.x * 32, r0 = blockIdx.y * 32;
  int tx = threadIdx.x & 31, ty = threadIdx.x >> 5;  // 32 x 8
#pragma unroll
  for (int j = 0; j < 32; j += 8)
    tile[ty + j][tx] = ip[(size_t)(r0 + ty + j) * Cc + c0 + tx];
  __syncthreads();
#pragma unroll
  for (int j = 0; j < 32; j += 8)
    op[(size_t)(c0 + ty + j) * Rr + r0 + tx] = f2bf(tile[tx][ty + j] * scale);
}

// ---- flat fp32 -> bf16 -----------------------------------------------------
__global__ __launch_bounds__(256) void wconv(const float* __restrict__ in,
                                             u16* __restrict__ out, int n) {
  int i = (blockIdx.x * 256 + threadIdx.x) * 4;
  if (i < n) {
    float4 v = *(const float4*)&in[i];
    ushort4 o;
    o.x = f2bf(v.x); o.y = f2bf(v.y); o.z = f2bf(v.z); o.w = f2bf(v.w);
    *(ushort4*)&out[i] = o;
  }
}

// ---- concat biases: [bq*C2F | bk | bvd] -> bqkv[2560] ----------------------
__global__ __launch_bounds__(256) void bconcat(const float* __restrict__ bq,
                                               const float* __restrict__ bk,
                                               const float* __restrict__ bvd,
                                               float* __restrict__ o) {
  int i = blockIdx.x * 256 + threadIdx.x;
  if (i < NQKV) {
    float v = (i < 1024) ? bq[i] * C2F : (i < 2048 ? bk[i - 1024] : bvd[i - 2048]);
    o[i] = v;
  }
}

// ---- LayerNorm (optionally fused residual add + x2 passthrough) -----------
__global__ __launch_bounds__(256) void ln_kernel(const float* __restrict__ xin,
                                                 const float* __restrict__ addin,
                                                 const float* __restrict__ gam,
                                                 const float* __restrict__ bet,
                                                 u16* __restrict__ hout,
                                                 float* __restrict__ x2out) {
  int row = blockIdx.x, tid = threadIdx.x;
  size_t base = (size_t)row * D_ + tid * 4;
  float4 v = *(const float4*)&xin[base];
  if (addin) {
    float4 a = *(const float4*)&addin[base];
    v.x += a.x; v.y += a.y; v.z += a.z; v.w += a.w;
  }
  if (x2out) *(float4*)&x2out[base] = v;
  float s = v.x + v.y + v.z + v.w;
  float ss = v.x * v.x + v.y * v.y + v.z * v.z + v.w * v.w;
#pragma unroll
  for (int off = 32; off > 0; off >>= 1) {
    s += __shfl_down(s, off);
    ss += __shfl_down(ss, off);
  }
  __shared__ float red[8];
  int wv = tid >> 6;
  if ((tid & 63) == 0) { red[wv] = s; red[4 + wv] = ss; }
  __syncthreads();
  if (tid == 0) {
    float s1 = red[0] + red[1] + red[2] + red[3];
    float s2 = red[4] + red[5] + red[6] + red[7];
    float mu = s1 * (1.0f / D_);
    red[0] = mu;
    red[1] = s2 * (1.0f / D_) - mu * mu;
  }
  __syncthreads();
  float mu = red[0];
  float rstd = rsqrtf(red[1] + 1e-5f);
  int ci = tid * 4;
  ushort4 o;
  o.x = f2bf((v.x - mu) * rstd * gam[ci + 0] + bet[ci + 0]);
  o.y = f2bf((v.y - mu) * rstd * gam[ci + 1] + bet[ci + 1]);
  o.z = f2bf((v.z - mu) * rstd * gam[ci + 2] + bet[ci + 2]);
  o.w = f2bf((v.w - mu) * rstd * gam[ci + 3] + bet[ci + 3]);
  *(ushort4*)&hout[base] = o;
}

// ---- NT GEMM (128x128, 2-phase dbuf): used for the fused QKV projection ---
// T1: XCD-aware block swizzle (nwg = 20*32 = 640, %8==0 -> bijective).
template <int MODE>
__global__ __launch_bounds__(256) void gemm_nt(const u16* __restrict__ A,
                                               const u16* __restrict__ Bt,
                                               int K, int lda, int ldb,
                                               const float* __restrict__ bias,
                                               const float* __restrict__ res,
                                               void* __restrict__ Cout,
                                               void* __restrict__ Cout2, int ldc) {
  __shared__ __align__(16) u16 As0[128 * 32];
  __shared__ __align__(16) u16 Bs0[128 * 32];
  __shared__ __align__(16) u16 As1[128 * 32];
  __shared__ __align__(16) u16 Bs1[128 * 32];
  int tid = threadIdx.x;
  int lane = tid & 63, wid = tid >> 6;
  int wm = wid >> 1, wn = wid & 1;
  int bid = blockIdx.x + gridDim.x * blockIdx.y;
  int nwg = gridDim.x * gridDim.y;
  int swz = (bid & 7) * (nwg >> 3) + (bid >> 3);
  int tbx = swz % gridDim.x, tby = swz / gridDim.x;
  int row0 = tby * 128, col0 = tbx * 128;
  int l15 = lane & 15, g = lane >> 4;
  int srow = lane >> 2, scol = (lane & 3) * 8;
  f32x4 acc[4][4] = {};
  const u16* Ap = A + (size_t)row0 * lda;
  const u16* Bp = Bt + (size_t)col0 * ldb;

  auto STAGE = [&](u16* AS, u16* BS, int kk) {
#pragma unroll
    for (int i = 0; i < 2; ++i) {
      int c = wid * 2 + i;
      gload_lds16(Ap + (size_t)(c * 16 + srow) * lda + kk + scol, &AS[c * 512]);
      gload_lds16(Bp + (size_t)(c * 16 + srow) * ldb + kk + scol, &BS[c * 512]);
    }
  };
  auto COMPUTE = [&](const u16* AS, const u16* BS) {
    bf16x8 af[4], bfr[4];
#pragma unroll
    for (int t = 0; t < 4; ++t) {
      af[t] = *(const bf16x8*)&AS[(wm * 64 + t * 16 + l15) * 32 + g * 8];
      bfr[t] = *(const bf16x8*)&BS[(wn * 64 + t * 16 + l15) * 32 + g * 8];
    }
#pragma unroll
    for (int mt = 0; mt < 4; ++mt)
#pragma unroll
      for (int nt = 0; nt < 4; ++nt)
        acc[mt][nt] = __builtin_amdgcn_mfma_f32_16x16x32_bf16(af[mt], bfr[nt],
                                                              acc[mt][nt], 0, 0, 0);
  };

  STAGE(As0, Bs0, 0);
  __syncthreads();
  for (int k0 = 0; k0 < K; k0 += 64) {
    if (k0 + 32 < K) STAGE(As1, Bs1, k0 + 32);
    COMPUTE(As0, Bs0);
    __syncthreads();
    if (k0 + 64 < K) STAGE(As0, Bs0, k0 + 64);
    COMPUTE(As1, Bs1);
    __syncthreads();
  }

#pragma unroll
  for (int mt = 0; mt < 4; ++mt) {
#pragma unroll
    for (int nt = 0; nt < 4; ++nt) {
      int cc = col0 + wn * 64 + nt * 16 + l15;
      float bv = bias ? bias[cc] : 0.0f;
#pragma unroll
      for (int j = 0; j < 4; ++j) {
        int rr = row0 + wm * 64 + mt * 16 + g * 4 + j;
        float v = acc[mt][nt][j] + bv;
        if (MODE == 1) v = gelu_f(v);
        if (MODE == 2) {
          ((float*)Cout)[(size_t)rr * ldc + cc] = v + res[(size_t)rr * ldc + cc];
        } else {
          ((u16*)Cout)[(size_t)rr * ldc + cc] = f2bf(v);
        }
      }
    }
  }
  (void)Cout2;
}

// ---- gemm8 (R7 schedule): 256x256, BK=64, 2-slot dbuf, stage interleaved ---
// 8 waves (2Mx4N). LDS: 2 slots x (A 32KB + B 32KB) = 128KB dynamic.
// Swizzle (row&7)<<4 both sides (conflicts measured 0).
// Per K-tile: {ds_read kk0 | STAGE_A(next) | 32 MFMA | ds_read kk1 |
// STAGE_B(next) | 32 MFMA | vmcnt(0) | s_barrier}.
// T1: XCD-aware (x,y) swizzle per z-slice (nwg%8==0; z-slices 64-aligned).
// MODE 1: bf16 gelu(v+bias) -> Cb. MODE 4: split-K, z=0 -> f32 RAW v to Cf;
// z=1..3 -> bf16 raw to P1/P2/P3 (bias/res applied in reduce2).
template <int MODE>
__global__ __launch_bounds__(512, 2) void gemm8(
    const u16* __restrict__ A, const u16* __restrict__ Bt,
    int lda, int ldb, int nk,
    const float* __restrict__ bias,
    float* __restrict__ Cf, u16* __restrict__ Cb,
    u16* __restrict__ P1, u16* __restrict__ P2, u16* __restrict__ P3,
    int ldc) {
  extern __shared__ __align__(16) char smem[];
  int tid = threadIdx.x;
  int lane = tid & 63, wid = tid >> 6;
  int wm = wid >> 2, wn = wid & 3;
  int l15 = lane & 15, g = lane >> 4;
  int bid = blockIdx.x + gridDim.x * blockIdx.y;
  int nwg = gridDim.x * gridDim.y;
  int swz = (bid & 7) * (nwg >> 3) + (bid >> 3);
  int tbx = swz % gridDim.x, tby = swz / gridDim.x;
  int row0 = tby * 256, col0 = tbx * 256;
  int koff = (MODE == 4) ? blockIdx.z * (nk * 64) : 0;
  const u16* Ap = A + (size_t)row0 * lda + koff;
  const u16* Bp = Bt + (size_t)col0 * ldb + koff;
  int trow = tid >> 3;
  int sbyte = ((tid & 7) * 16) ^ ((trow & 7) << 4);
  int xr = (l15 & 7) << 4;

  f32x4 acc[8][4] = {};

  auto STAGE_A = [&](int buf, int kt) {
#pragma unroll
    for (int l = 0; l < 4; ++l)
      gload_lds16((const char*)(Ap + (size_t)(l * 64 + trow) * lda + kt) + sbyte,
                  smem + buf * 65536 + (l * 64 + wid * 8) * 128);
  };
  auto STAGE_B = [&](int buf, int kt) {
#pragma unroll
    for (int l = 0; l < 4; ++l)
      gload_lds16((const char*)(Bp + (size_t)(l * 64 + trow) * ldb + kt) + sbyte,
                  smem + buf * 65536 + 32768 + (l * 64 + wid * 8) * 128);
  };

  STAGE_A(0, 0);
  STAGE_B(0, 0);
  asm volatile("s_waitcnt vmcnt(0)" ::: "memory");
  __builtin_amdgcn_sched_barrier(0);
  __builtin_amdgcn_s_barrier();

  int cur = 0;
  for (int it = 0; it < nk; ++it) {
    const char* Ab = smem + cur * 65536 + (size_t)(wm * 128 + l15) * 128;
    const char* Bb = smem + cur * 65536 + 32768 + (size_t)(wn * 64 + l15) * 128;
    bool nxt = (it + 1 < nk);
#pragma unroll
    for (int kk = 0; kk < 2; ++kk) {
      int kq = (kk * 64 + g * 16) ^ xr;
      bf16x8 bfr[4], af[8];
#pragma unroll
      for (int nt = 0; nt < 4; ++nt)
        bfr[nt] = *(const bf16x8*)(Bb + nt * 2048 + kq);
#pragma unroll
      for (int mt = 0; mt < 8; ++mt)
        af[mt] = *(const bf16x8*)(Ab + mt * 2048 + kq);
      if (nxt) {
        if (kk == 0) STAGE_A(cur ^ 1, (it + 1) * 64);
        else         STAGE_B(cur ^ 1, (it + 1) * 64);
      }
      __builtin_amdgcn_s_setprio(1);
#pragma unroll
      for (int mt = 0; mt < 8; ++mt)
#pragma unroll
        for (int nt = 0; nt < 4; ++nt)
          acc[mt][nt] = __builtin_amdgcn_mfma_f32_16x16x32_bf16(af[mt], bfr[nt],
                                                                acc[mt][nt], 0, 0, 0);
      __builtin_amdgcn_s_setprio(0);
    }
    asm volatile("s_waitcnt vmcnt(0)" ::: "memory");
    __builtin_amdgcn_sched_barrier(0);
    __builtin_amdgcn_s_barrier();
    cur ^= 1;
  }

  u16* pp = (u16*)nullptr;
  if (MODE == 4 && blockIdx.z != 0)
    pp = (blockIdx.z == 1) ? P1 : (blockIdx.z == 2 ? P2 : P3);
#pragma unroll
  for (int mt = 0; mt < 8; ++mt) {
#pragma unroll
    for (int nt = 0; nt < 4; ++nt) {
      int cc = col0 + wn * 64 + nt * 16 + l15;
      float bv = (MODE == 1) ? bias[cc] : 0.0f;
#pragma unroll
      for (int j = 0; j < 4; ++j) {
        int rr = row0 + wm * 128 + mt * 16 + g * 4 + j;
        float v = acc[mt][nt][j] + bv;
        if (MODE == 1) {
          Cb[(size_t)rr * ldc + cc] = f2bf(gelu_f(v));
        } else {
          if (blockIdx.z == 0) Cf[(size_t)rr * ldc + cc] = v;
          else                 pp[(size_t)rr * ldc + cc] = f2bf(v);
        }
      }
    }
  }
}

// ---- split-K reduce: out += p1+p2+p3 (bf16) + b2[col] + x2 -----------------
__global__ __launch_bounds__(256) void reduce2(float* __restrict__ out,
                                               const u16* __restrict__ p1,
                                               const u16* __restrict__ p2,
                                               const u16* __restrict__ p3,
                                               const float* __restrict__ b2,
                                               const float* __restrict__ x2) {
  int i = (blockIdx.x * 256 + threadIdx.x) * 4;
  float4 o = *(float4*)&out[i];
  ushort4 a = *(const ushort4*)&p1[i];
  ushort4 b = *(const ushort4*)&p2[i];
  ushort4 c = *(const ushort4*)&p3[i];
  float4 r = *(const float4*)&x2[i];
  int cix = i & (D_ - 1);
  o.x += bf2f(a.x) + bf2f(b.x) + bf2f(c.x) + b2[cix + 0] + r.x;
  o.y += bf2f(a.y) + bf2f(b.y) + bf2f(c.y) + b2[cix + 1] + r.y;
  o.z += bf2f(a.z) + bf2f(b.z) + bf2f(c.z) + b2[cix + 2] + r.z;
  o.w += bf2f(a.w) + bf2f(b.w) + bf2f(c.w) + b2[cix + 3] + r.w;
  *(float4*)&out[i] = o;
}

// ---- low-rank V up-proj -> V^T [b,h][e][t] bf16 ----------------------------
__global__ __launch_bounds__(256) void vu_kernel(const u16* __restrict__ vd,
                                                 const u16* __restrict__ wvu,
                                                 const float* __restrict__ bvu,
                                                 u16* __restrict__ v_t) {
  int t0 = blockIdx.x * 64, h = blockIdx.y, b = blockIdx.z;
  __shared__ u16 vds[64][32];
  __shared__ u16 vt[64][65];
  int tid = threadIdx.x;
  {
    int rr2 = tid >> 2, c8 = (tid & 3) * 8;
    *(bf16x8*)&vds[rr2][c8] =
        *(const bf16x8*)&vd[(size_t)(b * S_ + t0 + rr2) * NQKV + 2048 + h * R_ + c8];
  }
  __syncthreads();
  int e = tid & 63, tg = (tid >> 6) * 16;
  float wcol[32];
#pragma unroll
  for (int r = 0; r < 32; ++r) wcol[r] = bf2f(wvu[((size_t)h * R_ + r) * HD_ + e]);
  float bb = bvu[h * HD_ + e];
  for (int i = 0; i < 16; ++i) {
    int t = tg + i;
    float acc = bb;
#pragma unroll
    for (int r = 0; r < 32; ++r) acc += bf2f(vds[t][r]) * wcol[r];
    vt[t][e] = f2bf(acc);
  }
  __syncthreads();
  for (int idx = tid; idx < 64 * 64; idx += 256) {
    int e2 = idx >> 6, t2 = idx & 63;
    v_t[((size_t)(b * H_ + h) * HD_ + e2) * S_ + t0 + t2] = vt[t2][e2];
  }
}

// ---- attention v4 (R11-verified): reversed-causal (key t >= query s) -------
// grid (H, B, 8). 8 waves, QBLK=128 triangle-paired (uniform 34 steps).
// Counted-vmcnt 3-buffer ring: one s_barrier + vmcnt(2) per step (vmcnt(0)
// last), STAGE(it+2) after the barrier.
__global__ __launch_bounds__(512, 2) void attn_kernel(const u16* __restrict__ cqkv,
                                                      const u16* __restrict__ v_t,
                                                      float* __restrict__ o) {
  extern __shared__ __align__(16) u16 kv[];  // 3 bufs x (K 4096 + V 4096) u16
  __shared__ u16 Pl[8][16 * 64];             // per-wave Q then P^T tile
  int tid = threadIdx.x;
  int lane = tid & 63, w = tid >> 6;
  int h = blockIdx.x, b = blockIdx.y;
  int bx = blockIdx.z;
  int r = lane & 15, g = lane >> 4;
  const u16* qp = cqkv + (size_t)(b * S_) * NQKV + h * HD_;
  const u16* kp = cqkv + (size_t)(b * S_) * NQKV + 1024 + h * HD_;
  const u16* vp = v_t + (size_t)(b * H_ + h) * HD_ * S_;
  u16* Pw = Pl[w];

  int srow = w * 8 + (lane >> 3);
  int ssw = ((lane & 7) * 16) ^ (((lane >> 3) & 7) << 4);  // pre-swz byte in row

  int xr = (r & 7) << 4;                // read-side XOR (rows = ..*16 + r)
  int kq0 = ((g * 16) ^ xr) >> 1;       // elem offset, k-group 0
  int kq1 = ((64 + g * 16) ^ xr) >> 1;  // elem offset, k-group 1

  auto STAGE = [&](int buf, int kt) {
    u16* base = kv + buf * 8192;
    gload_lds16((const char*)(kp + (size_t)(kt + srow) * NQKV) + ssw,
                base + w * 512);
    gload_lds16((const char*)(vp + (size_t)srow * S_ + kt) + ssw,
                base + 4096 + w * 512);
  };

#pragma unroll 1
  for (int half = 0; half < 2; ++half) {
    int qb = half ? (S_ - 128) - bx * 128 : bx * 128;
    int s0 = qb + w * 16;
    int qrow = s0 + r;

    gload_lds16((const char*)(qp + (size_t)(s0 + (lane >> 3)) * NQKV) + ssw, Pw);
    gload_lds16((const char*)(qp + (size_t)(s0 + 8 + (lane >> 3)) * NQKV) + ssw,
                Pw + 512);
    asm volatile("s_waitcnt vmcnt(0)" ::: "memory");
    __builtin_amdgcn_sched_barrier(0);
    __builtin_amdgcn_s_barrier();
    __builtin_amdgcn_sched_barrier(0);
    bf16x8 aq0 = *(const bf16x8*)&Pw[(r << 6) + kq0];
    bf16x8 aq1 = *(const bf16x8*)&Pw[(r << 6) + kq1];

    f32x4 oa[4] = {};
    float m_ = -1e30f, l_ = 0.0f;

    int nt = (S_ - qb) >> 6;
    STAGE(0, qb);
    STAGE(1, qb + 64);

    for (int it = 0; it < nt; ++it) {
      int kt = qb + it * 64;
      if (it + 1 < nt) {
        asm volatile("s_waitcnt vmcnt(2)" ::: "memory");
      } else {
        asm volatile("s_waitcnt vmcnt(0)" ::: "memory");
      }
      __builtin_amdgcn_sched_barrier(0);
      __builtin_amdgcn_s_barrier();
      __builtin_amdgcn_sched_barrier(0);
      if (it + 2 < nt) STAGE((it + 2) % 3, qb + (it + 2) * 64);

      if (kt + 64 > s0) {
        const u16* Kb = kv + (it % 3) * 8192;
        const u16* Vb = Kb + 4096;

        f32x4 sc[4] = {};
#pragma unroll
        for (int blk = 0; blk < 4; ++blk) {
          bf16x8 a0 = *(const bf16x8*)&Kb[((blk * 16 + r) << 6) + kq0];
          bf16x8 a1 = *(const bf16x8*)&Kb[((blk * 16 + r) << 6) + kq1];
          sc[blk] = __builtin_amdgcn_mfma_f32_16x16x32_bf16(a0, aq0, sc[blk], 0, 0, 0);
          sc[blk] = __builtin_amdgcn_mfma_f32_16x16x32_bf16(a1, aq1, sc[blk], 0, 0, 0);
        }

        float p[16];
        if ((qrow & ~63) == kt) {
#pragma unroll
          for (int blk = 0; blk < 4; ++blk)
#pragma unroll
            for (int j = 0; j < 4; ++j) {
              int kk = kt + blk * 16 + g * 4 + j;
              p[blk * 4 + j] = (kk < qrow) ? -1e30f : sc[blk][j];
            }
        } else {
#pragma unroll
          for (int blk = 0; blk < 4; ++blk)
#pragma unroll
            for (int j = 0; j < 4; ++j) p[blk * 4 + j] = sc[blk][j];
        }
        float mx = p[0];
#pragma unroll
        for (int i = 1; i < 16; ++i) mx = fmaxf(mx, p[i]);
        mx = fmaxf(mx, __shfl_xor(mx, 16));
        mx = fmaxf(mx, __shfl_xor(mx, 32));
        float mn = fmaxf(m_, mx);
        float scl = __builtin_amdgcn_exp2f(m_ - mn);
        m_ = mn;
        float sm = 0.0f;
#pragma unroll
        for (int i = 0; i < 16; ++i) {
          p[i] = __builtin_amdgcn_exp2f(p[i] - mn);
          sm += p[i];
        }
        sm += __shfl_xor(sm, 16);
        sm += __shfl_xor(sm, 32);
        l_ = l_ * scl + sm;
#pragma unroll
        for (int et = 0; et < 4; ++et) oa[et] *= scl;

#pragma unroll
        for (int blk = 0; blk < 4; ++blk) {
          uint2 pk;
          pk.x = pk_bf16(p[blk * 4 + 0], p[blk * 4 + 1]);
          pk.y = pk_bf16(p[blk * 4 + 2], p[blk * 4 + 3]);
          *(uint2*)&Pw[(r << 6) + ((((blk << 5) + (g << 3)) ^ xr) >> 1)] = pk;
        }
        asm volatile("s_waitcnt lgkmcnt(0)" ::: "memory");
        __builtin_amdgcn_sched_barrier(0);
        bf16x8 pb0 = *(const bf16x8*)&Pw[(r << 6) + kq0];
        bf16x8 pb1 = *(const bf16x8*)&Pw[(r << 6) + kq1];
#pragma unroll
        for (int et = 0; et < 4; ++et) {
          bf16x8 v0 = *(const bf16x8*)&Vb[((et * 16 + r) << 6) + kq0];
          bf16x8 v1 = *(const bf16x8*)&Vb[((et * 16 + r) << 6) + kq1];
          oa[et] = __builtin_amdgcn_mfma_f32_16x16x32_bf16(v0, pb0, oa[et], 0, 0, 0);
          oa[et] = __builtin_amdgcn_mfma_f32_16x16x32_bf16(v1, pb1, oa[et], 0, 0, 0);
        }
      }
    }

    float inv = 1.0f / l_;
#pragma unroll
    for (int et = 0; et < 4; ++et)
#pragma unroll
      for (int j = 0; j < 4; ++j)
        o[(size_t)(b * S_ + s0 + r) * D_ + h * HD_ + et * 16 + g * 4 + j] =
            oa[et][j] * inv;
  }
}

// one-time (dlopen) LDS-limit raise for dynamic-shared kernels
namespace {
struct GemmAttrInit {
  GemmAttrInit() {
    hipFuncSetAttribute((const void*)gemm8<1>,
                        hipFuncAttributeMaxDynamicSharedMemorySize, 131072);
    hipFuncSetAttribute((const void*)gemm8<4>,
                        hipFuncAttributeMaxDynamicSharedMemorySize, 131072);
    hipFuncSetAttribute((const void*)attn_kernel,
                        hipFuncAttributeMaxDynamicSharedMemorySize, 49152);
  }
};
GemmAttrInit _gemm_attr_init;
}  // namespace

extern "C" void kernel_launch(void* const* d_in, const int* in_sizes, int n_in,
                              void* d_out, int out_size, void* d_ws, size_t ws_size,
                              hipStream_t stream) {
  const float* x = (const float*)d_in[0];
  const float* ln1_g = (const float*)d_in[1];
  const float* ln1_b = (const float*)d_in[2];
  const float* Wq = (const float*)d_in[3];
  const float* bq = (const float*)d_in[4];
  const float* Wk = (const float*)d_in[5];
  const float* bk = (const float*)d_in[6];
  const float* Wvd = (const float*)d_in[7];
  const float* bvd = (const float*)d_in[8];
  const float* Wvu = (const float*)d_in[9];
  const float* bvu = (const float*)d_in[10];
  const float* ln2_g = (const float*)d_in[11];
  const float* ln2_b = (const float*)d_in[12];
  const float* W1 = (const float*)d_in[13];
  const float* b1 = (const float*)d_in[14];
  const float* W2 = (const float*)d_in[15];
  const float* b2 = (const float*)d_in[16];
  float* out = (float*)d_out;
  (void)in_sizes; (void)n_in; (void)out_size; (void)ws_size;

  char* ws = (char*)d_ws;
  const size_t MB = 1024 * 1024;
  const size_t KB = 1024;
  u16* wqkvT = (u16*)(ws + 0);                    // [2560x1024] bf16, 5 MB
  u16* wvuB = (u16*)(ws + 5 * MB);                // 64 KB
  float* bqkv = (float*)(ws + 5 * MB + 64 * KB);  // 10 KB
  u16* w1T = (u16*)(ws + 5 * MB + 384 * KB);      // 8 MB -> 13.375
  u16* w2T = (u16*)(ws + 13 * MB + 384 * KB);     // 8 MB -> 21.375
  u16* hbuf = (u16*)(ws + 21 * MB + 384 * KB);    // 8 MB -> 29.375
  u16* cqkv = (u16*)(ws + 29 * MB + 384 * KB);    // 20 MB -> 49.375
  u16* vT = (u16*)(ws + 49 * MB + 384 * KB);      // 8 MB -> 57.375
  float* ob = (float*)(ws + 57 * MB + 384 * KB);  // 16 MB -> 73.375
  float* x2 = (float*)(ws + 73 * MB + 384 * KB);  // 16 MB -> 89.375
  // lifetime-disjoint reuses:
  u16* ubuf = cqkv;            // 32 MB (cqkv+vT+ob[0:4MB]), dead by FFN1
  u16* p1 = (u16*)(ws + 0);    // 8 MB over wqkvT+..., dead by FFN2
  u16* p2 = (u16*)hbuf;        // 8 MB, hbuf dead after FFN1
  u16* p3 = (u16*)vT;          // 8 MB, vT dead after attention

  dim3 blk(256);
  wtrans<<<dim3(2, 32, 16), blk, 0, stream>>>(Wq, wqkvT, 1024, 64, 65536L, 65536L, C2F);
  wtrans<<<dim3(2, 32, 16), blk, 0, stream>>>(Wk, wqkvT + 1024 * 1024, 1024, 64,
                                              65536L, 65536L, 1.0f);
  wtrans<<<dim3(1, 32, 16), blk, 0, stream>>>(Wvd, wqkvT + 2048 * 1024, 1024, 32,
                                              32768L, 32768L, 1.0f);
  wconv<<<dim3(32), blk, 0, stream>>>(Wvu, wvuB, H_ * R_ * HD_);
  bconcat<<<dim3(10), blk, 0, stream>>>(bq, bk, bvd, bqkv);
  wtrans<<<dim3(128, 32, 1), blk, 0, stream>>>(W1, w1T, 1024, 4096, 0L, 0L, 1.0f);
  wtrans<<<dim3(32, 128, 1), blk, 0, stream>>>(W2, w2T, 4096, 1024, 0L, 0L, 1.0f);
  ln_kernel<<<dim3(M_), blk, 0, stream>>>(x, (const float*)nullptr, ln1_g, ln1_b,
                                          hbuf, (float*)nullptr);
  // fused QKV projection (2-phase 128² — 640 blocks, 2.5/CU, T1-swizzled)
  gemm_nt<0><<<dim3(20, 32), blk, 0, stream>>>(hbuf, wqkvT, 1024, 1024, 1024, bqkv,
                                               (const float*)nullptr, (void*)cqkv,
                                               (void*)nullptr, NQKV);
  vu_kernel<<<dim3(S_ / 64, H_, B_), blk, 0, stream>>>(cqkv, wvuB, bvu, vT);
  // attention v4: grid (H, B, 8), 512 threads, 48KB dynamic LDS
  attn_kernel<<<dim3(H_, B_, 8), dim3(512), 49152, stream>>>(cqkv, vT, ob);
  ln_kernel<<<dim3(M_), blk, 0, stream>>>(x, ob, ln2_g, ln2_b, hbuf, x2);
  // FFN1: 256² R7 pipeline, grid 16x16 = 1 block/CU, T1-swizzled
  gemm8<1><<<dim3(16, 16, 1), dim3(512), 131072, stream>>>(
      hbuf, w1T, 1024, 1024, 16, b1, (float*)nullptr, ubuf,
      (u16*)nullptr, (u16*)nullptr, (u16*)nullptr, 4096);
  // FFN2: split-K=4, grid 4x16x4, T1-swizzled per z; z=0 -> raw f32 into out
  gemm8<4><<<dim3(4, 16, 4), dim3(512), 131072, stream>>>(
      ubuf, w2T, 4096, 4096, 16, (const float*)nullptr, out, (u16*)nullptr,
      p1, p2, p3, 1024);
  // out += p1+p2+p3 + b2 + x2
  reduce2<<<dim3(M_ * D_ / 1024), blk, 0, stream>>>(out, p1, p2, p3, b2, x2);
}

// Round 19
// 226.598 us; speedup vs baseline: 1.0698x; 1.0032x over previous
//
#include <hip/hip_runtime.h>

// ---------------------------------------------------------------------------
// TransformerBlock: LN1 -> QKV proj (fused) -> reversed-causal attention
// (scale 1/sqrt(D)=1/32) -> residual -> LN2 -> GELU FFN -> residual.
// B=2 S=2048 D=1024 H=16 HD=64 R=32 F=4096. All d_in/d_out fp32; internal
// compute bf16 MFMA.
// R18: ob (attention output) stored bf16 instead of f32 — halves the
// write+read round-trip (−16 MB HBM). Everything else = R18 verified
// composite: attn v4 (counted-vmcnt ring), gemm8 256² R7-schedule for
// FFN1/FFN2(split-K=4), gemm_nt 128² QKV, T1 XCD swizzles, unfused reduce2.
// ---------------------------------------------------------------------------

typedef unsigned short u16;
typedef __attribute__((ext_vector_type(4))) float f32x4;
typedef __attribute__((ext_vector_type(8))) __bf16 bf16x8;

#define B_ 2
#define S_ 2048
#define D_ 1024
#define H_ 16
#define HD_ 64
#define R_ 32
#define F_ 4096
#define M_ (B_ * S_)   // 4096 rows
#define NQKV 2560      // 1024 q + 1024 k + 512 vd
// (1/sqrt(D)) * log2(e): folded into Wq/bq so QK^T scores are exp2-ready
#define C2F 0.04508422002778011f

__device__ __forceinline__ u16 f2bf(float f) {
  union { float f; unsigned u; } v; v.f = f;
  unsigned u = v.u;
  return (u16)((u + 0x7FFFu + ((u >> 16) & 1u)) >> 16);  // RNE
}
__device__ __forceinline__ float bf2f(u16 h) {
  union { unsigned u; float f; } v; v.u = ((unsigned)h) << 16;
  return v.f;
}
__device__ __forceinline__ unsigned pk_bf16(float lo, float hi) {
  unsigned r;
  asm volatile("v_cvt_pk_bf16_f32 %0, %1, %2" : "=v"(r) : "v"(lo), "v"(hi));
  return r;
}

typedef __attribute__((address_space(1))) void gvoid;
typedef __attribute__((address_space(3))) void lvoid;
// async global->LDS, 16B/lane; lds base must be wave-uniform (lane*16 implicit)
__device__ __forceinline__ void gload_lds16(const void* g, void* l) {
  __builtin_amdgcn_global_load_lds((gvoid*)(void*)g, (lvoid*)l, 16, 0, 0);
}

__device__ __forceinline__ float gelu_f(float x) {
  float t = tanhf(0.7978845608028654f * (x + 0.044715f * x * x * x));
  return 0.5f * x * (1.0f + t);
}

// ---- fp32 [Rr,Cc] (batched) -> bf16 transposed [Cc,Rr], optional scale ----
__global__ __launch_bounds__(256) void wtrans(const float* __restrict__ in,
                                              u16* __restrict__ out,
                                              int Rr, int Cc, long ibs, long obs,
                                              float scale) {
  __shared__ float tile[32][33];
  const float* ip = in + (size_t)blockIdx.z * ibs;
  u16* op = out + (size_t)blockIdx.z * obs;
  int c0 = blockIdx.x * 32, r0 = blockIdx.y * 32;
  int tx = threadIdx.x & 31, ty = threadIdx.x >> 5;  // 32 x 8
#pragma unroll
  for (int j = 0; j < 32; j += 8)
    tile[ty + j][tx] = ip[(size_t)(r0 + ty + j) * Cc + c0 + tx];
  __syncthreads();
#pragma unroll
  for (int j = 0; j < 32; j += 8)
    op[(size_t)(c0 + ty + j) * Rr + r0 + tx] = f2bf(tile[tx][ty + j] * scale);
}

// ---- flat fp32 -> bf16 -----------------------------------------------------
__global__ __launch_bounds__(256) void wconv(const float* __restrict__ in,
                                             u16* __restrict__ out, int n) {
  int i = (blockIdx.x * 256 + threadIdx.x) * 4;
  if (i < n) {
    float4 v = *(const float4*)&in[i];
    ushort4 o;
    o.x = f2bf(v.x); o.y = f2bf(v.y); o.z = f2bf(v.z); o.w = f2bf(v.w);
    *(ushort4*)&out[i] = o;
  }
}

// ---- concat biases: [bq*C2F | bk | bvd] -> bqkv[2560] ----------------------
__global__ __launch_bounds__(256) void bconcat(const float* __restrict__ bq,
                                               const float* __restrict__ bk,
                                               const float* __restrict__ bvd,
                                               float* __restrict__ o) {
  int i = blockIdx.x * 256 + threadIdx.x;
  if (i < NQKV) {
    float v = (i < 1024) ? bq[i] * C2F : (i < 2048 ? bk[i - 1024] : bvd[i - 2048]);
    o[i] = v;
  }
}

// ---- LayerNorm (optional bf16 residual addin + x2 passthrough) -------------
__global__ __launch_bounds__(256) void ln_kernel(const float* __restrict__ xin,
                                                 const u16* __restrict__ addin,
                                                 const float* __restrict__ gam,
                                                 const float* __restrict__ bet,
                                                 u16* __restrict__ hout,
                                                 float* __restrict__ x2out) {
  int row = blockIdx.x, tid = threadIdx.x;
  size_t base = (size_t)row * D_ + tid * 4;
  float4 v = *(const float4*)&xin[base];
  if (addin) {
    ushort4 a = *(const ushort4*)&addin[base];
    v.x += bf2f(a.x); v.y += bf2f(a.y); v.z += bf2f(a.z); v.w += bf2f(a.w);
  }
  if (x2out) *(float4*)&x2out[base] = v;
  float s = v.x + v.y + v.z + v.w;
  float ss = v.x * v.x + v.y * v.y + v.z * v.z + v.w * v.w;
#pragma unroll
  for (int off = 32; off > 0; off >>= 1) {
    s += __shfl_down(s, off);
    ss += __shfl_down(ss, off);
  }
  __shared__ float red[8];
  int wv = tid >> 6;
  if ((tid & 63) == 0) { red[wv] = s; red[4 + wv] = ss; }
  __syncthreads();
  if (tid == 0) {
    float s1 = red[0] + red[1] + red[2] + red[3];
    float s2 = red[4] + red[5] + red[6] + red[7];
    float mu = s1 * (1.0f / D_);
    red[0] = mu;
    red[1] = s2 * (1.0f / D_) - mu * mu;
  }
  __syncthreads();
  float mu = red[0];
  float rstd = rsqrtf(red[1] + 1e-5f);
  int ci = tid * 4;
  ushort4 o;
  o.x = f2bf((v.x - mu) * rstd * gam[ci + 0] + bet[ci + 0]);
  o.y = f2bf((v.y - mu) * rstd * gam[ci + 1] + bet[ci + 1]);
  o.z = f2bf((v.z - mu) * rstd * gam[ci + 2] + bet[ci + 2]);
  o.w = f2bf((v.w - mu) * rstd * gam[ci + 3] + bet[ci + 3]);
  *(ushort4*)&hout[base] = o;
}

// ---- NT GEMM (128x128, 2-phase dbuf): used for the fused QKV projection ---
// T1: XCD-aware block swizzle (nwg = 20*32 = 640, %8==0 -> bijective).
template <int MODE>
__global__ __launch_bounds__(256) void gemm_nt(const u16* __restrict__ A,
                                               const u16* __restrict__ Bt,
                                               int K, int lda, int ldb,
                                               const float* __restrict__ bias,
                                               const float* __restrict__ res,
                                               void* __restrict__ Cout,
                                               void* __restrict__ Cout2, int ldc) {
  __shared__ __align__(16) u16 As0[128 * 32];
  __shared__ __align__(16) u16 Bs0[128 * 32];
  __shared__ __align__(16) u16 As1[128 * 32];
  __shared__ __align__(16) u16 Bs1[128 * 32];
  int tid = threadIdx.x;
  int lane = tid & 63, wid = tid >> 6;
  int wm = wid >> 1, wn = wid & 1;
  int bid = blockIdx.x + gridDim.x * blockIdx.y;
  int nwg = gridDim.x * gridDim.y;
  int swz = (bid & 7) * (nwg >> 3) + (bid >> 3);
  int tbx = swz % gridDim.x, tby = swz / gridDim.x;
  int row0 = tby * 128, col0 = tbx * 128;
  int l15 = lane & 15, g = lane >> 4;
  int srow = lane >> 2, scol = (lane & 3) * 8;
  f32x4 acc[4][4] = {};
  const u16* Ap = A + (size_t)row0 * lda;
  const u16* Bp = Bt + (size_t)col0 * ldb;

  auto STAGE = [&](u16* AS, u16* BS, int kk) {
#pragma unroll
    for (int i = 0; i < 2; ++i) {
      int c = wid * 2 + i;
      gload_lds16(Ap + (size_t)(c * 16 + srow) * lda + kk + scol, &AS[c * 512]);
      gload_lds16(Bp + (size_t)(c * 16 + srow) * ldb + kk + scol, &BS[c * 512]);
    }
  };
  auto COMPUTE = [&](const u16* AS, const u16* BS) {
    bf16x8 af[4], bfr[4];
#pragma unroll
    for (int t = 0; t < 4; ++t) {
      af[t] = *(const bf16x8*)&AS[(wm * 64 + t * 16 + l15) * 32 + g * 8];
      bfr[t] = *(const bf16x8*)&BS[(wn * 64 + t * 16 + l15) * 32 + g * 8];
    }
#pragma unroll
    for (int mt = 0; mt < 4; ++mt)
#pragma unroll
      for (int nt = 0; nt < 4; ++nt)
        acc[mt][nt] = __builtin_amdgcn_mfma_f32_16x16x32_bf16(af[mt], bfr[nt],
                                                              acc[mt][nt], 0, 0, 0);
  };

  STAGE(As0, Bs0, 0);
  __syncthreads();
  for (int k0 = 0; k0 < K; k0 += 64) {
    if (k0 + 32 < K) STAGE(As1, Bs1, k0 + 32);
    COMPUTE(As0, Bs0);
    __syncthreads();
    if (k0 + 64 < K) STAGE(As0, Bs0, k0 + 64);
    COMPUTE(As1, Bs1);
    __syncthreads();
  }

#pragma unroll
  for (int mt = 0; mt < 4; ++mt) {
#pragma unroll
    for (int nt = 0; nt < 4; ++nt) {
      int cc = col0 + wn * 64 + nt * 16 + l15;
      float bv = bias ? bias[cc] : 0.0f;
#pragma unroll
      for (int j = 0; j < 4; ++j) {
        int rr = row0 + wm * 64 + mt * 16 + g * 4 + j;
        float v = acc[mt][nt][j] + bv;
        if (MODE == 1) v = gelu_f(v);
        if (MODE == 2) {
          ((float*)Cout)[(size_t)rr * ldc + cc] = v + res[(size_t)rr * ldc + cc];
        } else {
          ((u16*)Cout)[(size_t)rr * ldc + cc] = f2bf(v);
        }
      }
    }
  }
  (void)Cout2;
}

// ---- gemm8 (R7 schedule): 256x256, BK=64, 2-slot dbuf, stage interleaved ---
// 8 waves (2Mx4N). LDS: 2 slots x (A 32KB + B 32KB) = 128KB dynamic.
// Swizzle (row&7)<<4 both sides (conflicts measured 0).
// Per K-tile: {ds_read kk0 | STAGE_A(next) | 32 MFMA | ds_read kk1 |
// STAGE_B(next) | 32 MFMA | vmcnt(0) | s_barrier}.
// T1: XCD-aware (x,y) swizzle per z-slice (nwg%8==0; z-slices 64-aligned).
// MODE 1: bf16 gelu(v+bias) -> Cb. MODE 4: split-K, z=0 -> f32 RAW v to Cf;
// z=1..3 -> bf16 raw to P1/P2/P3 (bias/res applied in reduce2).
template <int MODE>
__global__ __launch_bounds__(512, 2) void gemm8(
    const u16* __restrict__ A, const u16* __restrict__ Bt,
    int lda, int ldb, int nk,
    const float* __restrict__ bias,
    float* __restrict__ Cf, u16* __restrict__ Cb,
    u16* __restrict__ P1, u16* __restrict__ P2, u16* __restrict__ P3,
    int ldc) {
  extern __shared__ __align__(16) char smem[];
  int tid = threadIdx.x;
  int lane = tid & 63, wid = tid >> 6;
  int wm = wid >> 2, wn = wid & 3;
  int l15 = lane & 15, g = lane >> 4;
  int bid = blockIdx.x + gridDim.x * blockIdx.y;
  int nwg = gridDim.x * gridDim.y;
  int swz = (bid & 7) * (nwg >> 3) + (bid >> 3);
  int tbx = swz % gridDim.x, tby = swz / gridDim.x;
  int row0 = tby * 256, col0 = tbx * 256;
  int koff = (MODE == 4) ? blockIdx.z * (nk * 64) : 0;
  const u16* Ap = A + (size_t)row0 * lda + koff;
  const u16* Bp = Bt + (size_t)col0 * ldb + koff;
  int trow = tid >> 3;
  int sbyte = ((tid & 7) * 16) ^ ((trow & 7) << 4);
  int xr = (l15 & 7) << 4;

  f32x4 acc[8][4] = {};

  auto STAGE_A = [&](int buf, int kt) {
#pragma unroll
    for (int l = 0; l < 4; ++l)
      gload_lds16((const char*)(Ap + (size_t)(l * 64 + trow) * lda + kt) + sbyte,
                  smem + buf * 65536 + (l * 64 + wid * 8) * 128);
  };
  auto STAGE_B = [&](int buf, int kt) {
#pragma unroll
    for (int l = 0; l < 4; ++l)
      gload_lds16((const char*)(Bp + (size_t)(l * 64 + trow) * ldb + kt) + sbyte,
                  smem + buf * 65536 + 32768 + (l * 64 + wid * 8) * 128);
  };

  STAGE_A(0, 0);
  STAGE_B(0, 0);
  asm volatile("s_waitcnt vmcnt(0)" ::: "memory");
  __builtin_amdgcn_sched_barrier(0);
  __builtin_amdgcn_s_barrier();

  int cur = 0;
  for (int it = 0; it < nk; ++it) {
    const char* Ab = smem + cur * 65536 + (size_t)(wm * 128 + l15) * 128;
    const char* Bb = smem + cur * 65536 + 32768 + (size_t)(wn * 64 + l15) * 128;
    bool nxt = (it + 1 < nk);
#pragma unroll
    for (int kk = 0; kk < 2; ++kk) {
      int kq = (kk * 64 + g * 16) ^ xr;
      bf16x8 bfr[4], af[8];
#pragma unroll
      for (int nt = 0; nt < 4; ++nt)
        bfr[nt] = *(const bf16x8*)(Bb + nt * 2048 + kq);
#pragma unroll
      for (int mt = 0; mt < 8; ++mt)
        af[mt] = *(const bf16x8*)(Ab + mt * 2048 + kq);
      if (nxt) {
        if (kk == 0) STAGE_A(cur ^ 1, (it + 1) * 64);
        else         STAGE_B(cur ^ 1, (it + 1) * 64);
      }
      __builtin_amdgcn_s_setprio(1);
#pragma unroll
      for (int mt = 0; mt < 8; ++mt)
#pragma unroll
        for (int nt = 0; nt < 4; ++nt)
          acc[mt][nt] = __builtin_amdgcn_mfma_f32_16x16x32_bf16(af[mt], bfr[nt],
                                                                acc[mt][nt], 0, 0, 0);
      __builtin_amdgcn_s_setprio(0);
    }
    asm volatile("s_waitcnt vmcnt(0)" ::: "memory");
    __builtin_amdgcn_sched_barrier(0);
    __builtin_amdgcn_s_barrier();
    cur ^= 1;
  }

  u16* pp = (u16*)nullptr;
  if (MODE == 4 && blockIdx.z != 0)
    pp = (blockIdx.z == 1) ? P1 : (blockIdx.z == 2 ? P2 : P3);
#pragma unroll
  for (int mt = 0; mt < 8; ++mt) {
#pragma unroll
    for (int nt = 0; nt < 4; ++nt) {
      int cc = col0 + wn * 64 + nt * 16 + l15;
      float bv = (MODE == 1) ? bias[cc] : 0.0f;
#pragma unroll
      for (int j = 0; j < 4; ++j) {
        int rr = row0 + wm * 128 + mt * 16 + g * 4 + j;
        float v = acc[mt][nt][j] + bv;
        if (MODE == 1) {
          Cb[(size_t)rr * ldc + cc] = f2bf(gelu_f(v));
        } else {
          if (blockIdx.z == 0) Cf[(size_t)rr * ldc + cc] = v;
          else                 pp[(size_t)rr * ldc + cc] = f2bf(v);
        }
      }
    }
  }
}

// ---- split-K reduce: out += p1+p2+p3 (bf16) + b2[col] + x2 -----------------
__global__ __launch_bounds__(256) void reduce2(float* __restrict__ out,
                                               const u16* __restrict__ p1,
                                               const u16* __restrict__ p2,
                                               const u16* __restrict__ p3,
                                               const float* __restrict__ b2,
                                               const float* __restrict__ x2) {
  int i = (blockIdx.x * 256 + threadIdx.x) * 4;
  float4 o = *(float4*)&out[i];
  ushort4 a = *(const ushort4*)&p1[i];
  ushort4 b = *(const ushort4*)&p2[i];
  ushort4 c = *(const ushort4*)&p3[i];
  float4 r = *(const float4*)&x2[i];
  int cix = i & (D_ - 1);
  o.x += bf2f(a.x) + bf2f(b.x) + bf2f(c.x) + b2[cix + 0] + r.x;
  o.y += bf2f(a.y) + bf2f(b.y) + bf2f(c.y) + b2[cix + 1] + r.y;
  o.z += bf2f(a.z) + bf2f(b.z) + bf2f(c.z) + b2[cix + 2] + r.z;
  o.w += bf2f(a.w) + bf2f(b.w) + bf2f(c.w) + b2[cix + 3] + r.w;
  *(float4*)&out[i] = o;
}

// ---- low-rank V up-proj -> V^T [b,h][e][t] bf16 ----------------------------
__global__ __launch_bounds__(256) void vu_kernel(const u16* __restrict__ vd,
                                                 const u16* __restrict__ wvu,
                                                 const float* __restrict__ bvu,
                                                 u16* __restrict__ v_t) {
  int t0 = blockIdx.x * 64, h = blockIdx.y, b = blockIdx.z;
  __shared__ u16 vds[64][32];
  __shared__ u16 vt[64][65];
  int tid = threadIdx.x;
  {
    int rr2 = tid >> 2, c8 = (tid & 3) * 8;
    *(bf16x8*)&vds[rr2][c8] =
        *(const bf16x8*)&vd[(size_t)(b * S_ + t0 + rr2) * NQKV + 2048 + h * R_ + c8];
  }
  __syncthreads();
  int e = tid & 63, tg = (tid >> 6) * 16;
  float wcol[32];
#pragma unroll
  for (int r = 0; r < 32; ++r) wcol[r] = bf2f(wvu[((size_t)h * R_ + r) * HD_ + e]);
  float bb = bvu[h * HD_ + e];
  for (int i = 0; i < 16; ++i) {
    int t = tg + i;
    float acc = bb;
#pragma unroll
    for (int r = 0; r < 32; ++r) acc += bf2f(vds[t][r]) * wcol[r];
    vt[t][e] = f2bf(acc);
  }
  __syncthreads();
  for (int idx = tid; idx < 64 * 64; idx += 256) {
    int e2 = idx >> 6, t2 = idx & 63;
    v_t[((size_t)(b * H_ + h) * HD_ + e2) * S_ + t0 + t2] = vt[t2][e2];
  }
}

// ---- attention v4 (R11-verified): reversed-causal (key t >= query s) -------
// grid (H, B, 8). 8 waves, QBLK=128 triangle-paired (uniform 34 steps).
// Counted-vmcnt 3-buffer ring: one s_barrier + vmcnt(2) per step (vmcnt(0)
// last), STAGE(it+2) after the barrier. Output stored bf16 (R18).
__global__ __launch_bounds__(512, 2) void attn_kernel(const u16* __restrict__ cqkv,
                                                      const u16* __restrict__ v_t,
                                                      u16* __restrict__ o) {
  extern __shared__ __align__(16) u16 kv[];  // 3 bufs x (K 4096 + V 4096) u16
  __shared__ u16 Pl[8][16 * 64];             // per-wave Q then P^T tile
  int tid = threadIdx.x;
  int lane = tid & 63, w = tid >> 6;
  int h = blockIdx.x, b = blockIdx.y;
  int bx = blockIdx.z;
  int r = lane & 15, g = lane >> 4;
  const u16* qp = cqkv + (size_t)(b * S_) * NQKV + h * HD_;
  const u16* kp = cqkv + (size_t)(b * S_) * NQKV + 1024 + h * HD_;
  const u16* vp = v_t + (size_t)(b * H_ + h) * HD_ * S_;
  u16* Pw = Pl[w];

  int srow = w * 8 + (lane >> 3);
  int ssw = ((lane & 7) * 16) ^ (((lane >> 3) & 7) << 4);  // pre-swz byte in row

  int xr = (r & 7) << 4;                // read-side XOR (rows = ..*16 + r)
  int kq0 = ((g * 16) ^ xr) >> 1;       // elem offset, k-group 0
  int kq1 = ((64 + g * 16) ^ xr) >> 1;  // elem offset, k-group 1

  auto STAGE = [&](int buf, int kt) {
    u16* base = kv + buf * 8192;
    gload_lds16((const char*)(kp + (size_t)(kt + srow) * NQKV) + ssw,
                base + w * 512);
    gload_lds16((const char*)(vp + (size_t)srow * S_ + kt) + ssw,
                base + 4096 + w * 512);
  };

#pragma unroll 1
  for (int half = 0; half < 2; ++half) {
    int qb = half ? (S_ - 128) - bx * 128 : bx * 128;
    int s0 = qb + w * 16;
    int qrow = s0 + r;

    gload_lds16((const char*)(qp + (size_t)(s0 + (lane >> 3)) * NQKV) + ssw, Pw);
    gload_lds16((const char*)(qp + (size_t)(s0 + 8 + (lane >> 3)) * NQKV) + ssw,
                Pw + 512);
    asm volatile("s_waitcnt vmcnt(0)" ::: "memory");
    __builtin_amdgcn_sched_barrier(0);
    __builtin_amdgcn_s_barrier();
    __builtin_amdgcn_sched_barrier(0);
    bf16x8 aq0 = *(const bf16x8*)&Pw[(r << 6) + kq0];
    bf16x8 aq1 = *(const bf16x8*)&Pw[(r << 6) + kq1];

    f32x4 oa[4] = {};
    float m_ = -1e30f, l_ = 0.0f;

    int nt = (S_ - qb) >> 6;
    STAGE(0, qb);
    STAGE(1, qb + 64);

    for (int it = 0; it < nt; ++it) {
      int kt = qb + it * 64;
      if (it + 1 < nt) {
        asm volatile("s_waitcnt vmcnt(2)" ::: "memory");
      } else {
        asm volatile("s_waitcnt vmcnt(0)" ::: "memory");
      }
      __builtin_amdgcn_sched_barrier(0);
      __builtin_amdgcn_s_barrier();
      __builtin_amdgcn_sched_barrier(0);
      if (it + 2 < nt) STAGE((it + 2) % 3, qb + (it + 2) * 64);

      if (kt + 64 > s0) {
        const u16* Kb = kv + (it % 3) * 8192;
        const u16* Vb = Kb + 4096;

        f32x4 sc[4] = {};
#pragma unroll
        for (int blk = 0; blk < 4; ++blk) {
          bf16x8 a0 = *(const bf16x8*)&Kb[((blk * 16 + r) << 6) + kq0];
          bf16x8 a1 = *(const bf16x8*)&Kb[((blk * 16 + r) << 6) + kq1];
          sc[blk] = __builtin_amdgcn_mfma_f32_16x16x32_bf16(a0, aq0, sc[blk], 0, 0, 0);
          sc[blk] = __builtin_amdgcn_mfma_f32_16x16x32_bf16(a1, aq1, sc[blk], 0, 0, 0);
        }

        float p[16];
        if ((qrow & ~63) == kt) {
#pragma unroll
          for (int blk = 0; blk < 4; ++blk)
#pragma unroll
            for (int j = 0; j < 4; ++j) {
              int kk = kt + blk * 16 + g * 4 + j;
              p[blk * 4 + j] = (kk < qrow) ? -1e30f : sc[blk][j];
            }
        } else {
#pragma unroll
          for (int blk = 0; blk < 4; ++blk)
#pragma unroll
            for (int j = 0; j < 4; ++j) p[blk * 4 + j] = sc[blk][j];
        }
        float mx = p[0];
#pragma unroll
        for (int i = 1; i < 16; ++i) mx = fmaxf(mx, p[i]);
        mx = fmaxf(mx, __shfl_xor(mx, 16));
        mx = fmaxf(mx, __shfl_xor(mx, 32));
        float mn = fmaxf(m_, mx);
        float scl = __builtin_amdgcn_exp2f(m_ - mn);
        m_ = mn;
        float sm = 0.0f;
#pragma unroll
        for (int i = 0; i < 16; ++i) {
          p[i] = __builtin_amdgcn_exp2f(p[i] - mn);
          sm += p[i];
        }
        sm += __shfl_xor(sm, 16);
        sm += __shfl_xor(sm, 32);
        l_ = l_ * scl + sm;
#pragma unroll
        for (int et = 0; et < 4; ++et) oa[et] *= scl;

#pragma unroll
        for (int blk = 0; blk < 4; ++blk) {
          uint2 pk;
          pk.x = pk_bf16(p[blk * 4 + 0], p[blk * 4 + 1]);
          pk.y = pk_bf16(p[blk * 4 + 2], p[blk * 4 + 3]);
          *(uint2*)&Pw[(r << 6) + ((((blk << 5) + (g << 3)) ^ xr) >> 1)] = pk;
        }
        asm volatile("s_waitcnt lgkmcnt(0)" ::: "memory");
        __builtin_amdgcn_sched_barrier(0);
        bf16x8 pb0 = *(const bf16x8*)&Pw[(r << 6) + kq0];
        bf16x8 pb1 = *(const bf16x8*)&Pw[(r << 6) + kq1];
#pragma unroll
        for (int et = 0; et < 4; ++et) {
          bf16x8 v0 = *(const bf16x8*)&Vb[((et * 16 + r) << 6) + kq0];
          bf16x8 v1 = *(const bf16x8*)&Vb[((et * 16 + r) << 6) + kq1];
          oa[et] = __builtin_amdgcn_mfma_f32_16x16x32_bf16(v0, pb0, oa[et], 0, 0, 0);
          oa[et] = __builtin_amdgcn_mfma_f32_16x16x32_bf16(v1, pb1, oa[et], 0, 0, 0);
        }
      }
    }

    float inv = 1.0f / l_;
#pragma unroll
    for (int et = 0; et < 4; ++et)
#pragma unroll
      for (int j = 0; j < 4; ++j)
        o[(size_t)(b * S_ + s0 + r) * D_ + h * HD_ + et * 16 + g * 4 + j] =
            f2bf(oa[et][j] * inv);
  }
}

// one-time (dlopen) LDS-limit raise for dynamic-shared kernels
namespace {
struct GemmAttrInit {
  GemmAttrInit() {
    hipFuncSetAttribute((const void*)gemm8<1>,
                        hipFuncAttributeMaxDynamicSharedMemorySize, 131072);
    hipFuncSetAttribute((const void*)gemm8<4>,
                        hipFuncAttributeMaxDynamicSharedMemorySize, 131072);
    hipFuncSetAttribute((const void*)attn_kernel,
                        hipFuncAttributeMaxDynamicSharedMemorySize, 49152);
  }
};
GemmAttrInit _gemm_attr_init;
}  // namespace

extern "C" void kernel_launch(void* const* d_in, const int* in_sizes, int n_in,
                              void* d_out, int out_size, void* d_ws, size_t ws_size,
                              hipStream_t stream) {
  const float* x = (const float*)d_in[0];
  const float* ln1_g = (const float*)d_in[1];
  const float* ln1_b = (const float*)d_in[2];
  const float* Wq = (const float*)d_in[3];
  const float* bq = (const float*)d_in[4];
  const float* Wk = (const float*)d_in[5];
  const float* bk = (const float*)d_in[6];
  const float* Wvd = (const float*)d_in[7];
  const float* bvd = (const float*)d_in[8];
  const float* Wvu = (const float*)d_in[9];
  const float* bvu = (const float*)d_in[10];
  const float* ln2_g = (const float*)d_in[11];
  const float* ln2_b = (const float*)d_in[12];
  const float* W1 = (const float*)d_in[13];
  const float* b1 = (const float*)d_in[14];
  const float* W2 = (const float*)d_in[15];
  const float* b2 = (const float*)d_in[16];
  float* out = (float*)d_out;
  (void)in_sizes; (void)n_in; (void)out_size; (void)ws_size;

  char* ws = (char*)d_ws;
  const size_t MB = 1024 * 1024;
  const size_t KB = 1024;
  u16* wqkvT = (u16*)(ws + 0);                    // [2560x1024] bf16, 5 MB
  u16* wvuB = (u16*)(ws + 5 * MB);                // 64 KB
  float* bqkv = (float*)(ws + 5 * MB + 64 * KB);  // 10 KB
  u16* w1T = (u16*)(ws + 5 * MB + 384 * KB);      // 8 MB -> 13.375
  u16* w2T = (u16*)(ws + 13 * MB + 384 * KB);     // 8 MB -> 21.375
  u16* hbuf = (u16*)(ws + 21 * MB + 384 * KB);    // 8 MB -> 29.375
  u16* cqkv = (u16*)(ws + 29 * MB + 384 * KB);    // 20 MB -> 49.375
  u16* vT = (u16*)(ws + 49 * MB + 384 * KB);      // 8 MB -> 57.375
  u16* ob16 = (u16*)(ws + 57 * MB + 384 * KB);    // 8 MB (bf16) -> 65.375
  float* x2 = (float*)(ws + 73 * MB + 384 * KB);  // 16 MB -> 89.375
  // lifetime-disjoint reuses:
  u16* ubuf = cqkv;            // 32 MB (cqkv+vT+ob16), dead by FFN1
  u16* p1 = (u16*)(ws + 0);    // 8 MB over wqkvT+..., dead by FFN2
  u16* p2 = (u16*)hbuf;        // 8 MB, hbuf dead after FFN1
  u16* p3 = (u16*)vT;          // 8 MB, vT dead after attention

  dim3 blk(256);
  wtrans<<<dim3(2, 32, 16), blk, 0, stream>>>(Wq, wqkvT, 1024, 64, 65536L, 65536L, C2F);
  wtrans<<<dim3(2, 32, 16), blk, 0, stream>>>(Wk, wqkvT + 1024 * 1024, 1024, 64,
                                              65536L, 65536L, 1.0f);
  wtrans<<<dim3(1, 32, 16), blk, 0, stream>>>(Wvd, wqkvT + 2048 * 1024, 1024, 32,
                                              32768L, 32768L, 1.0f);
  wconv<<<dim3(32), blk, 0, stream>>>(Wvu, wvuB, H_ * R_ * HD_);
  bconcat<<<dim3(10), blk, 0, stream>>>(bq, bk, bvd, bqkv);
  wtrans<<<dim3(128, 32, 1), blk, 0, stream>>>(W1, w1T, 1024, 4096, 0L, 0L, 1.0f);
  wtrans<<<dim3(32, 128, 1), blk, 0, stream>>>(W2, w2T, 4096, 1024, 0L, 0L, 1.0f);
  ln_kernel<<<dim3(M_), blk, 0, stream>>>(x, (const u16*)nullptr, ln1_g, ln1_b,
                                          hbuf, (float*)nullptr);
  // fused QKV projection (2-phase 128² — 640 blocks, 2.5/CU, T1-swizzled)
  gemm_nt<0><<<dim3(20, 32), blk, 0, stream>>>(hbuf, wqkvT, 1024, 1024, 1024, bqkv,
                                               (const float*)nullptr, (void*)cqkv,
                                               (void*)nullptr, NQKV);
  vu_kernel<<<dim3(S_ / 64, H_, B_), blk, 0, stream>>>(cqkv, wvuB, bvu, vT);
  // attention v4: grid (H, B, 8), 512 threads, 48KB dynamic LDS; bf16 out
  attn_kernel<<<dim3(H_, B_, 8), dim3(512), 49152, stream>>>(cqkv, vT, ob16);
  ln_kernel<<<dim3(M_), blk, 0, stream>>>(x, ob16, ln2_g, ln2_b, hbuf, x2);
  // FFN1: 256² R7 pipeline, grid 16x16 = 1 block/CU, T1-swizzled
  gemm8<1><<<dim3(16, 16, 1), dim3(512), 131072, stream>>>(
      hbuf, w1T, 1024, 1024, 16, b1, (float*)nullptr, ubuf,
      (u16*)nullptr, (u16*)nullptr, (u16*)nullptr, 4096);
  // FFN2: split-K=4, grid 4x16x4, T1-swizzled per z; z=0 -> raw f32 into out
  gemm8<4><<<dim3(4, 16, 4), dim3(512), 131072, stream>>>(
      ubuf, w2T, 4096, 4096, 16, (const float*)nullptr, out, (u16*)nullptr,
      p1, p2, p3, 1024);
  // out += p1+p2+p3 + b2 + x2
  reduce2<<<dim3(M_ * D_ / 1024), blk, 0, stream>>>(out, p1, p2, p3, b2, x2);
}

// Round 20
// 222.947 us; speedup vs baseline: 1.0873x; 1.0164x over previous
//
#include <hip/hip_runtime.h>

// ---------------------------------------------------------------------------
// TransformerBlock: LN1 -> QKV proj (fused) -> reversed-causal attention
// (scale 1/sqrt(D)=1/32) -> residual -> LN2 -> GELU FFN -> residual.
// B=2 S=2048 D=1024 H=16 HD=64 R=32 F=4096. All d_in/d_out fp32; internal
// compute bf16 MFMA.
// R19: epilogue-traffic trims + layout-hazard fix —
//   * x2 (residual passthrough) stored bf16 (−16 MB round trip)
//   * FFN2 z=0 writes bf16 partial p0; reduce2 WRITES out = Σp + b2 + x2
//     (no read-modify-write; −16 MB)
//   * p3 moved out of the ubuf range (latent epilogue-write/A-read overlap)
// Everything else = R19 verified composite (attn v4 + bf16 ob, gemm8 256²
// R7-schedule FFNs, gemm_nt 128² QKV, T1 swizzles).
// ---------------------------------------------------------------------------

typedef unsigned short u16;
typedef __attribute__((ext_vector_type(4))) float f32x4;
typedef __attribute__((ext_vector_type(8))) __bf16 bf16x8;

#define B_ 2
#define S_ 2048
#define D_ 1024
#define H_ 16
#define HD_ 64
#define R_ 32
#define F_ 4096
#define M_ (B_ * S_)   // 4096 rows
#define NQKV 2560      // 1024 q + 1024 k + 512 vd
// (1/sqrt(D)) * log2(e): folded into Wq/bq so QK^T scores are exp2-ready
#define C2F 0.04508422002778011f

__device__ __forceinline__ u16 f2bf(float f) {
  union { float f; unsigned u; } v; v.f = f;
  unsigned u = v.u;
  return (u16)((u + 0x7FFFu + ((u >> 16) & 1u)) >> 16);  // RNE
}
__device__ __forceinline__ float bf2f(u16 h) {
  union { unsigned u; float f; } v; v.u = ((unsigned)h) << 16;
  return v.f;
}
__device__ __forceinline__ unsigned pk_bf16(float lo, float hi) {
  unsigned r;
  asm volatile("v_cvt_pk_bf16_f32 %0, %1, %2" : "=v"(r) : "v"(lo), "v"(hi));
  return r;
}

typedef __attribute__((address_space(1))) void gvoid;
typedef __attribute__((address_space(3))) void lvoid;
// async global->LDS, 16B/lane; lds base must be wave-uniform (lane*16 implicit)
__device__ __forceinline__ void gload_lds16(const void* g, void* l) {
  __builtin_amdgcn_global_load_lds((gvoid*)(void*)g, (lvoid*)l, 16, 0, 0);
}

__device__ __forceinline__ float gelu_f(float x) {
  float t = tanhf(0.7978845608028654f * (x + 0.044715f * x * x * x));
  return 0.5f * x * (1.0f + t);
}

// ---- fp32 [Rr,Cc] (batched) -> bf16 transposed [Cc,Rr], optional scale ----
__global__ __launch_bounds__(256) void wtrans(const float* __restrict__ in,
                                              u16* __restrict__ out,
                                              int Rr, int Cc, long ibs, long obs,
                                              float scale) {
  __shared__ float tile[32][33];
  const float* ip = in + (size_t)blockIdx.z * ibs;
  u16* op = out + (size_t)blockIdx.z * obs;
  int c0 = blockIdx.x * 32, r0 = blockIdx.y * 32;
  int tx = threadIdx.x & 31, ty = threadIdx.x >> 5;  // 32 x 8
#pragma unroll
  for (int j = 0; j < 32; j += 8)
    tile[ty + j][tx] = ip[(size_t)(r0 + ty + j) * Cc + c0 + tx];
  __syncthreads();
#pragma unroll
  for (int j = 0; j < 32; j += 8)
    op[(size_t)(c0 + ty + j) * Rr + r0 + tx] = f2bf(tile[tx][ty + j] * scale);
}

// ---- flat fp32 -> bf16 -----------------------------------------------------
__global__ __launch_bounds__(256) void wconv(const float* __restrict__ in,
                                             u16* __restrict__ out, int n) {
  int i = (blockIdx.x * 256 + threadIdx.x) * 4;
  if (i < n) {
    float4 v = *(const float4*)&in[i];
    ushort4 o;
    o.x = f2bf(v.x); o.y = f2bf(v.y); o.z = f2bf(v.z); o.w = f2bf(v.w);
    *(ushort4*)&out[i] = o;
  }
}

// ---- concat biases: [bq*C2F | bk | bvd] -> bqkv[2560] ----------------------
__global__ __launch_bounds__(256) void bconcat(const float* __restrict__ bq,
                                               const float* __restrict__ bk,
                                               const float* __restrict__ bvd,
                                               float* __restrict__ o) {
  int i = blockIdx.x * 256 + threadIdx.x;
  if (i < NQKV) {
    float v = (i < 1024) ? bq[i] * C2F : (i < 2048 ? bk[i - 1024] : bvd[i - 2048]);
    o[i] = v;
  }
}

// ---- LayerNorm (optional bf16 residual addin + bf16 x2 passthrough) --------
__global__ __launch_bounds__(256) void ln_kernel(const float* __restrict__ xin,
                                                 const u16* __restrict__ addin,
                                                 const float* __restrict__ gam,
                                                 const float* __restrict__ bet,
                                                 u16* __restrict__ hout,
                                                 u16* __restrict__ x2out) {
  int row = blockIdx.x, tid = threadIdx.x;
  size_t base = (size_t)row * D_ + tid * 4;
  float4 v = *(const float4*)&xin[base];
  if (addin) {
    ushort4 a = *(const ushort4*)&addin[base];
    v.x += bf2f(a.x); v.y += bf2f(a.y); v.z += bf2f(a.z); v.w += bf2f(a.w);
  }
  if (x2out) {
    ushort4 xo;
    xo.x = f2bf(v.x); xo.y = f2bf(v.y); xo.z = f2bf(v.z); xo.w = f2bf(v.w);
    *(ushort4*)&x2out[base] = xo;
  }
  float s = v.x + v.y + v.z + v.w;
  float ss = v.x * v.x + v.y * v.y + v.z * v.z + v.w * v.w;
#pragma unroll
  for (int off = 32; off > 0; off >>= 1) {
    s += __shfl_down(s, off);
    ss += __shfl_down(ss, off);
  }
  __shared__ float red[8];
  int wv = tid >> 6;
  if ((tid & 63) == 0) { red[wv] = s; red[4 + wv] = ss; }
  __syncthreads();
  if (tid == 0) {
    float s1 = red[0] + red[1] + red[2] + red[3];
    float s2 = red[4] + red[5] + red[6] + red[7];
    float mu = s1 * (1.0f / D_);
    red[0] = mu;
    red[1] = s2 * (1.0f / D_) - mu * mu;
  }
  __syncthreads();
  float mu = red[0];
  float rstd = rsqrtf(red[1] + 1e-5f);
  int ci = tid * 4;
  ushort4 o;
  o.x = f2bf((v.x - mu) * rstd * gam[ci + 0] + bet[ci + 0]);
  o.y = f2bf((v.y - mu) * rstd * gam[ci + 1] + bet[ci + 1]);
  o.z = f2bf((v.z - mu) * rstd * gam[ci + 2] + bet[ci + 2]);
  o.w = f2bf((v.w - mu) * rstd * gam[ci + 3] + bet[ci + 3]);
  *(ushort4*)&hout[base] = o;
}

// ---- NT GEMM (128x128, 2-phase dbuf): used for the fused QKV projection ---
// T1: XCD-aware block swizzle (nwg = 20*32 = 640, %8==0 -> bijective).
template <int MODE>
__global__ __launch_bounds__(256) void gemm_nt(const u16* __restrict__ A,
                                               const u16* __restrict__ Bt,
                                               int K, int lda, int ldb,
                                               const float* __restrict__ bias,
                                               const float* __restrict__ res,
                                               void* __restrict__ Cout,
                                               void* __restrict__ Cout2, int ldc) {
  __shared__ __align__(16) u16 As0[128 * 32];
  __shared__ __align__(16) u16 Bs0[128 * 32];
  __shared__ __align__(16) u16 As1[128 * 32];
  __shared__ __align__(16) u16 Bs1[128 * 32];
  int tid = threadIdx.x;
  int lane = tid & 63, wid = tid >> 6;
  int wm = wid >> 1, wn = wid & 1;
  int bid = blockIdx.x + gridDim.x * blockIdx.y;
  int nwg = gridDim.x * gridDim.y;
  int swz = (bid & 7) * (nwg >> 3) + (bid >> 3);
  int tbx = swz % gridDim.x, tby = swz / gridDim.x;
  int row0 = tby * 128, col0 = tbx * 128;
  int l15 = lane & 15, g = lane >> 4;
  int srow = lane >> 2, scol = (lane & 3) * 8;
  f32x4 acc[4][4] = {};
  const u16* Ap = A + (size_t)row0 * lda;
  const u16* Bp = Bt + (size_t)col0 * ldb;

  auto STAGE = [&](u16* AS, u16* BS, int kk) {
#pragma unroll
    for (int i = 0; i < 2; ++i) {
      int c = wid * 2 + i;
      gload_lds16(Ap + (size_t)(c * 16 + srow) * lda + kk + scol, &AS[c * 512]);
      gload_lds16(Bp + (size_t)(c * 16 + srow) * ldb + kk + scol, &BS[c * 512]);
    }
  };
  auto COMPUTE = [&](const u16* AS, const u16* BS) {
    bf16x8 af[4], bfr[4];
#pragma unroll
    for (int t = 0; t < 4; ++t) {
      af[t] = *(const bf16x8*)&AS[(wm * 64 + t * 16 + l15) * 32 + g * 8];
      bfr[t] = *(const bf16x8*)&BS[(wn * 64 + t * 16 + l15) * 32 + g * 8];
    }
#pragma unroll
    for (int mt = 0; mt < 4; ++mt)
#pragma unroll
      for (int nt = 0; nt < 4; ++nt)
        acc[mt][nt] = __builtin_amdgcn_mfma_f32_16x16x32_bf16(af[mt], bfr[nt],
                                                              acc[mt][nt], 0, 0, 0);
  };

  STAGE(As0, Bs0, 0);
  __syncthreads();
  for (int k0 = 0; k0 < K; k0 += 64) {
    if (k0 + 32 < K) STAGE(As1, Bs1, k0 + 32);
    COMPUTE(As0, Bs0);
    __syncthreads();
    if (k0 + 64 < K) STAGE(As0, Bs0, k0 + 64);
    COMPUTE(As1, Bs1);
    __syncthreads();
  }

#pragma unroll
  for (int mt = 0; mt < 4; ++mt) {
#pragma unroll
    for (int nt = 0; nt < 4; ++nt) {
      int cc = col0 + wn * 64 + nt * 16 + l15;
      float bv = bias ? bias[cc] : 0.0f;
#pragma unroll
      for (int j = 0; j < 4; ++j) {
        int rr = row0 + wm * 64 + mt * 16 + g * 4 + j;
        float v = acc[mt][nt][j] + bv;
        if (MODE == 1) v = gelu_f(v);
        if (MODE == 2) {
          ((float*)Cout)[(size_t)rr * ldc + cc] = v + res[(size_t)rr * ldc + cc];
        } else {
          ((u16*)Cout)[(size_t)rr * ldc + cc] = f2bf(v);
        }
      }
    }
  }
  (void)Cout2;
}

// ---- gemm8 (R7 schedule): 256x256, BK=64, 2-slot dbuf, stage interleaved ---
// 8 waves (2Mx4N). LDS: 2 slots x (A 32KB + B 32KB) = 128KB dynamic.
// Swizzle (row&7)<<4 both sides (conflicts measured 0).
// Per K-tile: {ds_read kk0 | STAGE_A(next) | 32 MFMA | ds_read kk1 |
// STAGE_B(next) | 32 MFMA | vmcnt(0) | s_barrier}.
// T1: XCD-aware (x,y) swizzle per z-slice (nwg%8==0; z-slices 64-aligned).
// MODE 1: bf16 gelu(v+bias) -> Cb. MODE 4: split-K, ALL z -> bf16 raw
// partials P0..P3 (bias/res/sum applied in reduce2).
template <int MODE>
__global__ __launch_bounds__(512, 2) void gemm8(
    const u16* __restrict__ A, const u16* __restrict__ Bt,
    int lda, int ldb, int nk,
    const float* __restrict__ bias,
    u16* __restrict__ Cb,
    u16* __restrict__ P0, u16* __restrict__ P1,
    u16* __restrict__ P2, u16* __restrict__ P3,
    int ldc) {
  extern __shared__ __align__(16) char smem[];
  int tid = threadIdx.x;
  int lane = tid & 63, wid = tid >> 6;
  int wm = wid >> 2, wn = wid & 3;
  int l15 = lane & 15, g = lane >> 4;
  int bid = blockIdx.x + gridDim.x * blockIdx.y;
  int nwg = gridDim.x * gridDim.y;
  int swz = (bid & 7) * (nwg >> 3) + (bid >> 3);
  int tbx = swz % gridDim.x, tby = swz / gridDim.x;
  int row0 = tby * 256, col0 = tbx * 256;
  int koff = (MODE == 4) ? blockIdx.z * (nk * 64) : 0;
  const u16* Ap = A + (size_t)row0 * lda + koff;
  const u16* Bp = Bt + (size_t)col0 * ldb + koff;
  int trow = tid >> 3;
  int sbyte = ((tid & 7) * 16) ^ ((trow & 7) << 4);
  int xr = (l15 & 7) << 4;

  f32x4 acc[8][4] = {};

  auto STAGE_A = [&](int buf, int kt) {
#pragma unroll
    for (int l = 0; l < 4; ++l)
      gload_lds16((const char*)(Ap + (size_t)(l * 64 + trow) * lda + kt) + sbyte,
                  smem + buf * 65536 + (l * 64 + wid * 8) * 128);
  };
  auto STAGE_B = [&](int buf, int kt) {
#pragma unroll
    for (int l = 0; l < 4; ++l)
      gload_lds16((const char*)(Bp + (size_t)(l * 64 + trow) * ldb + kt) + sbyte,
                  smem + buf * 65536 + 32768 + (l * 64 + wid * 8) * 128);
  };

  STAGE_A(0, 0);
  STAGE_B(0, 0);
  asm volatile("s_waitcnt vmcnt(0)" ::: "memory");
  __builtin_amdgcn_sched_barrier(0);
  __builtin_amdgcn_s_barrier();

  int cur = 0;
  for (int it = 0; it < nk; ++it) {
    const char* Ab = smem + cur * 65536 + (size_t)(wm * 128 + l15) * 128;
    const char* Bb = smem + cur * 65536 + 32768 + (size_t)(wn * 64 + l15) * 128;
    bool nxt = (it + 1 < nk);
#pragma unroll
    for (int kk = 0; kk < 2; ++kk) {
      int kq = (kk * 64 + g * 16) ^ xr;
      bf16x8 bfr[4], af[8];
#pragma unroll
      for (int nt = 0; nt < 4; ++nt)
        bfr[nt] = *(const bf16x8*)(Bb + nt * 2048 + kq);
#pragma unroll
      for (int mt = 0; mt < 8; ++mt)
        af[mt] = *(const bf16x8*)(Ab + mt * 2048 + kq);
      if (nxt) {
        if (kk == 0) STAGE_A(cur ^ 1, (it + 1) * 64);
        else         STAGE_B(cur ^ 1, (it + 1) * 64);
      }
      __builtin_amdgcn_s_setprio(1);
#pragma unroll
      for (int mt = 0; mt < 8; ++mt)
#pragma unroll
        for (int nt = 0; nt < 4; ++nt)
          acc[mt][nt] = __builtin_amdgcn_mfma_f32_16x16x32_bf16(af[mt], bfr[nt],
                                                                acc[mt][nt], 0, 0, 0);
      __builtin_amdgcn_s_setprio(0);
    }
    asm volatile("s_waitcnt vmcnt(0)" ::: "memory");
    __builtin_amdgcn_sched_barrier(0);
    __builtin_amdgcn_s_barrier();
    cur ^= 1;
  }

  u16* pp = Cb;
  if (MODE == 4)
    pp = (blockIdx.z == 0) ? P0
       : (blockIdx.z == 1) ? P1
       : (blockIdx.z == 2) ? P2 : P3;
#pragma unroll
  for (int mt = 0; mt < 8; ++mt) {
#pragma unroll
    for (int nt = 0; nt < 4; ++nt) {
      int cc = col0 + wn * 64 + nt * 16 + l15;
      float bv = (MODE == 1) ? bias[cc] : 0.0f;
#pragma unroll
      for (int j = 0; j < 4; ++j) {
        int rr = row0 + wm * 128 + mt * 16 + g * 4 + j;
        float v = acc[mt][nt][j] + bv;
        if (MODE == 1) {
          pp[(size_t)rr * ldc + cc] = f2bf(gelu_f(v));
        } else {
          pp[(size_t)rr * ldc + cc] = f2bf(v);
        }
      }
    }
  }
}

// ---- split-K reduce: out = p0+p1+p2+p3 (bf16) + b2[col] + x2 (bf16) --------
__global__ __launch_bounds__(256) void reduce2(float* __restrict__ out,
                                               const u16* __restrict__ p0,
                                               const u16* __restrict__ p1,
                                               const u16* __restrict__ p2,
                                               const u16* __restrict__ p3,
                                               const float* __restrict__ b2,
                                               const u16* __restrict__ x2) {
  int i = (blockIdx.x * 256 + threadIdx.x) * 4;
  ushort4 a0 = *(const ushort4*)&p0[i];
  ushort4 a = *(const ushort4*)&p1[i];
  ushort4 b = *(const ushort4*)&p2[i];
  ushort4 c = *(const ushort4*)&p3[i];
  ushort4 r = *(const ushort4*)&x2[i];
  int cix = i & (D_ - 1);
  float4 o;
  o.x = bf2f(a0.x) + bf2f(a.x) + bf2f(b.x) + bf2f(c.x) + b2[cix + 0] + bf2f(r.x);
  o.y = bf2f(a0.y) + bf2f(a.y) + bf2f(b.y) + bf2f(c.y) + b2[cix + 1] + bf2f(r.y);
  o.z = bf2f(a0.z) + bf2f(a.z) + bf2f(b.z) + bf2f(c.z) + b2[cix + 2] + bf2f(r.z);
  o.w = bf2f(a0.w) + bf2f(a.w) + bf2f(b.w) + bf2f(c.w) + b2[cix + 3] + bf2f(r.w);
  *(float4*)&out[i] = o;
}

// ---- low-rank V up-proj -> V^T [b,h][e][t] bf16 ----------------------------
__global__ __launch_bounds__(256) void vu_kernel(const u16* __restrict__ vd,
                                                 const u16* __restrict__ wvu,
                                                 const float* __restrict__ bvu,
                                                 u16* __restrict__ v_t) {
  int t0 = blockIdx.x * 64, h = blockIdx.y, b = blockIdx.z;
  __shared__ u16 vds[64][32];
  __shared__ u16 vt[64][65];
  int tid = threadIdx.x;
  {
    int rr2 = tid >> 2, c8 = (tid & 3) * 8;
    *(bf16x8*)&vds[rr2][c8] =
        *(const bf16x8*)&vd[(size_t)(b * S_ + t0 + rr2) * NQKV + 2048 + h * R_ + c8];
  }
  __syncthreads();
  int e = tid & 63, tg = (tid >> 6) * 16;
  float wcol[32];
#pragma unroll
  for (int r = 0; r < 32; ++r) wcol[r] = bf2f(wvu[((size_t)h * R_ + r) * HD_ + e]);
  float bb = bvu[h * HD_ + e];
  for (int i = 0; i < 16; ++i) {
    int t = tg + i;
    float acc = bb;
#pragma unroll
    for (int r = 0; r < 32; ++r) acc += bf2f(vds[t][r]) * wcol[r];
    vt[t][e] = f2bf(acc);
  }
  __syncthreads();
  for (int idx = tid; idx < 64 * 64; idx += 256) {
    int e2 = idx >> 6, t2 = idx & 63;
    v_t[((size_t)(b * H_ + h) * HD_ + e2) * S_ + t0 + t2] = vt[t2][e2];
  }
}

// ---- attention v4 (R11-verified): reversed-causal (key t >= query s) -------
// grid (H, B, 8). 8 waves, QBLK=128 triangle-paired (uniform 34 steps).
// Counted-vmcnt 3-buffer ring: one s_barrier + vmcnt(2) per step (vmcnt(0)
// last), STAGE(it+2) after the barrier. Output stored bf16.
__global__ __launch_bounds__(512, 2) void attn_kernel(const u16* __restrict__ cqkv,
                                                      const u16* __restrict__ v_t,
                                                      u16* __restrict__ o) {
  extern __shared__ __align__(16) u16 kv[];  // 3 bufs x (K 4096 + V 4096) u16
  __shared__ u16 Pl[8][16 * 64];             // per-wave Q then P^T tile
  int tid = threadIdx.x;
  int lane = tid & 63, w = tid >> 6;
  int h = blockIdx.x, b = blockIdx.y;
  int bx = blockIdx.z;
  int r = lane & 15, g = lane >> 4;
  const u16* qp = cqkv + (size_t)(b * S_) * NQKV + h * HD_;
  const u16* kp = cqkv + (size_t)(b * S_) * NQKV + 1024 + h * HD_;
  const u16* vp = v_t + (size_t)(b * H_ + h) * HD_ * S_;
  u16* Pw = Pl[w];

  int srow = w * 8 + (lane >> 3);
  int ssw = ((lane & 7) * 16) ^ (((lane >> 3) & 7) << 4);  // pre-swz byte in row

  int xr = (r & 7) << 4;                // read-side XOR (rows = ..*16 + r)
  int kq0 = ((g * 16) ^ xr) >> 1;       // elem offset, k-group 0
  int kq1 = ((64 + g * 16) ^ xr) >> 1;  // elem offset, k-group 1

  auto STAGE = [&](int buf, int kt) {
    u16* base = kv + buf * 8192;
    gload_lds16((const char*)(kp + (size_t)(kt + srow) * NQKV) + ssw,
                base + w * 512);
    gload_lds16((const char*)(vp + (size_t)srow * S_ + kt) + ssw,
                base + 4096 + w * 512);
  };

#pragma unroll 1
  for (int half = 0; half < 2; ++half) {
    int qb = half ? (S_ - 128) - bx * 128 : bx * 128;
    int s0 = qb + w * 16;
    int qrow = s0 + r;

    gload_lds16((const char*)(qp + (size_t)(s0 + (lane >> 3)) * NQKV) + ssw, Pw);
    gload_lds16((const char*)(qp + (size_t)(s0 + 8 + (lane >> 3)) * NQKV) + ssw,
                Pw + 512);
    asm volatile("s_waitcnt vmcnt(0)" ::: "memory");
    __builtin_amdgcn_sched_barrier(0);
    __builtin_amdgcn_s_barrier();
    __builtin_amdgcn_sched_barrier(0);
    bf16x8 aq0 = *(const bf16x8*)&Pw[(r << 6) + kq0];
    bf16x8 aq1 = *(const bf16x8*)&Pw[(r << 6) + kq1];

    f32x4 oa[4] = {};
    float m_ = -1e30f, l_ = 0.0f;

    int nt = (S_ - qb) >> 6;
    STAGE(0, qb);
    STAGE(1, qb + 64);

    for (int it = 0; it < nt; ++it) {
      int kt = qb + it * 64;
      if (it + 1 < nt) {
        asm volatile("s_waitcnt vmcnt(2)" ::: "memory");
      } else {
        asm volatile("s_waitcnt vmcnt(0)" ::: "memory");
      }
      __builtin_amdgcn_sched_barrier(0);
      __builtin_amdgcn_s_barrier();
      __builtin_amdgcn_sched_barrier(0);
      if (it + 2 < nt) STAGE((it + 2) % 3, qb + (it + 2) * 64);

      if (kt + 64 > s0) {
        const u16* Kb = kv + (it % 3) * 8192;
        const u16* Vb = Kb + 4096;

        f32x4 sc[4] = {};
#pragma unroll
        for (int blk = 0; blk < 4; ++blk) {
          bf16x8 a0 = *(const bf16x8*)&Kb[((blk * 16 + r) << 6) + kq0];
          bf16x8 a1 = *(const bf16x8*)&Kb[((blk * 16 + r) << 6) + kq1];
          sc[blk] = __builtin_amdgcn_mfma_f32_16x16x32_bf16(a0, aq0, sc[blk], 0, 0, 0);
          sc[blk] = __builtin_amdgcn_mfma_f32_16x16x32_bf16(a1, aq1, sc[blk], 0, 0, 0);
        }

        float p[16];
        if ((qrow & ~63) == kt) {
#pragma unroll
          for (int blk = 0; blk < 4; ++blk)
#pragma unroll
            for (int j = 0; j < 4; ++j) {
              int kk = kt + blk * 16 + g * 4 + j;
              p[blk * 4 + j] = (kk < qrow) ? -1e30f : sc[blk][j];
            }
        } else {
#pragma unroll
          for (int blk = 0; blk < 4; ++blk)
#pragma unroll
            for (int j = 0; j < 4; ++j) p[blk * 4 + j] = sc[blk][j];
        }
        float mx = p[0];
#pragma unroll
        for (int i = 1; i < 16; ++i) mx = fmaxf(mx, p[i]);
        mx = fmaxf(mx, __shfl_xor(mx, 16));
        mx = fmaxf(mx, __shfl_xor(mx, 32));
        float mn = fmaxf(m_, mx);
        float scl = __builtin_amdgcn_exp2f(m_ - mn);
        m_ = mn;
        float sm = 0.0f;
#pragma unroll
        for (int i = 0; i < 16; ++i) {
          p[i] = __builtin_amdgcn_exp2f(p[i] - mn);
          sm += p[i];
        }
        sm += __shfl_xor(sm, 16);
        sm += __shfl_xor(sm, 32);
        l_ = l_ * scl + sm;
#pragma unroll
        for (int et = 0; et < 4; ++et) oa[et] *= scl;

#pragma unroll
        for (int blk = 0; blk < 4; ++blk) {
          uint2 pk;
          pk.x = pk_bf16(p[blk * 4 + 0], p[blk * 4 + 1]);
          pk.y = pk_bf16(p[blk * 4 + 2], p[blk * 4 + 3]);
          *(uint2*)&Pw[(r << 6) + ((((blk << 5) + (g << 3)) ^ xr) >> 1)] = pk;
        }
        asm volatile("s_waitcnt lgkmcnt(0)" ::: "memory");
        __builtin_amdgcn_sched_barrier(0);
        bf16x8 pb0 = *(const bf16x8*)&Pw[(r << 6) + kq0];
        bf16x8 pb1 = *(const bf16x8*)&Pw[(r << 6) + kq1];
#pragma unroll
        for (int et = 0; et < 4; ++et) {
          bf16x8 v0 = *(const bf16x8*)&Vb[((et * 16 + r) << 6) + kq0];
          bf16x8 v1 = *(const bf16x8*)&Vb[((et * 16 + r) << 6) + kq1];
          oa[et] = __builtin_amdgcn_mfma_f32_16x16x32_bf16(v0, pb0, oa[et], 0, 0, 0);
          oa[et] = __builtin_amdgcn_mfma_f32_16x16x32_bf16(v1, pb1, oa[et], 0, 0, 0);
        }
      }
    }

    float inv = 1.0f / l_;
#pragma unroll
    for (int et = 0; et < 4; ++et)
#pragma unroll
      for (int j = 0; j < 4; ++j)
        o[(size_t)(b * S_ + s0 + r) * D_ + h * HD_ + et * 16 + g * 4 + j] =
            f2bf(oa[et][j] * inv);
  }
}

// one-time (dlopen) LDS-limit raise for dynamic-shared kernels
namespace {
struct GemmAttrInit {
  GemmAttrInit() {
    hipFuncSetAttribute((const void*)gemm8<1>,
                        hipFuncAttributeMaxDynamicSharedMemorySize, 131072);
    hipFuncSetAttribute((const void*)gemm8<4>,
                        hipFuncAttributeMaxDynamicSharedMemorySize, 131072);
    hipFuncSetAttribute((const void*)attn_kernel,
                        hipFuncAttributeMaxDynamicSharedMemorySize, 49152);
  }
};
GemmAttrInit _gemm_attr_init;
}  // namespace

extern "C" void kernel_launch(void* const* d_in, const int* in_sizes, int n_in,
                              void* d_out, int out_size, void* d_ws, size_t ws_size,
                              hipStream_t stream) {
  const float* x = (const float*)d_in[0];
  const float* ln1_g = (const float*)d_in[1];
  const float* ln1_b = (const float*)d_in[2];
  const float* Wq = (const float*)d_in[3];
  const float* bq = (const float*)d_in[4];
  const float* Wk = (const float*)d_in[5];
  const float* bk = (const float*)d_in[6];
  const float* Wvd = (const float*)d_in[7];
  const float* bvd = (const float*)d_in[8];
  const float* Wvu = (const float*)d_in[9];
  const float* bvu = (const float*)d_in[10];
  const float* ln2_g = (const float*)d_in[11];
  const float* ln2_b = (const float*)d_in[12];
  const float* W1 = (const float*)d_in[13];
  const float* b1 = (const float*)d_in[14];
  const float* W2 = (const float*)d_in[15];
  const float* b2 = (const float*)d_in[16];
  float* out = (float*)d_out;
  (void)in_sizes; (void)n_in; (void)out_size; (void)ws_size;

  char* ws = (char*)d_ws;
  const size_t MB = 1024 * 1024;
  const size_t KB = 1024;
  u16* wqkvT = (u16*)(ws + 0);                    // [2560x1024] bf16, 5 MB
  u16* wvuB = (u16*)(ws + 5 * MB);                // 64 KB
  float* bqkv = (float*)(ws + 5 * MB + 64 * KB);  // 10 KB
  u16* w1T = (u16*)(ws + 5 * MB + 384 * KB);      // 8 MB -> 13.375
  u16* w2T = (u16*)(ws + 13 * MB + 384 * KB);     // 8 MB -> 21.375
  u16* hbuf = (u16*)(ws + 21 * MB + 384 * KB);    // 8 MB -> 29.375
  u16* cqkv = (u16*)(ws + 29 * MB + 384 * KB);    // 20 MB -> 49.375
  u16* vT = (u16*)(ws + 49 * MB + 384 * KB);      // 8 MB -> 57.375
  u16* ob16 = (u16*)(ws + 57 * MB + 384 * KB);    // 8 MB (bf16) -> 65.375
  u16* p3 = (u16*)(ws + 65 * MB + 384 * KB);      // 8 MB -> 73.375 (OUTSIDE ubuf)
  u16* x2 = (u16*)(ws + 73 * MB + 384 * KB);      // 8 MB (bf16) -> 81.375
  u16* p0 = (u16*)(ws + 81 * MB + 384 * KB);      // 8 MB -> 89.375
  // lifetime-disjoint reuses:
  u16* ubuf = cqkv;            // 32 MB (29.375-61.375: cqkv+vT+ob16[0:4MB]), dead by FFN1
  u16* p1 = (u16*)(ws + 0);    // 8 MB over wqkvT+..., dead by FFN2
  u16* p2 = (u16*)hbuf;        // 8 MB, hbuf dead after FFN1

  dim3 blk(256);
  wtrans<<<dim3(2, 32, 16), blk, 0, stream>>>(Wq, wqkvT, 1024, 64, 65536L, 65536L, C2F);
  wtrans<<<dim3(2, 32, 16), blk, 0, stream>>>(Wk, wqkvT + 1024 * 1024, 1024, 64,
                                              65536L, 65536L, 1.0f);
  wtrans<<<dim3(1, 32, 16), blk, 0, stream>>>(Wvd, wqkvT + 2048 * 1024, 1024, 32,
                                              32768L, 32768L, 1.0f);
  wconv<<<dim3(32), blk, 0, stream>>>(Wvu, wvuB, H_ * R_ * HD_);
  bconcat<<<dim3(10), blk, 0, stream>>>(bq, bk, bvd, bqkv);
  wtrans<<<dim3(128, 32, 1), blk, 0, stream>>>(W1, w1T, 1024, 4096, 0L, 0L, 1.0f);
  wtrans<<<dim3(32, 128, 1), blk, 0, stream>>>(W2, w2T, 4096, 1024, 0L, 0L, 1.0f);
  ln_kernel<<<dim3(M_), blk, 0, stream>>>(x, (const u16*)nullptr, ln1_g, ln1_b,
                                          hbuf, (u16*)nullptr);
  // fused QKV projection (2-phase 128² — 640 blocks, 2.5/CU, T1-swizzled)
  gemm_nt<0><<<dim3(20, 32), blk, 0, stream>>>(hbuf, wqkvT, 1024, 1024, 1024, bqkv,
                                               (const float*)nullptr, (void*)cqkv,
                                               (void*)nullptr, NQKV);
  vu_kernel<<<dim3(S_ / 64, H_, B_), blk, 0, stream>>>(cqkv, wvuB, bvu, vT);
  // attention v4: grid (H, B, 8), 512 threads, 48KB dynamic LDS; bf16 out
  attn_kernel<<<dim3(H_, B_, 8), dim3(512), 49152, stream>>>(cqkv, vT, ob16);
  ln_kernel<<<dim3(M_), blk, 0, stream>>>(x, ob16, ln2_g, ln2_b, hbuf, x2);
  // FFN1: 256² R7 pipeline, grid 16x16 = 1 block/CU, T1-swizzled
  gemm8<1><<<dim3(16, 16, 1), dim3(512), 131072, stream>>>(
      hbuf, w1T, 1024, 1024, 16, b1, ubuf,
      (u16*)nullptr, (u16*)nullptr, (u16*)nullptr, (u16*)nullptr, 4096);
  // FFN2: split-K=4, grid 4x16x4, T1-swizzled per z; all z -> bf16 partials
  gemm8<4><<<dim3(4, 16, 4), dim3(512), 131072, stream>>>(
      ubuf, w2T, 4096, 4096, 16, (const float*)nullptr, (u16*)nullptr,
      p0, p1, p2, p3, 1024);
  // out = p0+p1+p2+p3 + b2 + x2
  reduce2<<<dim3(M_ * D_ / 1024), blk, 0, stream>>>(out, p0, p1, p2, p3, b2, x2);
}

// Round 21
// 218.172 us; speedup vs baseline: 1.1111x; 1.0219x over previous
//
#include <hip/hip_runtime.h>

// ---------------------------------------------------------------------------
// TransformerBlock: LN1 -> QKV proj (fused) -> reversed-causal attention
// (scale 1/sqrt(D)=1/32) -> residual -> LN2 -> GELU FFN -> residual.
// B=2 S=2048 D=1024 H=16 HD=64 R=32 F=4096. All d_in/d_out fp32; internal
// compute bf16 MFMA.
// R20: (1) T13 defer-max in attention (skip O-rescale while per-step max
// growth <= 8 in exp2 domain; P bounded by 2^8, f32 accum tolerant);
// (2) prologue merge: Wq/Wk/Wvd transposes -> one launch, wconv+bconcat ->
// one launch (7 -> 4 prologue launches). Rest = R20 verified composite.
// ---------------------------------------------------------------------------

typedef unsigned short u16;
typedef __attribute__((ext_vector_type(4))) float f32x4;
typedef __attribute__((ext_vector_type(8))) __bf16 bf16x8;

#define B_ 2
#define S_ 2048
#define D_ 1024
#define H_ 16
#define HD_ 64
#define R_ 32
#define F_ 4096
#define M_ (B_ * S_)   // 4096 rows
#define NQKV 2560      // 1024 q + 1024 k + 512 vd
// (1/sqrt(D)) * log2(e): folded into Wq/bq so QK^T scores are exp2-ready
#define C2F 0.04508422002778011f

__device__ __forceinline__ u16 f2bf(float f) {
  union { float f; unsigned u; } v; v.f = f;
  unsigned u = v.u;
  return (u16)((u + 0x7FFFu + ((u >> 16) & 1u)) >> 16);  // RNE
}
__device__ __forceinline__ float bf2f(u16 h) {
  union { unsigned u; float f; } v; v.u = ((unsigned)h) << 16;
  return v.f;
}
__device__ __forceinline__ unsigned pk_bf16(float lo, float hi) {
  unsigned r;
  asm volatile("v_cvt_pk_bf16_f32 %0, %1, %2" : "=v"(r) : "v"(lo), "v"(hi));
  return r;
}

typedef __attribute__((address_space(1))) void gvoid;
typedef __attribute__((address_space(3))) void lvoid;
// async global->LDS, 16B/lane; lds base must be wave-uniform (lane*16 implicit)
__device__ __forceinline__ void gload_lds16(const void* g, void* l) {
  __builtin_amdgcn_global_load_lds((gvoid*)(void*)g, (lvoid*)l, 16, 0, 0);
}

__device__ __forceinline__ float gelu_f(float x) {
  float t = tanhf(0.7978845608028654f * (x + 0.044715f * x * x * x));
  return 0.5f * x * (1.0f + t);
}

// ---- fp32 [Rr,Cc] (batched) -> bf16 transposed [Cc,Rr], optional scale ----
__global__ __launch_bounds__(256) void wtrans(const float* __restrict__ in,
                                              u16* __restrict__ out,
                                              int Rr, int Cc, long ibs, long obs,
                                              float scale) {
  __shared__ float tile[32][33];
  const float* ip = in + (size_t)blockIdx.z * ibs;
  u16* op = out + (size_t)blockIdx.z * obs;
  int c0 = blockIdx.x * 32, r0 = blockIdx.y * 32;
  int tx = threadIdx.x & 31, ty = threadIdx.x >> 5;  // 32 x 8
#pragma unroll
  for (int j = 0; j < 32; j += 8)
    tile[ty + j][tx] = ip[(size_t)(r0 + ty + j) * Cc + c0 + tx];
  __syncthreads();
#pragma unroll
  for (int j = 0; j < 32; j += 8)
    op[(size_t)(c0 + ty + j) * Rr + r0 + tx] = f2bf(tile[tx][ty + j] * scale);
}

// ---- merged QKV weight transpose: grid (2, 32, 48) ------------------------
// z<16: Wq head z (scale C2F); z<32: Wk head z-16; z>=32: Wvd head z-32
// (Cc=32, only blockIdx.x==0 active).
__global__ __launch_bounds__(256) void wtrans_qkv(const float* __restrict__ Wq,
                                                  const float* __restrict__ Wk,
                                                  const float* __restrict__ Wvd,
                                                  u16* __restrict__ wqkvT) {
  __shared__ float tile[32][33];
  int z = blockIdx.z;
  const float* ip;
  u16* op;
  int Cc;
  float scale;
  if (z < 16) {
    ip = Wq + (size_t)z * 65536;
    op = wqkvT + (size_t)z * 65536;
    Cc = 64; scale = C2F;
  } else if (z < 32) {
    ip = Wk + (size_t)(z - 16) * 65536;
    op = wqkvT + 1048576 + (size_t)(z - 16) * 65536;
    Cc = 64; scale = 1.0f;
  } else {
    if (blockIdx.x != 0) return;
    ip = Wvd + (size_t)(z - 32) * 32768;
    op = wqkvT + 2097152 + (size_t)(z - 32) * 32768;
    Cc = 32; scale = 1.0f;
  }
  int c0 = blockIdx.x * 32, r0 = blockIdx.y * 32;
  int tx = threadIdx.x & 31, ty = threadIdx.x >> 5;  // 32 x 8
#pragma unroll
  for (int j = 0; j < 32; j += 8)
    tile[ty + j][tx] = ip[(size_t)(r0 + ty + j) * Cc + c0 + tx];
  __syncthreads();
#pragma unroll
  for (int j = 0; j < 32; j += 8)
    op[(size_t)(c0 + ty + j) * 1024 + r0 + tx] = f2bf(tile[tx][ty + j] * scale);
}

// ---- merged: wconv(Wvu->bf16, 32 blocks) + bconcat (10 blocks) -------------
__global__ __launch_bounds__(256) void wconv_bconcat(const float* __restrict__ Wvu,
                                                     u16* __restrict__ wvuB,
                                                     const float* __restrict__ bq,
                                                     const float* __restrict__ bk,
                                                     const float* __restrict__ bvd,
                                                     float* __restrict__ bqkv) {
  int bid = blockIdx.x;
  if (bid < 32) {
    int i = (bid * 256 + threadIdx.x) * 4;
    if (i < H_ * R_ * HD_) {
      float4 v = *(const float4*)&Wvu[i];
      ushort4 o;
      o.x = f2bf(v.x); o.y = f2bf(v.y); o.z = f2bf(v.z); o.w = f2bf(v.w);
      *(ushort4*)&wvuB[i] = o;
    }
  } else {
    int i = (bid - 32) * 256 + threadIdx.x;
    if (i < NQKV) {
      float v = (i < 1024) ? bq[i] * C2F : (i < 2048 ? bk[i - 1024] : bvd[i - 2048]);
      bqkv[i] = v;
    }
  }
}

// ---- LayerNorm (optional bf16 residual addin + bf16 x2 passthrough) --------
__global__ __launch_bounds__(256) void ln_kernel(const float* __restrict__ xin,
                                                 const u16* __restrict__ addin,
                                                 const float* __restrict__ gam,
                                                 const float* __restrict__ bet,
                                                 u16* __restrict__ hout,
                                                 u16* __restrict__ x2out) {
  int row = blockIdx.x, tid = threadIdx.x;
  size_t base = (size_t)row * D_ + tid * 4;
  float4 v = *(const float4*)&xin[base];
  if (addin) {
    ushort4 a = *(const ushort4*)&addin[base];
    v.x += bf2f(a.x); v.y += bf2f(a.y); v.z += bf2f(a.z); v.w += bf2f(a.w);
  }
  if (x2out) {
    ushort4 xo;
    xo.x = f2bf(v.x); xo.y = f2bf(v.y); xo.z = f2bf(v.z); xo.w = f2bf(v.w);
    *(ushort4*)&x2out[base] = xo;
  }
  float s = v.x + v.y + v.z + v.w;
  float ss = v.x * v.x + v.y * v.y + v.z * v.z + v.w * v.w;
#pragma unroll
  for (int off = 32; off > 0; off >>= 1) {
    s += __shfl_down(s, off);
    ss += __shfl_down(ss, off);
  }
  __shared__ float red[8];
  int wv = tid >> 6;
  if ((tid & 63) == 0) { red[wv] = s; red[4 + wv] = ss; }
  __syncthreads();
  if (tid == 0) {
    float s1 = red[0] + red[1] + red[2] + red[3];
    float s2 = red[4] + red[5] + red[6] + red[7];
    float mu = s1 * (1.0f / D_);
    red[0] = mu;
    red[1] = s2 * (1.0f / D_) - mu * mu;
  }
  __syncthreads();
  float mu = red[0];
  float rstd = rsqrtf(red[1] + 1e-5f);
  int ci = tid * 4;
  ushort4 o;
  o.x = f2bf((v.x - mu) * rstd * gam[ci + 0] + bet[ci + 0]);
  o.y = f2bf((v.y - mu) * rstd * gam[ci + 1] + bet[ci + 1]);
  o.z = f2bf((v.z - mu) * rstd * gam[ci + 2] + bet[ci + 2]);
  o.w = f2bf((v.w - mu) * rstd * gam[ci + 3] + bet[ci + 3]);
  *(ushort4*)&hout[base] = o;
}

// ---- NT GEMM (128x128, 2-phase dbuf): used for the fused QKV projection ---
// T1: XCD-aware block swizzle (nwg = 20*32 = 640, %8==0 -> bijective).
template <int MODE>
__global__ __launch_bounds__(256) void gemm_nt(const u16* __restrict__ A,
                                               const u16* __restrict__ Bt,
                                               int K, int lda, int ldb,
                                               const float* __restrict__ bias,
                                               const float* __restrict__ res,
                                               void* __restrict__ Cout,
                                               void* __restrict__ Cout2, int ldc) {
  __shared__ __align__(16) u16 As0[128 * 32];
  __shared__ __align__(16) u16 Bs0[128 * 32];
  __shared__ __align__(16) u16 As1[128 * 32];
  __shared__ __align__(16) u16 Bs1[128 * 32];
  int tid = threadIdx.x;
  int lane = tid & 63, wid = tid >> 6;
  int wm = wid >> 1, wn = wid & 1;
  int bid = blockIdx.x + gridDim.x * blockIdx.y;
  int nwg = gridDim.x * gridDim.y;
  int swz = (bid & 7) * (nwg >> 3) + (bid >> 3);
  int tbx = swz % gridDim.x, tby = swz / gridDim.x;
  int row0 = tby * 128, col0 = tbx * 128;
  int l15 = lane & 15, g = lane >> 4;
  int srow = lane >> 2, scol = (lane & 3) * 8;
  f32x4 acc[4][4] = {};
  const u16* Ap = A + (size_t)row0 * lda;
  const u16* Bp = Bt + (size_t)col0 * ldb;

  auto STAGE = [&](u16* AS, u16* BS, int kk) {
#pragma unroll
    for (int i = 0; i < 2; ++i) {
      int c = wid * 2 + i;
      gload_lds16(Ap + (size_t)(c * 16 + srow) * lda + kk + scol, &AS[c * 512]);
      gload_lds16(Bp + (size_t)(c * 16 + srow) * ldb + kk + scol, &BS[c * 512]);
    }
  };
  auto COMPUTE = [&](const u16* AS, const u16* BS) {
    bf16x8 af[4], bfr[4];
#pragma unroll
    for (int t = 0; t < 4; ++t) {
      af[t] = *(const bf16x8*)&AS[(wm * 64 + t * 16 + l15) * 32 + g * 8];
      bfr[t] = *(const bf16x8*)&BS[(wn * 64 + t * 16 + l15) * 32 + g * 8];
    }
#pragma unroll
    for (int mt = 0; mt < 4; ++mt)
#pragma unroll
      for (int nt = 0; nt < 4; ++nt)
        acc[mt][nt] = __builtin_amdgcn_mfma_f32_16x16x32_bf16(af[mt], bfr[nt],
                                                              acc[mt][nt], 0, 0, 0);
  };

  STAGE(As0, Bs0, 0);
  __syncthreads();
  for (int k0 = 0; k0 < K; k0 += 64) {
    if (k0 + 32 < K) STAGE(As1, Bs1, k0 + 32);
    COMPUTE(As0, Bs0);
    __syncthreads();
    if (k0 + 64 < K) STAGE(As0, Bs0, k0 + 64);
    COMPUTE(As1, Bs1);
    __syncthreads();
  }

#pragma unroll
  for (int mt = 0; mt < 4; ++mt) {
#pragma unroll
    for (int nt = 0; nt < 4; ++nt) {
      int cc = col0 + wn * 64 + nt * 16 + l15;
      float bv = bias ? bias[cc] : 0.0f;
#pragma unroll
      for (int j = 0; j < 4; ++j) {
        int rr = row0 + wm * 64 + mt * 16 + g * 4 + j;
        float v = acc[mt][nt][j] + bv;
        if (MODE == 1) v = gelu_f(v);
        if (MODE == 2) {
          ((float*)Cout)[(size_t)rr * ldc + cc] = v + res[(size_t)rr * ldc + cc];
        } else {
          ((u16*)Cout)[(size_t)rr * ldc + cc] = f2bf(v);
        }
      }
    }
  }
  (void)Cout2;
}

// ---- gemm8 (R7 schedule): 256x256, BK=64, 2-slot dbuf, stage interleaved ---
// MODE 1: bf16 gelu(v+bias) -> Cb. MODE 4: split-K, all z -> bf16 partials.
template <int MODE>
__global__ __launch_bounds__(512, 2) void gemm8(
    const u16* __restrict__ A, const u16* __restrict__ Bt,
    int lda, int ldb, int nk,
    const float* __restrict__ bias,
    u16* __restrict__ Cb,
    u16* __restrict__ P0, u16* __restrict__ P1,
    u16* __restrict__ P2, u16* __restrict__ P3,
    int ldc) {
  extern __shared__ __align__(16) char smem[];
  int tid = threadIdx.x;
  int lane = tid & 63, wid = tid >> 6;
  int wm = wid >> 2, wn = wid & 3;
  int l15 = lane & 15, g = lane >> 4;
  int bid = blockIdx.x + gridDim.x * blockIdx.y;
  int nwg = gridDim.x * gridDim.y;
  int swz = (bid & 7) * (nwg >> 3) + (bid >> 3);
  int tbx = swz % gridDim.x, tby = swz / gridDim.x;
  int row0 = tby * 256, col0 = tbx * 256;
  int koff = (MODE == 4) ? blockIdx.z * (nk * 64) : 0;
  const u16* Ap = A + (size_t)row0 * lda + koff;
  const u16* Bp = Bt + (size_t)col0 * ldb + koff;
  int trow = tid >> 3;
  int sbyte = ((tid & 7) * 16) ^ ((trow & 7) << 4);
  int xr = (l15 & 7) << 4;

  f32x4 acc[8][4] = {};

  auto STAGE_A = [&](int buf, int kt) {
#pragma unroll
    for (int l = 0; l < 4; ++l)
      gload_lds16((const char*)(Ap + (size_t)(l * 64 + trow) * lda + kt) + sbyte,
                  smem + buf * 65536 + (l * 64 + wid * 8) * 128);
  };
  auto STAGE_B = [&](int buf, int kt) {
#pragma unroll
    for (int l = 0; l < 4; ++l)
      gload_lds16((const char*)(Bp + (size_t)(l * 64 + trow) * ldb + kt) + sbyte,
                  smem + buf * 65536 + 32768 + (l * 64 + wid * 8) * 128);
  };

  STAGE_A(0, 0);
  STAGE_B(0, 0);
  asm volatile("s_waitcnt vmcnt(0)" ::: "memory");
  __builtin_amdgcn_sched_barrier(0);
  __builtin_amdgcn_s_barrier();

  int cur = 0;
  for (int it = 0; it < nk; ++it) {
    const char* Ab = smem + cur * 65536 + (size_t)(wm * 128 + l15) * 128;
    const char* Bb = smem + cur * 65536 + 32768 + (size_t)(wn * 64 + l15) * 128;
    bool nxt = (it + 1 < nk);
#pragma unroll
    for (int kk = 0; kk < 2; ++kk) {
      int kq = (kk * 64 + g * 16) ^ xr;
      bf16x8 bfr[4], af[8];
#pragma unroll
      for (int nt = 0; nt < 4; ++nt)
        bfr[nt] = *(const bf16x8*)(Bb + nt * 2048 + kq);
#pragma unroll
      for (int mt = 0; mt < 8; ++mt)
        af[mt] = *(const bf16x8*)(Ab + mt * 2048 + kq);
      if (nxt) {
        if (kk == 0) STAGE_A(cur ^ 1, (it + 1) * 64);
        else         STAGE_B(cur ^ 1, (it + 1) * 64);
      }
      __builtin_amdgcn_s_setprio(1);
#pragma unroll
      for (int mt = 0; mt < 8; ++mt)
#pragma unroll
        for (int nt = 0; nt < 4; ++nt)
          acc[mt][nt] = __builtin_amdgcn_mfma_f32_16x16x32_bf16(af[mt], bfr[nt],
                                                                acc[mt][nt], 0, 0, 0);
      __builtin_amdgcn_s_setprio(0);
    }
    asm volatile("s_waitcnt vmcnt(0)" ::: "memory");
    __builtin_amdgcn_sched_barrier(0);
    __builtin_amdgcn_s_barrier();
    cur ^= 1;
  }

  u16* pp = Cb;
  if (MODE == 4)
    pp = (blockIdx.z == 0) ? P0
       : (blockIdx.z == 1) ? P1
       : (blockIdx.z == 2) ? P2 : P3;
#pragma unroll
  for (int mt = 0; mt < 8; ++mt) {
#pragma unroll
    for (int nt = 0; nt < 4; ++nt) {
      int cc = col0 + wn * 64 + nt * 16 + l15;
      float bv = (MODE == 1) ? bias[cc] : 0.0f;
#pragma unroll
      for (int j = 0; j < 4; ++j) {
        int rr = row0 + wm * 128 + mt * 16 + g * 4 + j;
        float v = acc[mt][nt][j] + bv;
        if (MODE == 1) {
          pp[(size_t)rr * ldc + cc] = f2bf(gelu_f(v));
        } else {
          pp[(size_t)rr * ldc + cc] = f2bf(v);
        }
      }
    }
  }
}

// ---- split-K reduce: out = p0+p1+p2+p3 (bf16) + b2[col] + x2 (bf16) --------
__global__ __launch_bounds__(256) void reduce2(float* __restrict__ out,
                                               const u16* __restrict__ p0,
                                               const u16* __restrict__ p1,
                                               const u16* __restrict__ p2,
                                               const u16* __restrict__ p3,
                                               const float* __restrict__ b2,
                                               const u16* __restrict__ x2) {
  int i = (blockIdx.x * 256 + threadIdx.x) * 4;
  ushort4 a0 = *(const ushort4*)&p0[i];
  ushort4 a = *(const ushort4*)&p1[i];
  ushort4 b = *(const ushort4*)&p2[i];
  ushort4 c = *(const ushort4*)&p3[i];
  ushort4 r = *(const ushort4*)&x2[i];
  int cix = i & (D_ - 1);
  float4 o;
  o.x = bf2f(a0.x) + bf2f(a.x) + bf2f(b.x) + bf2f(c.x) + b2[cix + 0] + bf2f(r.x);
  o.y = bf2f(a0.y) + bf2f(a.y) + bf2f(b.y) + bf2f(c.y) + b2[cix + 1] + bf2f(r.y);
  o.z = bf2f(a0.z) + bf2f(a.z) + bf2f(b.z) + bf2f(c.z) + b2[cix + 2] + bf2f(r.z);
  o.w = bf2f(a0.w) + bf2f(a.w) + bf2f(b.w) + bf2f(c.w) + b2[cix + 3] + bf2f(r.w);
  *(float4*)&out[i] = o;
}

// ---- low-rank V up-proj -> V^T [b,h][e][t] bf16 ----------------------------
__global__ __launch_bounds__(256) void vu_kernel(const u16* __restrict__ vd,
                                                 const u16* __restrict__ wvu,
                                                 const float* __restrict__ bvu,
                                                 u16* __restrict__ v_t) {
  int t0 = blockIdx.x * 64, h = blockIdx.y, b = blockIdx.z;
  __shared__ u16 vds[64][32];
  __shared__ u16 vt[64][65];
  int tid = threadIdx.x;
  {
    int rr2 = tid >> 2, c8 = (tid & 3) * 8;
    *(bf16x8*)&vds[rr2][c8] =
        *(const bf16x8*)&vd[(size_t)(b * S_ + t0 + rr2) * NQKV + 2048 + h * R_ + c8];
  }
  __syncthreads();
  int e = tid & 63, tg = (tid >> 6) * 16;
  float wcol[32];
#pragma unroll
  for (int r = 0; r < 32; ++r) wcol[r] = bf2f(wvu[((size_t)h * R_ + r) * HD_ + e]);
  float bb = bvu[h * HD_ + e];
  for (int i = 0; i < 16; ++i) {
    int t = tg + i;
    float acc = bb;
#pragma unroll
    for (int r = 0; r < 32; ++r) acc += bf2f(vds[t][r]) * wcol[r];
    vt[t][e] = f2bf(acc);
  }
  __syncthreads();
  for (int idx = tid; idx < 64 * 64; idx += 256) {
    int e2 = idx >> 6, t2 = idx & 63;
    v_t[((size_t)(b * H_ + h) * HD_ + e2) * S_ + t0 + t2] = vt[t2][e2];
  }
}

// ---- attention v4 + T13 defer-max: reversed-causal (key t >= query s) ------
// grid (H, B, 8). 8 waves, QBLK=128 triangle-paired (uniform 34 steps).
// Counted-vmcnt 3-buffer ring. Output bf16. Defer-max: skip O-rescale while
// __all(mx <= m_ + 8) — P bounded by 2^8, f32 accum tolerant (THR=8, T13).
__global__ __launch_bounds__(512, 2) void attn_kernel(const u16* __restrict__ cqkv,
                                                      const u16* __restrict__ v_t,
                                                      u16* __restrict__ o) {
  extern __shared__ __align__(16) u16 kv[];  // 3 bufs x (K 4096 + V 4096) u16
  __shared__ u16 Pl[8][16 * 64];             // per-wave Q then P^T tile
  int tid = threadIdx.x;
  int lane = tid & 63, w = tid >> 6;
  int h = blockIdx.x, b = blockIdx.y;
  int bx = blockIdx.z;
  int r = lane & 15, g = lane >> 4;
  const u16* qp = cqkv + (size_t)(b * S_) * NQKV + h * HD_;
  const u16* kp = cqkv + (size_t)(b * S_) * NQKV + 1024 + h * HD_;
  const u16* vp = v_t + (size_t)(b * H_ + h) * HD_ * S_;
  u16* Pw = Pl[w];

  int srow = w * 8 + (lane >> 3);
  int ssw = ((lane & 7) * 16) ^ (((lane >> 3) & 7) << 4);  // pre-swz byte in row

  int xr = (r & 7) << 4;                // read-side XOR (rows = ..*16 + r)
  int kq0 = ((g * 16) ^ xr) >> 1;       // elem offset, k-group 0
  int kq1 = ((64 + g * 16) ^ xr) >> 1;  // elem offset, k-group 1

  auto STAGE = [&](int buf, int kt) {
    u16* base = kv + buf * 8192;
    gload_lds16((const char*)(kp + (size_t)(kt + srow) * NQKV) + ssw,
                base + w * 512);
    gload_lds16((const char*)(vp + (size_t)srow * S_ + kt) + ssw,
                base + 4096 + w * 512);
  };

#pragma unroll 1
  for (int half = 0; half < 2; ++half) {
    int qb = half ? (S_ - 128) - bx * 128 : bx * 128;
    int s0 = qb + w * 16;
    int qrow = s0 + r;

    gload_lds16((const char*)(qp + (size_t)(s0 + (lane >> 3)) * NQKV) + ssw, Pw);
    gload_lds16((const char*)(qp + (size_t)(s0 + 8 + (lane >> 3)) * NQKV) + ssw,
                Pw + 512);
    asm volatile("s_waitcnt vmcnt(0)" ::: "memory");
    __builtin_amdgcn_sched_barrier(0);
    __builtin_amdgcn_s_barrier();
    __builtin_amdgcn_sched_barrier(0);
    bf16x8 aq0 = *(const bf16x8*)&Pw[(r << 6) + kq0];
    bf16x8 aq1 = *(const bf16x8*)&Pw[(r << 6) + kq1];

    f32x4 oa[4] = {};
    float m_ = -1e30f, l_ = 0.0f;

    int nt = (S_ - qb) >> 6;
    STAGE(0, qb);
    STAGE(1, qb + 64);

    for (int it = 0; it < nt; ++it) {
      int kt = qb + it * 64;
      if (it + 1 < nt) {
        asm volatile("s_waitcnt vmcnt(2)" ::: "memory");
      } else {
        asm volatile("s_waitcnt vmcnt(0)" ::: "memory");
      }
      __builtin_amdgcn_sched_barrier(0);
      __builtin_amdgcn_s_barrier();
      __builtin_amdgcn_sched_barrier(0);
      if (it + 2 < nt) STAGE((it + 2) % 3, qb + (it + 2) * 64);

      if (kt + 64 > s0) {
        const u16* Kb = kv + (it % 3) * 8192;
        const u16* Vb = Kb + 4096;

        f32x4 sc[4] = {};
#pragma unroll
        for (int blk = 0; blk < 4; ++blk) {
          bf16x8 a0 = *(const bf16x8*)&Kb[((blk * 16 + r) << 6) + kq0];
          bf16x8 a1 = *(const bf16x8*)&Kb[((blk * 16 + r) << 6) + kq1];
          sc[blk] = __builtin_amdgcn_mfma_f32_16x16x32_bf16(a0, aq0, sc[blk], 0, 0, 0);
          sc[blk] = __builtin_amdgcn_mfma_f32_16x16x32_bf16(a1, aq1, sc[blk], 0, 0, 0);
        }

        float p[16];
        if ((qrow & ~63) == kt) {
#pragma unroll
          for (int blk = 0; blk < 4; ++blk)
#pragma unroll
            for (int j = 0; j < 4; ++j) {
              int kk = kt + blk * 16 + g * 4 + j;
              p[blk * 4 + j] = (kk < qrow) ? -1e30f : sc[blk][j];
            }
        } else {
#pragma unroll
          for (int blk = 0; blk < 4; ++blk)
#pragma unroll
            for (int j = 0; j < 4; ++j) p[blk * 4 + j] = sc[blk][j];
        }
        float mx = p[0];
#pragma unroll
        for (int i = 1; i < 16; ++i) mx = fmaxf(mx, p[i]);
        mx = fmaxf(mx, __shfl_xor(mx, 16));
        mx = fmaxf(mx, __shfl_xor(mx, 32));
        // T13 defer-max: only rescale when max grew by > 8 (exp2 domain)
        if (!__all(mx <= m_ + 8.0f)) {
          float mn = fmaxf(m_, mx);
          float scl = __builtin_amdgcn_exp2f(m_ - mn);
          m_ = mn;
          l_ *= scl;
#pragma unroll
          for (int et = 0; et < 4; ++et) oa[et] *= scl;
        }
        float sm = 0.0f;
#pragma unroll
        for (int i = 0; i < 16; ++i) {
          p[i] = __builtin_amdgcn_exp2f(p[i] - m_);
          sm += p[i];
        }
        sm += __shfl_xor(sm, 16);
        sm += __shfl_xor(sm, 32);
        l_ += sm;

#pragma unroll
        for (int blk = 0; blk < 4; ++blk) {
          uint2 pk;
          pk.x = pk_bf16(p[blk * 4 + 0], p[blk * 4 + 1]);
          pk.y = pk_bf16(p[blk * 4 + 2], p[blk * 4 + 3]);
          *(uint2*)&Pw[(r << 6) + ((((blk << 5) + (g << 3)) ^ xr) >> 1)] = pk;
        }
        asm volatile("s_waitcnt lgkmcnt(0)" ::: "memory");
        __builtin_amdgcn_sched_barrier(0);
        bf16x8 pb0 = *(const bf16x8*)&Pw[(r << 6) + kq0];
        bf16x8 pb1 = *(const bf16x8*)&Pw[(r << 6) + kq1];
#pragma unroll
        for (int et = 0; et < 4; ++et) {
          bf16x8 v0 = *(const bf16x8*)&Vb[((et * 16 + r) << 6) + kq0];
          bf16x8 v1 = *(const bf16x8*)&Vb[((et * 16 + r) << 6) + kq1];
          oa[et] = __builtin_amdgcn_mfma_f32_16x16x32_bf16(v0, pb0, oa[et], 0, 0, 0);
          oa[et] = __builtin_amdgcn_mfma_f32_16x16x32_bf16(v1, pb1, oa[et], 0, 0, 0);
        }
      }
    }

    float inv = 1.0f / l_;
#pragma unroll
    for (int et = 0; et < 4; ++et)
#pragma unroll
      for (int j = 0; j < 4; ++j)
        o[(size_t)(b * S_ + s0 + r) * D_ + h * HD_ + et * 16 + g * 4 + j] =
            f2bf(oa[et][j] * inv);
  }
}

// one-time (dlopen) LDS-limit raise for dynamic-shared kernels
namespace {
struct GemmAttrInit {
  GemmAttrInit() {
    hipFuncSetAttribute((const void*)gemm8<1>,
                        hipFuncAttributeMaxDynamicSharedMemorySize, 131072);
    hipFuncSetAttribute((const void*)gemm8<4>,
                        hipFuncAttributeMaxDynamicSharedMemorySize, 131072);
    hipFuncSetAttribute((const void*)attn_kernel,
                        hipFuncAttributeMaxDynamicSharedMemorySize, 49152);
  }
};
GemmAttrInit _gemm_attr_init;
}  // namespace

extern "C" void kernel_launch(void* const* d_in, const int* in_sizes, int n_in,
                              void* d_out, int out_size, void* d_ws, size_t ws_size,
                              hipStream_t stream) {
  const float* x = (const float*)d_in[0];
  const float* ln1_g = (const float*)d_in[1];
  const float* ln1_b = (const float*)d_in[2];
  const float* Wq = (const float*)d_in[3];
  const float* bq = (const float*)d_in[4];
  const float* Wk = (const float*)d_in[5];
  const float* bk = (const float*)d_in[6];
  const float* Wvd = (const float*)d_in[7];
  const float* bvd = (const float*)d_in[8];
  const float* Wvu = (const float*)d_in[9];
  const float* bvu = (const float*)d_in[10];
  const float* ln2_g = (const float*)d_in[11];
  const float* ln2_b = (const float*)d_in[12];
  const float* W1 = (const float*)d_in[13];
  const float* b1 = (const float*)d_in[14];
  const float* W2 = (const float*)d_in[15];
  const float* b2 = (const float*)d_in[16];
  float* out = (float*)d_out;
  (void)in_sizes; (void)n_in; (void)out_size; (void)ws_size;

  char* ws = (char*)d_ws;
  const size_t MB = 1024 * 1024;
  const size_t KB = 1024;
  u16* wqkvT = (u16*)(ws + 0);                    // [2560x1024] bf16, 5 MB
  u16* wvuB = (u16*)(ws + 5 * MB);                // 64 KB
  float* bqkv = (float*)(ws + 5 * MB + 64 * KB);  // 10 KB
  u16* w1T = (u16*)(ws + 5 * MB + 384 * KB);      // 8 MB -> 13.375
  u16* w2T = (u16*)(ws + 13 * MB + 384 * KB);     // 8 MB -> 21.375
  u16* hbuf = (u16*)(ws + 21 * MB + 384 * KB);    // 8 MB -> 29.375
  u16* cqkv = (u16*)(ws + 29 * MB + 384 * KB);    // 20 MB -> 49.375
  u16* vT = (u16*)(ws + 49 * MB + 384 * KB);      // 8 MB -> 57.375
  u16* ob16 = (u16*)(ws + 57 * MB + 384 * KB);    // 8 MB (bf16) -> 65.375
  u16* p3 = (u16*)(ws + 65 * MB + 384 * KB);      // 8 MB -> 73.375 (outside ubuf)
  u16* x2 = (u16*)(ws + 73 * MB + 384 * KB);      // 8 MB (bf16) -> 81.375
  u16* p0 = (u16*)(ws + 81 * MB + 384 * KB);      // 8 MB -> 89.375
  // lifetime-disjoint reuses:
  u16* ubuf = cqkv;            // 32 MB (cqkv+vT+ob16[0:4MB]), dead by FFN1
  u16* p1 = (u16*)(ws + 0);    // 8 MB over wqkvT+..., dead by FFN2
  u16* p2 = (u16*)hbuf;        // 8 MB, hbuf dead after FFN1

  dim3 blk(256);
  // merged prologue: QKV transposes (1 launch), W1/W2 transposes, conv+concat
  wtrans_qkv<<<dim3(2, 32, 48), blk, 0, stream>>>(Wq, Wk, Wvd, wqkvT);
  wconv_bconcat<<<dim3(42), blk, 0, stream>>>(Wvu, wvuB, bq, bk, bvd, bqkv);
  wtrans<<<dim3(128, 32, 1), blk, 0, stream>>>(W1, w1T, 1024, 4096, 0L, 0L, 1.0f);
  wtrans<<<dim3(32, 128, 1), blk, 0, stream>>>(W2, w2T, 4096, 1024, 0L, 0L, 1.0f);
  ln_kernel<<<dim3(M_), blk, 0, stream>>>(x, (const u16*)nullptr, ln1_g, ln1_b,
                                          hbuf, (u16*)nullptr);
  // fused QKV projection (2-phase 128² — 640 blocks, 2.5/CU, T1-swizzled)
  gemm_nt<0><<<dim3(20, 32), blk, 0, stream>>>(hbuf, wqkvT, 1024, 1024, 1024, bqkv,
                                               (const float*)nullptr, (void*)cqkv,
                                               (void*)nullptr, NQKV);
  vu_kernel<<<dim3(S_ / 64, H_, B_), blk, 0, stream>>>(cqkv, wvuB, bvu, vT);
  // attention v4 + defer-max: grid (H, B, 8), 512 threads, 48KB dynamic LDS
  attn_kernel<<<dim3(H_, B_, 8), dim3(512), 49152, stream>>>(cqkv, vT, ob16);
  ln_kernel<<<dim3(M_), blk, 0, stream>>>(x, ob16, ln2_g, ln2_b, hbuf, x2);
  // FFN1: 256² R7 pipeline, grid 16x16 = 1 block/CU, T1-swizzled
  gemm8<1><<<dim3(16, 16, 1), dim3(512), 131072, stream>>>(
      hbuf, w1T, 1024, 1024, 16, b1, ubuf,
      (u16*)nullptr, (u16*)nullptr, (u16*)nullptr, (u16*)nullptr, 4096);
  // FFN2: split-K=4, grid 4x16x4, T1-swizzled per z; all z -> bf16 partials
  gemm8<4><<<dim3(4, 16, 4), dim3(512), 131072, stream>>>(
      ubuf, w2T, 4096, 4096, 16, (const float*)nullptr, (u16*)nullptr,
      p0, p1, p2, p3, 1024);
  // out = p0+p1+p2+p3 + b2 + x2
  reduce2<<<dim3(M_ * D_ / 1024), blk, 0, stream>>>(out, p0, p1, p2, p3, b2, x2);
}

// Round 22
// 213.881 us; speedup vs baseline: 1.1334x; 1.0201x over previous
//
#include <hip/hip_runtime.h>

// ---------------------------------------------------------------------------
// TransformerBlock: LN1 -> QKV proj (fused) -> reversed-causal attention
// (scale 1/sqrt(D)=1/32) -> residual -> LN2 -> GELU FFN -> residual.
// B=2 S=2048 D=1024 H=16 HD=64 R=32 F=4096. All d_in/d_out fp32; internal
// compute bf16 MFMA.
// R21: W1/W2 transposes merged into one launch (wtrans_ffn, z-dim remap).
// Rest = R21 verified composite: attn v4 + T13 defer-max (bf16 out),
// gemm8 256² R7-schedule FFN1/FFN2(split-K=4, bf16 partials), gemm_nt 128²
// fused QKV, T1 XCD swizzles, bf16 ob/x2 streams, merged prologue.
// ---------------------------------------------------------------------------

typedef unsigned short u16;
typedef __attribute__((ext_vector_type(4))) float f32x4;
typedef __attribute__((ext_vector_type(8))) __bf16 bf16x8;

#define B_ 2
#define S_ 2048
#define D_ 1024
#define H_ 16
#define HD_ 64
#define R_ 32
#define F_ 4096
#define M_ (B_ * S_)   // 4096 rows
#define NQKV 2560      // 1024 q + 1024 k + 512 vd
// (1/sqrt(D)) * log2(e): folded into Wq/bq so QK^T scores are exp2-ready
#define C2F 0.04508422002778011f

__device__ __forceinline__ u16 f2bf(float f) {
  union { float f; unsigned u; } v; v.f = f;
  unsigned u = v.u;
  return (u16)((u + 0x7FFFu + ((u >> 16) & 1u)) >> 16);  // RNE
}
__device__ __forceinline__ float bf2f(u16 h) {
  union { unsigned u; float f; } v; v.u = ((unsigned)h) << 16;
  return v.f;
}
__device__ __forceinline__ unsigned pk_bf16(float lo, float hi) {
  unsigned r;
  asm volatile("v_cvt_pk_bf16_f32 %0, %1, %2" : "=v"(r) : "v"(lo), "v"(hi));
  return r;
}

typedef __attribute__((address_space(1))) void gvoid;
typedef __attribute__((address_space(3))) void lvoid;
// async global->LDS, 16B/lane; lds base must be wave-uniform (lane*16 implicit)
__device__ __forceinline__ void gload_lds16(const void* g, void* l) {
  __builtin_amdgcn_global_load_lds((gvoid*)(void*)g, (lvoid*)l, 16, 0, 0);
}

__device__ __forceinline__ float gelu_f(float x) {
  float t = tanhf(0.7978845608028654f * (x + 0.044715f * x * x * x));
  return 0.5f * x * (1.0f + t);
}

// ---- merged QKV weight transpose: grid (2, 32, 48) ------------------------
// z<16: Wq head z (scale C2F); z<32: Wk head z-16; z>=32: Wvd head z-32
// (Cc=32, only blockIdx.x==0 active).
__global__ __launch_bounds__(256) void wtrans_qkv(const float* __restrict__ Wq,
                                                  const float* __restrict__ Wk,
                                                  const float* __restrict__ Wvd,
                                                  u16* __restrict__ wqkvT) {
  __shared__ float tile[32][33];
  int z = blockIdx.z;
  const float* ip;
  u16* op;
  int Cc;
  float scale;
  if (z < 16) {
    ip = Wq + (size_t)z * 65536;
    op = wqkvT + (size_t)z * 65536;
    Cc = 64; scale = C2F;
  } else if (z < 32) {
    ip = Wk + (size_t)(z - 16) * 65536;
    op = wqkvT + 1048576 + (size_t)(z - 16) * 65536;
    Cc = 64; scale = 1.0f;
  } else {
    if (blockIdx.x != 0) return;
    ip = Wvd + (size_t)(z - 32) * 32768;
    op = wqkvT + 2097152 + (size_t)(z - 32) * 32768;
    Cc = 32; scale = 1.0f;
  }
  int c0 = blockIdx.x * 32, r0 = blockIdx.y * 32;
  int tx = threadIdx.x & 31, ty = threadIdx.x >> 5;  // 32 x 8
#pragma unroll
  for (int j = 0; j < 32; j += 8)
    tile[ty + j][tx] = ip[(size_t)(r0 + ty + j) * Cc + c0 + tx];
  __syncthreads();
#pragma unroll
  for (int j = 0; j < 32; j += 8)
    op[(size_t)(c0 + ty + j) * 1024 + r0 + tx] = f2bf(tile[tx][ty + j] * scale);
}

// ---- merged FFN weight transpose: grid (128, 32, 2) -----------------------
// z=0: W1 [1024x4096] -> w1T [4096][1024] (direct 128x32 tiling)
// z=1: W2 [4096x1024] -> w2T [1024][4096]; (x,y) -> (x&31, y*4 + x>>5)
//      (bijection: x = (by&3)*32 + bx, y = by>>2)
__global__ __launch_bounds__(256) void wtrans_ffn(const float* __restrict__ W1,
                                                  const float* __restrict__ W2,
                                                  u16* __restrict__ w1T,
                                                  u16* __restrict__ w2T) {
  __shared__ float tile[32][33];
  const float* ip;
  u16* op;
  int Rr, Cc, bx, by;
  if (blockIdx.z == 0) {
    ip = W1; op = w1T; Rr = 1024; Cc = 4096;
    bx = blockIdx.x; by = blockIdx.y;
  } else {
    ip = W2; op = w2T; Rr = 4096; Cc = 1024;
    bx = blockIdx.x & 31; by = blockIdx.y * 4 + (blockIdx.x >> 5);
  }
  int c0 = bx * 32, r0 = by * 32;
  int tx = threadIdx.x & 31, ty = threadIdx.x >> 5;  // 32 x 8
#pragma unroll
  for (int j = 0; j < 32; j += 8)
    tile[ty + j][tx] = ip[(size_t)(r0 + ty + j) * Cc + c0 + tx];
  __syncthreads();
#pragma unroll
  for (int j = 0; j < 32; j += 8)
    op[(size_t)(c0 + ty + j) * Rr + r0 + tx] = f2bf(tile[tx][ty + j]);
}

// ---- merged: wconv(Wvu->bf16, 32 blocks) + bconcat (10 blocks) -------------
__global__ __launch_bounds__(256) void wconv_bconcat(const float* __restrict__ Wvu,
                                                     u16* __restrict__ wvuB,
                                                     const float* __restrict__ bq,
                                                     const float* __restrict__ bk,
                                                     const float* __restrict__ bvd,
                                                     float* __restrict__ bqkv) {
  int bid = blockIdx.x;
  if (bid < 32) {
    int i = (bid * 256 + threadIdx.x) * 4;
    if (i < H_ * R_ * HD_) {
      float4 v = *(const float4*)&Wvu[i];
      ushort4 o;
      o.x = f2bf(v.x); o.y = f2bf(v.y); o.z = f2bf(v.z); o.w = f2bf(v.w);
      *(ushort4*)&wvuB[i] = o;
    }
  } else {
    int i = (bid - 32) * 256 + threadIdx.x;
    if (i < NQKV) {
      float v = (i < 1024) ? bq[i] * C2F : (i < 2048 ? bk[i - 1024] : bvd[i - 2048]);
      bqkv[i] = v;
    }
  }
}

// ---- LayerNorm (optional bf16 residual addin + bf16 x2 passthrough) --------
__global__ __launch_bounds__(256) void ln_kernel(const float* __restrict__ xin,
                                                 const u16* __restrict__ addin,
                                                 const float* __restrict__ gam,
                                                 const float* __restrict__ bet,
                                                 u16* __restrict__ hout,
                                                 u16* __restrict__ x2out) {
  int row = blockIdx.x, tid = threadIdx.x;
  size_t base = (size_t)row * D_ + tid * 4;
  float4 v = *(const float4*)&xin[base];
  if (addin) {
    ushort4 a = *(const ushort4*)&addin[base];
    v.x += bf2f(a.x); v.y += bf2f(a.y); v.z += bf2f(a.z); v.w += bf2f(a.w);
  }
  if (x2out) {
    ushort4 xo;
    xo.x = f2bf(v.x); xo.y = f2bf(v.y); xo.z = f2bf(v.z); xo.w = f2bf(v.w);
    *(ushort4*)&x2out[base] = xo;
  }
  float s = v.x + v.y + v.z + v.w;
  float ss = v.x * v.x + v.y * v.y + v.z * v.z + v.w * v.w;
#pragma unroll
  for (int off = 32; off > 0; off >>= 1) {
    s += __shfl_down(s, off);
    ss += __shfl_down(ss, off);
  }
  __shared__ float red[8];
  int wv = tid >> 6;
  if ((tid & 63) == 0) { red[wv] = s; red[4 + wv] = ss; }
  __syncthreads();
  if (tid == 0) {
    float s1 = red[0] + red[1] + red[2] + red[3];
    float s2 = red[4] + red[5] + red[6] + red[7];
    float mu = s1 * (1.0f / D_);
    red[0] = mu;
    red[1] = s2 * (1.0f / D_) - mu * mu;
  }
  __syncthreads();
  float mu = red[0];
  float rstd = rsqrtf(red[1] + 1e-5f);
  int ci = tid * 4;
  ushort4 o;
  o.x = f2bf((v.x - mu) * rstd * gam[ci + 0] + bet[ci + 0]);
  o.y = f2bf((v.y - mu) * rstd * gam[ci + 1] + bet[ci + 1]);
  o.z = f2bf((v.z - mu) * rstd * gam[ci + 2] + bet[ci + 2]);
  o.w = f2bf((v.w - mu) * rstd * gam[ci + 3] + bet[ci + 3]);
  *(ushort4*)&hout[base] = o;
}

// ---- NT GEMM (128x128, 2-phase dbuf): used for the fused QKV projection ---
// T1: XCD-aware block swizzle (nwg = 20*32 = 640, %8==0 -> bijective).
template <int MODE>
__global__ __launch_bounds__(256) void gemm_nt(const u16* __restrict__ A,
                                               const u16* __restrict__ Bt,
                                               int K, int lda, int ldb,
                                               const float* __restrict__ bias,
                                               const float* __restrict__ res,
                                               void* __restrict__ Cout,
                                               void* __restrict__ Cout2, int ldc) {
  __shared__ __align__(16) u16 As0[128 * 32];
  __shared__ __align__(16) u16 Bs0[128 * 32];
  __shared__ __align__(16) u16 As1[128 * 32];
  __shared__ __align__(16) u16 Bs1[128 * 32];
  int tid = threadIdx.x;
  int lane = tid & 63, wid = tid >> 6;
  int wm = wid >> 1, wn = wid & 1;
  int bid = blockIdx.x + gridDim.x * blockIdx.y;
  int nwg = gridDim.x * gridDim.y;
  int swz = (bid & 7) * (nwg >> 3) + (bid >> 3);
  int tbx = swz % gridDim.x, tby = swz / gridDim.x;
  int row0 = tby * 128, col0 = tbx * 128;
  int l15 = lane & 15, g = lane >> 4;
  int srow = lane >> 2, scol = (lane & 3) * 8;
  f32x4 acc[4][4] = {};
  const u16* Ap = A + (size_t)row0 * lda;
  const u16* Bp = Bt + (size_t)col0 * ldb;

  auto STAGE = [&](u16* AS, u16* BS, int kk) {
#pragma unroll
    for (int i = 0; i < 2; ++i) {
      int c = wid * 2 + i;
      gload_lds16(Ap + (size_t)(c * 16 + srow) * lda + kk + scol, &AS[c * 512]);
      gload_lds16(Bp + (size_t)(c * 16 + srow) * ldb + kk + scol, &BS[c * 512]);
    }
  };
  auto COMPUTE = [&](const u16* AS, const u16* BS) {
    bf16x8 af[4], bfr[4];
#pragma unroll
    for (int t = 0; t < 4; ++t) {
      af[t] = *(const bf16x8*)&AS[(wm * 64 + t * 16 + l15) * 32 + g * 8];
      bfr[t] = *(const bf16x8*)&BS[(wn * 64 + t * 16 + l15) * 32 + g * 8];
    }
#pragma unroll
    for (int mt = 0; mt < 4; ++mt)
#pragma unroll
      for (int nt = 0; nt < 4; ++nt)
        acc[mt][nt] = __builtin_amdgcn_mfma_f32_16x16x32_bf16(af[mt], bfr[nt],
                                                              acc[mt][nt], 0, 0, 0);
  };

  STAGE(As0, Bs0, 0);
  __syncthreads();
  for (int k0 = 0; k0 < K; k0 += 64) {
    if (k0 + 32 < K) STAGE(As1, Bs1, k0 + 32);
    COMPUTE(As0, Bs0);
    __syncthreads();
    if (k0 + 64 < K) STAGE(As0, Bs0, k0 + 64);
    COMPUTE(As1, Bs1);
    __syncthreads();
  }

#pragma unroll
  for (int mt = 0; mt < 4; ++mt) {
#pragma unroll
    for (int nt = 0; nt < 4; ++nt) {
      int cc = col0 + wn * 64 + nt * 16 + l15;
      float bv = bias ? bias[cc] : 0.0f;
#pragma unroll
      for (int j = 0; j < 4; ++j) {
        int rr = row0 + wm * 64 + mt * 16 + g * 4 + j;
        float v = acc[mt][nt][j] + bv;
        if (MODE == 1) v = gelu_f(v);
        if (MODE == 2) {
          ((float*)Cout)[(size_t)rr * ldc + cc] = v + res[(size_t)rr * ldc + cc];
        } else {
          ((u16*)Cout)[(size_t)rr * ldc + cc] = f2bf(v);
        }
      }
    }
  }
  (void)Cout2;
}

// ---- gemm8 (R7 schedule): 256x256, BK=64, 2-slot dbuf, stage interleaved ---
// MODE 1: bf16 gelu(v+bias) -> Cb. MODE 4: split-K, all z -> bf16 partials.
template <int MODE>
__global__ __launch_bounds__(512, 2) void gemm8(
    const u16* __restrict__ A, const u16* __restrict__ Bt,
    int lda, int ldb, int nk,
    const float* __restrict__ bias,
    u16* __restrict__ Cb,
    u16* __restrict__ P0, u16* __restrict__ P1,
    u16* __restrict__ P2, u16* __restrict__ P3,
    int ldc) {
  extern __shared__ __align__(16) char smem[];
  int tid = threadIdx.x;
  int lane = tid & 63, wid = tid >> 6;
  int wm = wid >> 2, wn = wid & 3;
  int l15 = lane & 15, g = lane >> 4;
  int bid = blockIdx.x + gridDim.x * blockIdx.y;
  int nwg = gridDim.x * gridDim.y;
  int swz = (bid & 7) * (nwg >> 3) + (bid >> 3);
  int tbx = swz % gridDim.x, tby = swz / gridDim.x;
  int row0 = tby * 256, col0 = tbx * 256;
  int koff = (MODE == 4) ? blockIdx.z * (nk * 64) : 0;
  const u16* Ap = A + (size_t)row0 * lda + koff;
  const u16* Bp = Bt + (size_t)col0 * ldb + koff;
  int trow = tid >> 3;
  int sbyte = ((tid & 7) * 16) ^ ((trow & 7) << 4);
  int xr = (l15 & 7) << 4;

  f32x4 acc[8][4] = {};

  auto STAGE_A = [&](int buf, int kt) {
#pragma unroll
    for (int l = 0; l < 4; ++l)
      gload_lds16((const char*)(Ap + (size_t)(l * 64 + trow) * lda + kt) + sbyte,
                  smem + buf * 65536 + (l * 64 + wid * 8) * 128);
  };
  auto STAGE_B = [&](int buf, int kt) {
#pragma unroll
    for (int l = 0; l < 4; ++l)
      gload_lds16((const char*)(Bp + (size_t)(l * 64 + trow) * ldb + kt) + sbyte,
                  smem + buf * 65536 + 32768 + (l * 64 + wid * 8) * 128);
  };

  STAGE_A(0, 0);
  STAGE_B(0, 0);
  asm volatile("s_waitcnt vmcnt(0)" ::: "memory");
  __builtin_amdgcn_sched_barrier(0);
  __builtin_amdgcn_s_barrier();

  int cur = 0;
  for (int it = 0; it < nk; ++it) {
    const char* Ab = smem + cur * 65536 + (size_t)(wm * 128 + l15) * 128;
    const char* Bb = smem + cur * 65536 + 32768 + (size_t)(wn * 64 + l15) * 128;
    bool nxt = (it + 1 < nk);
#pragma unroll
    for (int kk = 0; kk < 2; ++kk) {
      int kq = (kk * 64 + g * 16) ^ xr;
      bf16x8 bfr[4], af[8];
#pragma unroll
      for (int nt = 0; nt < 4; ++nt)
        bfr[nt] = *(const bf16x8*)(Bb + nt * 2048 + kq);
#pragma unroll
      for (int mt = 0; mt < 8; ++mt)
        af[mt] = *(const bf16x8*)(Ab + mt * 2048 + kq);
      if (nxt) {
        if (kk == 0) STAGE_A(cur ^ 1, (it + 1) * 64);
        else         STAGE_B(cur ^ 1, (it + 1) * 64);
      }
      __builtin_amdgcn_s_setprio(1);
#pragma unroll
      for (int mt = 0; mt < 8; ++mt)
#pragma unroll
        for (int nt = 0; nt < 4; ++nt)
          acc[mt][nt] = __builtin_amdgcn_mfma_f32_16x16x32_bf16(af[mt], bfr[nt],
                                                                acc[mt][nt], 0, 0, 0);
      __builtin_amdgcn_s_setprio(0);
    }
    asm volatile("s_waitcnt vmcnt(0)" ::: "memory");
    __builtin_amdgcn_sched_barrier(0);
    __builtin_amdgcn_s_barrier();
    cur ^= 1;
  }

  u16* pp = Cb;
  if (MODE == 4)
    pp = (blockIdx.z == 0) ? P0
       : (blockIdx.z == 1) ? P1
       : (blockIdx.z == 2) ? P2 : P3;
#pragma unroll
  for (int mt = 0; mt < 8; ++mt) {
#pragma unroll
    for (int nt = 0; nt < 4; ++nt) {
      int cc = col0 + wn * 64 + nt * 16 + l15;
      float bv = (MODE == 1) ? bias[cc] : 0.0f;
#pragma unroll
      for (int j = 0; j < 4; ++j) {
        int rr = row0 + wm * 128 + mt * 16 + g * 4 + j;
        float v = acc[mt][nt][j] + bv;
        if (MODE == 1) {
          pp[(size_t)rr * ldc + cc] = f2bf(gelu_f(v));
        } else {
          pp[(size_t)rr * ldc + cc] = f2bf(v);
        }
      }
    }
  }
}

// ---- split-K reduce: out = p0+p1+p2+p3 (bf16) + b2[col] + x2 (bf16) --------
__global__ __launch_bounds__(256) void reduce2(float* __restrict__ out,
                                               const u16* __restrict__ p0,
                                               const u16* __restrict__ p1,
                                               const u16* __restrict__ p2,
                                               const u16* __restrict__ p3,
                                               const float* __restrict__ b2,
                                               const u16* __restrict__ x2) {
  int i = (blockIdx.x * 256 + threadIdx.x) * 4;
  ushort4 a0 = *(const ushort4*)&p0[i];
  ushort4 a = *(const ushort4*)&p1[i];
  ushort4 b = *(const ushort4*)&p2[i];
  ushort4 c = *(const ushort4*)&p3[i];
  ushort4 r = *(const ushort4*)&x2[i];
  int cix = i & (D_ - 1);
  float4 o;
  o.x = bf2f(a0.x) + bf2f(a.x) + bf2f(b.x) + bf2f(c.x) + b2[cix + 0] + bf2f(r.x);
  o.y = bf2f(a0.y) + bf2f(a.y) + bf2f(b.y) + bf2f(c.y) + b2[cix + 1] + bf2f(r.y);
  o.z = bf2f(a0.z) + bf2f(a.z) + bf2f(b.z) + bf2f(c.z) + b2[cix + 2] + bf2f(r.z);
  o.w = bf2f(a0.w) + bf2f(a.w) + bf2f(b.w) + bf2f(c.w) + b2[cix + 3] + bf2f(r.w);
  *(float4*)&out[i] = o;
}

// ---- low-rank V up-proj -> V^T [b,h][e][t] bf16 ----------------------------
__global__ __launch_bounds__(256) void vu_kernel(const u16* __restrict__ vd,
                                                 const u16* __restrict__ wvu,
                                                 const float* __restrict__ bvu,
                                                 u16* __restrict__ v_t) {
  int t0 = blockIdx.x * 64, h = blockIdx.y, b = blockIdx.z;
  __shared__ u16 vds[64][32];
  __shared__ u16 vt[64][65];
  int tid = threadIdx.x;
  {
    int rr2 = tid >> 2, c8 = (tid & 3) * 8;
    *(bf16x8*)&vds[rr2][c8] =
        *(const bf16x8*)&vd[(size_t)(b * S_ + t0 + rr2) * NQKV + 2048 + h * R_ + c8];
  }
  __syncthreads();
  int e = tid & 63, tg = (tid >> 6) * 16;
  float wcol[32];
#pragma unroll
  for (int r = 0; r < 32; ++r) wcol[r] = bf2f(wvu[((size_t)h * R_ + r) * HD_ + e]);
  float bb = bvu[h * HD_ + e];
  for (int i = 0; i < 16; ++i) {
    int t = tg + i;
    float acc = bb;
#pragma unroll
    for (int r = 0; r < 32; ++r) acc += bf2f(vds[t][r]) * wcol[r];
    vt[t][e] = f2bf(acc);
  }
  __syncthreads();
  for (int idx = tid; idx < 64 * 64; idx += 256) {
    int e2 = idx >> 6, t2 = idx & 63;
    v_t[((size_t)(b * H_ + h) * HD_ + e2) * S_ + t0 + t2] = vt[t2][e2];
  }
}

// ---- attention v4 + T13 defer-max: reversed-causal (key t >= query s) ------
// grid (H, B, 8). 8 waves, QBLK=128 triangle-paired (uniform 34 steps).
// Counted-vmcnt 3-buffer ring. Output bf16. Defer-max: skip O-rescale while
// __all(mx <= m_ + 8) — P bounded by 2^8, f32 accum tolerant (THR=8, T13).
__global__ __launch_bounds__(512, 2) void attn_kernel(const u16* __restrict__ cqkv,
                                                      const u16* __restrict__ v_t,
                                                      u16* __restrict__ o) {
  extern __shared__ __align__(16) u16 kv[];  // 3 bufs x (K 4096 + V 4096) u16
  __shared__ u16 Pl[8][16 * 64];             // per-wave Q then P^T tile
  int tid = threadIdx.x;
  int lane = tid & 63, w = tid >> 6;
  int h = blockIdx.x, b = blockIdx.y;
  int bx = blockIdx.z;
  int r = lane & 15, g = lane >> 4;
  const u16* qp = cqkv + (size_t)(b * S_) * NQKV + h * HD_;
  const u16* kp = cqkv + (size_t)(b * S_) * NQKV + 1024 + h * HD_;
  const u16* vp = v_t + (size_t)(b * H_ + h) * HD_ * S_;
  u16* Pw = Pl[w];

  int srow = w * 8 + (lane >> 3);
  int ssw = ((lane & 7) * 16) ^ (((lane >> 3) & 7) << 4);  // pre-swz byte in row

  int xr = (r & 7) << 4;                // read-side XOR (rows = ..*16 + r)
  int kq0 = ((g * 16) ^ xr) >> 1;       // elem offset, k-group 0
  int kq1 = ((64 + g * 16) ^ xr) >> 1;  // elem offset, k-group 1

  auto STAGE = [&](int buf, int kt) {
    u16* base = kv + buf * 8192;
    gload_lds16((const char*)(kp + (size_t)(kt + srow) * NQKV) + ssw,
                base + w * 512);
    gload_lds16((const char*)(vp + (size_t)srow * S_ + kt) + ssw,
                base + 4096 + w * 512);
  };

#pragma unroll 1
  for (int half = 0; half < 2; ++half) {
    int qb = half ? (S_ - 128) - bx * 128 : bx * 128;
    int s0 = qb + w * 16;
    int qrow = s0 + r;

    gload_lds16((const char*)(qp + (size_t)(s0 + (lane >> 3)) * NQKV) + ssw, Pw);
    gload_lds16((const char*)(qp + (size_t)(s0 + 8 + (lane >> 3)) * NQKV) + ssw,
                Pw + 512);
    asm volatile("s_waitcnt vmcnt(0)" ::: "memory");
    __builtin_amdgcn_sched_barrier(0);
    __builtin_amdgcn_s_barrier();
    __builtin_amdgcn_sched_barrier(0);
    bf16x8 aq0 = *(const bf16x8*)&Pw[(r << 6) + kq0];
    bf16x8 aq1 = *(const bf16x8*)&Pw[(r << 6) + kq1];

    f32x4 oa[4] = {};
    float m_ = -1e30f, l_ = 0.0f;

    int nt = (S_ - qb) >> 6;
    STAGE(0, qb);
    STAGE(1, qb + 64);

    for (int it = 0; it < nt; ++it) {
      int kt = qb + it * 64;
      if (it + 1 < nt) {
        asm volatile("s_waitcnt vmcnt(2)" ::: "memory");
      } else {
        asm volatile("s_waitcnt vmcnt(0)" ::: "memory");
      }
      __builtin_amdgcn_sched_barrier(0);
      __builtin_amdgcn_s_barrier();
      __builtin_amdgcn_sched_barrier(0);
      if (it + 2 < nt) STAGE((it + 2) % 3, qb + (it + 2) * 64);

      if (kt + 64 > s0) {
        const u16* Kb = kv + (it % 3) * 8192;
        const u16* Vb = Kb + 4096;

        f32x4 sc[4] = {};
#pragma unroll
        for (int blk = 0; blk < 4; ++blk) {
          bf16x8 a0 = *(const bf16x8*)&Kb[((blk * 16 + r) << 6) + kq0];
          bf16x8 a1 = *(const bf16x8*)&Kb[((blk * 16 + r) << 6) + kq1];
          sc[blk] = __builtin_amdgcn_mfma_f32_16x16x32_bf16(a0, aq0, sc[blk], 0, 0, 0);
          sc[blk] = __builtin_amdgcn_mfma_f32_16x16x32_bf16(a1, aq1, sc[blk], 0, 0, 0);
        }

        float p[16];
        if ((qrow & ~63) == kt) {
#pragma unroll
          for (int blk = 0; blk < 4; ++blk)
#pragma unroll
            for (int j = 0; j < 4; ++j) {
              int kk = kt + blk * 16 + g * 4 + j;
              p[blk * 4 + j] = (kk < qrow) ? -1e30f : sc[blk][j];
            }
        } else {
#pragma unroll
          for (int blk = 0; blk < 4; ++blk)
#pragma unroll
            for (int j = 0; j < 4; ++j) p[blk * 4 + j] = sc[blk][j];
        }
        float mx = p[0];
#pragma unroll
        for (int i = 1; i < 16; ++i) mx = fmaxf(mx, p[i]);
        mx = fmaxf(mx, __shfl_xor(mx, 16));
        mx = fmaxf(mx, __shfl_xor(mx, 32));
        // T13 defer-max: only rescale when max grew by > 8 (exp2 domain)
        if (!__all(mx <= m_ + 8.0f)) {
          float mn = fmaxf(m_, mx);
          float scl = __builtin_amdgcn_exp2f(m_ - mn);
          m_ = mn;
          l_ *= scl;
#pragma unroll
          for (int et = 0; et < 4; ++et) oa[et] *= scl;
        }
        float sm = 0.0f;
#pragma unroll
        for (int i = 0; i < 16; ++i) {
          p[i] = __builtin_amdgcn_exp2f(p[i] - m_);
          sm += p[i];
        }
        sm += __shfl_xor(sm, 16);
        sm += __shfl_xor(sm, 32);
        l_ += sm;

#pragma unroll
        for (int blk = 0; blk < 4; ++blk) {
          uint2 pk;
          pk.x = pk_bf16(p[blk * 4 + 0], p[blk * 4 + 1]);
          pk.y = pk_bf16(p[blk * 4 + 2], p[blk * 4 + 3]);
          *(uint2*)&Pw[(r << 6) + ((((blk << 5) + (g << 3)) ^ xr) >> 1)] = pk;
        }
        asm volatile("s_waitcnt lgkmcnt(0)" ::: "memory");
        __builtin_amdgcn_sched_barrier(0);
        bf16x8 pb0 = *(const bf16x8*)&Pw[(r << 6) + kq0];
        bf16x8 pb1 = *(const bf16x8*)&Pw[(r << 6) + kq1];
#pragma unroll
        for (int et = 0; et < 4; ++et) {
          bf16x8 v0 = *(const bf16x8*)&Vb[((et * 16 + r) << 6) + kq0];
          bf16x8 v1 = *(const bf16x8*)&Vb[((et * 16 + r) << 6) + kq1];
          oa[et] = __builtin_amdgcn_mfma_f32_16x16x32_bf16(v0, pb0, oa[et], 0, 0, 0);
          oa[et] = __builtin_amdgcn_mfma_f32_16x16x32_bf16(v1, pb1, oa[et], 0, 0, 0);
        }
      }
    }

    float inv = 1.0f / l_;
#pragma unroll
    for (int et = 0; et < 4; ++et)
#pragma unroll
      for (int j = 0; j < 4; ++j)
        o[(size_t)(b * S_ + s0 + r) * D_ + h * HD_ + et * 16 + g * 4 + j] =
            f2bf(oa[et][j] * inv);
  }
}

// one-time (dlopen) LDS-limit raise for dynamic-shared kernels
namespace {
struct GemmAttrInit {
  GemmAttrInit() {
    hipFuncSetAttribute((const void*)gemm8<1>,
                        hipFuncAttributeMaxDynamicSharedMemorySize, 131072);
    hipFuncSetAttribute((const void*)gemm8<4>,
                        hipFuncAttributeMaxDynamicSharedMemorySize, 131072);
    hipFuncSetAttribute((const void*)attn_kernel,
                        hipFuncAttributeMaxDynamicSharedMemorySize, 49152);
  }
};
GemmAttrInit _gemm_attr_init;
}  // namespace

extern "C" void kernel_launch(void* const* d_in, const int* in_sizes, int n_in,
                              void* d_out, int out_size, void* d_ws, size_t ws_size,
                              hipStream_t stream) {
  const float* x = (const float*)d_in[0];
  const float* ln1_g = (const float*)d_in[1];
  const float* ln1_b = (const float*)d_in[2];
  const float* Wq = (const float*)d_in[3];
  const float* bq = (const float*)d_in[4];
  const float* Wk = (const float*)d_in[5];
  const float* bk = (const float*)d_in[6];
  const float* Wvd = (const float*)d_in[7];
  const float* bvd = (const float*)d_in[8];
  const float* Wvu = (const float*)d_in[9];
  const float* bvu = (const float*)d_in[10];
  const float* ln2_g = (const float*)d_in[11];
  const float* ln2_b = (const float*)d_in[12];
  const float* W1 = (const float*)d_in[13];
  const float* b1 = (const float*)d_in[14];
  const float* W2 = (const float*)d_in[15];
  const float* b2 = (const float*)d_in[16];
  float* out = (float*)d_out;
  (void)in_sizes; (void)n_in; (void)out_size; (void)ws_size;

  char* ws = (char*)d_ws;
  const size_t MB = 1024 * 1024;
  const size_t KB = 1024;
  u16* wqkvT = (u16*)(ws + 0);                    // [2560x1024] bf16, 5 MB
  u16* wvuB = (u16*)(ws + 5 * MB);                // 64 KB
  float* bqkv = (float*)(ws + 5 * MB + 64 * KB);  // 10 KB
  u16* w1T = (u16*)(ws + 5 * MB + 384 * KB);      // 8 MB -> 13.375
  u16* w2T = (u16*)(ws + 13 * MB + 384 * KB);     // 8 MB -> 21.375
  u16* hbuf = (u16*)(ws + 21 * MB + 384 * KB);    // 8 MB -> 29.375
  u16* cqkv = (u16*)(ws + 29 * MB + 384 * KB);    // 20 MB -> 49.375
  u16* vT = (u16*)(ws + 49 * MB + 384 * KB);      // 8 MB -> 57.375
  u16* ob16 = (u16*)(ws + 57 * MB + 384 * KB);    // 8 MB (bf16) -> 65.375
  u16* p3 = (u16*)(ws + 65 * MB + 384 * KB);      // 8 MB -> 73.375 (outside ubuf)
  u16* x2 = (u16*)(ws + 73 * MB + 384 * KB);      // 8 MB (bf16) -> 81.375
  u16* p0 = (u16*)(ws + 81 * MB + 384 * KB);      // 8 MB -> 89.375
  // lifetime-disjoint reuses:
  u16* ubuf = cqkv;            // 32 MB (cqkv+vT+ob16[0:4MB]), dead by FFN1
  u16* p1 = (u16*)(ws + 0);    // 8 MB over wqkvT+..., dead by FFN2
  u16* p2 = (u16*)hbuf;        // 8 MB, hbuf dead after FFN1

  dim3 blk(256);
  // merged prologue: 3 launches (QKV transposes, conv+concat, FFN transposes)
  wtrans_qkv<<<dim3(2, 32, 48), blk, 0, stream>>>(Wq, Wk, Wvd, wqkvT);
  wconv_bconcat<<<dim3(42), blk, 0, stream>>>(Wvu, wvuB, bq, bk, bvd, bqkv);
  wtrans_ffn<<<dim3(128, 32, 2), blk, 0, stream>>>(W1, W2, w1T, w2T);
  ln_kernel<<<dim3(M_), blk, 0, stream>>>(x, (const u16*)nullptr, ln1_g, ln1_b,
                                          hbuf, (u16*)nullptr);
  // fused QKV projection (2-phase 128² — 640 blocks, 2.5/CU, T1-swizzled)
  gemm_nt<0><<<dim3(20, 32), blk, 0, stream>>>(hbuf, wqkvT, 1024, 1024, 1024, bqkv,
                                               (const float*)nullptr, (void*)cqkv,
                                               (void*)nullptr, NQKV);
  vu_kernel<<<dim3(S_ / 64, H_, B_), blk, 0, stream>>>(cqkv, wvuB, bvu, vT);
  // attention v4 + defer-max: grid (H, B, 8), 512 threads, 48KB dynamic LDS
  attn_kernel<<<dim3(H_, B_, 8), dim3(512), 49152, stream>>>(cqkv, vT, ob16);
  ln_kernel<<<dim3(M_), blk, 0, stream>>>(x, ob16, ln2_g, ln2_b, hbuf, x2);
  // FFN1: 256² R7 pipeline, grid 16x16 = 1 block/CU, T1-swizzled
  gemm8<1><<<dim3(16, 16, 1), dim3(512), 131072, stream>>>(
      hbuf, w1T, 1024, 1024, 16, b1, ubuf,
      (u16*)nullptr, (u16*)nullptr, (u16*)nullptr, (u16*)nullptr, 4096);
  // FFN2: split-K=4, grid 4x16x4, T1-swizzled per z; all z -> bf16 partials
  gemm8<4><<<dim3(4, 16, 4), dim3(512), 131072, stream>>>(
      ubuf, w2T, 4096, 4096, 16, (const float*)nullptr, (u16*)nullptr,
      p0, p1, p2, p3, 1024);
  // out = p0+p1+p2+p3 + b2 + x2
  reduce2<<<dim3(M_ * D_ / 1024), blk, 0, stream>>>(out, p0, p1, p2, p3, b2, x2);
}

// Round 23
// 210.976 us; speedup vs baseline: 1.1490x; 1.0138x over previous
//
#include <hip/hip_runtime.h>

// ---------------------------------------------------------------------------
// TransformerBlock: LN1 -> QKV proj (fused) -> reversed-causal attention
// (scale 1/sqrt(D)=1/32) -> residual -> LN2 -> GELU FFN -> residual.
// B=2 S=2048 D=1024 H=16 HD=64 R=32 F=4096. All d_in/d_out fp32; internal
// compute bf16 MFMA.
// R22: attn grid 256 -> 512 blocks (2 blocks/CU, 16 waves/CU): each block
// does ONE q-tile; z-map t = z<8 ? z : 23-z pairs complementary step counts
// (32-2t) + (2+2t) = 34 on blocks id/id+256 (round-robin same CU) — same
// per-CU work as triangle pairing but two independent chains interleave.
// Body unchanged. Rest = R22 verified composite.
// ---------------------------------------------------------------------------

typedef unsigned short u16;
typedef __attribute__((ext_vector_type(4))) float f32x4;
typedef __attribute__((ext_vector_type(8))) __bf16 bf16x8;

#define B_ 2
#define S_ 2048
#define D_ 1024
#define H_ 16
#define HD_ 64
#define R_ 32
#define F_ 4096
#define M_ (B_ * S_)   // 4096 rows
#define NQKV 2560      // 1024 q + 1024 k + 512 vd
// (1/sqrt(D)) * log2(e): folded into Wq/bq so QK^T scores are exp2-ready
#define C2F 0.04508422002778011f

__device__ __forceinline__ u16 f2bf(float f) {
  union { float f; unsigned u; } v; v.f = f;
  unsigned u = v.u;
  return (u16)((u + 0x7FFFu + ((u >> 16) & 1u)) >> 16);  // RNE
}
__device__ __forceinline__ float bf2f(u16 h) {
  union { unsigned u; float f; } v; v.u = ((unsigned)h) << 16;
  return v.f;
}
__device__ __forceinline__ unsigned pk_bf16(float lo, float hi) {
  unsigned r;
  asm volatile("v_cvt_pk_bf16_f32 %0, %1, %2" : "=v"(r) : "v"(lo), "v"(hi));
  return r;
}

typedef __attribute__((address_space(1))) void gvoid;
typedef __attribute__((address_space(3))) void lvoid;
// async global->LDS, 16B/lane; lds base must be wave-uniform (lane*16 implicit)
__device__ __forceinline__ void gload_lds16(const void* g, void* l) {
  __builtin_amdgcn_global_load_lds((gvoid*)(void*)g, (lvoid*)l, 16, 0, 0);
}

__device__ __forceinline__ float gelu_f(float x) {
  float t = tanhf(0.7978845608028654f * (x + 0.044715f * x * x * x));
  return 0.5f * x * (1.0f + t);
}

// ---- merged QKV weight transpose: grid (2, 32, 48) ------------------------
// z<16: Wq head z (scale C2F); z<32: Wk head z-16; z>=32: Wvd head z-32
// (Cc=32, only blockIdx.x==0 active).
__global__ __launch_bounds__(256) void wtrans_qkv(const float* __restrict__ Wq,
                                                  const float* __restrict__ Wk,
                                                  const float* __restrict__ Wvd,
                                                  u16* __restrict__ wqkvT) {
  __shared__ float tile[32][33];
  int z = blockIdx.z;
  const float* ip;
  u16* op;
  int Cc;
  float scale;
  if (z < 16) {
    ip = Wq + (size_t)z * 65536;
    op = wqkvT + (size_t)z * 65536;
    Cc = 64; scale = C2F;
  } else if (z < 32) {
    ip = Wk + (size_t)(z - 16) * 65536;
    op = wqkvT + 1048576 + (size_t)(z - 16) * 65536;
    Cc = 64; scale = 1.0f;
  } else {
    if (blockIdx.x != 0) return;
    ip = Wvd + (size_t)(z - 32) * 32768;
    op = wqkvT + 2097152 + (size_t)(z - 32) * 32768;
    Cc = 32; scale = 1.0f;
  }
  int c0 = blockIdx.x * 32, r0 = blockIdx.y * 32;
  int tx = threadIdx.x & 31, ty = threadIdx.x >> 5;  // 32 x 8
#pragma unroll
  for (int j = 0; j < 32; j += 8)
    tile[ty + j][tx] = ip[(size_t)(r0 + ty + j) * Cc + c0 + tx];
  __syncthreads();
#pragma unroll
  for (int j = 0; j < 32; j += 8)
    op[(size_t)(c0 + ty + j) * 1024 + r0 + tx] = f2bf(tile[tx][ty + j] * scale);
}

// ---- merged FFN weight transpose: grid (128, 32, 2) -----------------------
// z=0: W1 [1024x4096] -> w1T [4096][1024] (direct 128x32 tiling)
// z=1: W2 [4096x1024] -> w2T [1024][4096]; (x,y) -> (x&31, y*4 + x>>5)
__global__ __launch_bounds__(256) void wtrans_ffn(const float* __restrict__ W1,
                                                  const float* __restrict__ W2,
                                                  u16* __restrict__ w1T,
                                                  u16* __restrict__ w2T) {
  __shared__ float tile[32][33];
  const float* ip;
  u16* op;
  int Rr, Cc, bx, by;
  if (blockIdx.z == 0) {
    ip = W1; op = w1T; Rr = 1024; Cc = 4096;
    bx = blockIdx.x; by = blockIdx.y;
  } else {
    ip = W2; op = w2T; Rr = 4096; Cc = 1024;
    bx = blockIdx.x & 31; by = blockIdx.y * 4 + (blockIdx.x >> 5);
  }
  int c0 = bx * 32, r0 = by * 32;
  int tx = threadIdx.x & 31, ty = threadIdx.x >> 5;  // 32 x 8
#pragma unroll
  for (int j = 0; j < 32; j += 8)
    tile[ty + j][tx] = ip[(size_t)(r0 + ty + j) * Cc + c0 + tx];
  __syncthreads();
#pragma unroll
  for (int j = 0; j < 32; j += 8)
    op[(size_t)(c0 + ty + j) * Rr + r0 + tx] = f2bf(tile[tx][ty + j]);
}

// ---- merged: wconv(Wvu->bf16, 32 blocks) + bconcat (10 blocks) -------------
__global__ __launch_bounds__(256) void wconv_bconcat(const float* __restrict__ Wvu,
                                                     u16* __restrict__ wvuB,
                                                     const float* __restrict__ bq,
                                                     const float* __restrict__ bk,
                                                     const float* __restrict__ bvd,
                                                     float* __restrict__ bqkv) {
  int bid = blockIdx.x;
  if (bid < 32) {
    int i = (bid * 256 + threadIdx.x) * 4;
    if (i < H_ * R_ * HD_) {
      float4 v = *(const float4*)&Wvu[i];
      ushort4 o;
      o.x = f2bf(v.x); o.y = f2bf(v.y); o.z = f2bf(v.z); o.w = f2bf(v.w);
      *(ushort4*)&wvuB[i] = o;
    }
  } else {
    int i = (bid - 32) * 256 + threadIdx.x;
    if (i < NQKV) {
      float v = (i < 1024) ? bq[i] * C2F : (i < 2048 ? bk[i - 1024] : bvd[i - 2048]);
      bqkv[i] = v;
    }
  }
}

// ---- LayerNorm (optional bf16 residual addin + bf16 x2 passthrough) --------
__global__ __launch_bounds__(256) void ln_kernel(const float* __restrict__ xin,
                                                 const u16* __restrict__ addin,
                                                 const float* __restrict__ gam,
                                                 const float* __restrict__ bet,
                                                 u16* __restrict__ hout,
                                                 u16* __restrict__ x2out) {
  int row = blockIdx.x, tid = threadIdx.x;
  size_t base = (size_t)row * D_ + tid * 4;
  float4 v = *(const float4*)&xin[base];
  if (addin) {
    ushort4 a = *(const ushort4*)&addin[base];
    v.x += bf2f(a.x); v.y += bf2f(a.y); v.z += bf2f(a.z); v.w += bf2f(a.w);
  }
  if (x2out) {
    ushort4 xo;
    xo.x = f2bf(v.x); xo.y = f2bf(v.y); xo.z = f2bf(v.z); xo.w = f2bf(v.w);
    *(ushort4*)&x2out[base] = xo;
  }
  float s = v.x + v.y + v.z + v.w;
  float ss = v.x * v.x + v.y * v.y + v.z * v.z + v.w * v.w;
#pragma unroll
  for (int off = 32; off > 0; off >>= 1) {
    s += __shfl_down(s, off);
    ss += __shfl_down(ss, off);
  }
  __shared__ float red[8];
  int wv = tid >> 6;
  if ((tid & 63) == 0) { red[wv] = s; red[4 + wv] = ss; }
  __syncthreads();
  if (tid == 0) {
    float s1 = red[0] + red[1] + red[2] + red[3];
    float s2 = red[4] + red[5] + red[6] + red[7];
    float mu = s1 * (1.0f / D_);
    red[0] = mu;
    red[1] = s2 * (1.0f / D_) - mu * mu;
  }
  __syncthreads();
  float mu = red[0];
  float rstd = rsqrtf(red[1] + 1e-5f);
  int ci = tid * 4;
  ushort4 o;
  o.x = f2bf((v.x - mu) * rstd * gam[ci + 0] + bet[ci + 0]);
  o.y = f2bf((v.y - mu) * rstd * gam[ci + 1] + bet[ci + 1]);
  o.z = f2bf((v.z - mu) * rstd * gam[ci + 2] + bet[ci + 2]);
  o.w = f2bf((v.w - mu) * rstd * gam[ci + 3] + bet[ci + 3]);
  *(ushort4*)&hout[base] = o;
}

// ---- NT GEMM (128x128, 2-phase dbuf): used for the fused QKV projection ---
// T1: XCD-aware block swizzle (nwg = 20*32 = 640, %8==0 -> bijective).
template <int MODE>
__global__ __launch_bounds__(256) void gemm_nt(const u16* __restrict__ A,
                                               const u16* __restrict__ Bt,
                                               int K, int lda, int ldb,
                                               const float* __restrict__ bias,
                                               const float* __restrict__ res,
                                               void* __restrict__ Cout,
                                               void* __restrict__ Cout2, int ldc) {
  __shared__ __align__(16) u16 As0[128 * 32];
  __shared__ __align__(16) u16 Bs0[128 * 32];
  __shared__ __align__(16) u16 As1[128 * 32];
  __shared__ __align__(16) u16 Bs1[128 * 32];
  int tid = threadIdx.x;
  int lane = tid & 63, wid = tid >> 6;
  int wm = wid >> 1, wn = wid & 1;
  int bid = blockIdx.x + gridDim.x * blockIdx.y;
  int nwg = gridDim.x * gridDim.y;
  int swz = (bid & 7) * (nwg >> 3) + (bid >> 3);
  int tbx = swz % gridDim.x, tby = swz / gridDim.x;
  int row0 = tby * 128, col0 = tbx * 128;
  int l15 = lane & 15, g = lane >> 4;
  int srow = lane >> 2, scol = (lane & 3) * 8;
  f32x4 acc[4][4] = {};
  const u16* Ap = A + (size_t)row0 * lda;
  const u16* Bp = Bt + (size_t)col0 * ldb;

  auto STAGE = [&](u16* AS, u16* BS, int kk) {
#pragma unroll
    for (int i = 0; i < 2; ++i) {
      int c = wid * 2 + i;
      gload_lds16(Ap + (size_t)(c * 16 + srow) * lda + kk + scol, &AS[c * 512]);
      gload_lds16(Bp + (size_t)(c * 16 + srow) * ldb + kk + scol, &BS[c * 512]);
    }
  };
  auto COMPUTE = [&](const u16* AS, const u16* BS) {
    bf16x8 af[4], bfr[4];
#pragma unroll
    for (int t = 0; t < 4; ++t) {
      af[t] = *(const bf16x8*)&AS[(wm * 64 + t * 16 + l15) * 32 + g * 8];
      bfr[t] = *(const bf16x8*)&BS[(wn * 64 + t * 16 + l15) * 32 + g * 8];
    }
#pragma unroll
    for (int mt = 0; mt < 4; ++mt)
#pragma unroll
      for (int nt = 0; nt < 4; ++nt)
        acc[mt][nt] = __builtin_amdgcn_mfma_f32_16x16x32_bf16(af[mt], bfr[nt],
                                                              acc[mt][nt], 0, 0, 0);
  };

  STAGE(As0, Bs0, 0);
  __syncthreads();
  for (int k0 = 0; k0 < K; k0 += 64) {
    if (k0 + 32 < K) STAGE(As1, Bs1, k0 + 32);
    COMPUTE(As0, Bs0);
    __syncthreads();
    if (k0 + 64 < K) STAGE(As0, Bs0, k0 + 64);
    COMPUTE(As1, Bs1);
    __syncthreads();
  }

#pragma unroll
  for (int mt = 0; mt < 4; ++mt) {
#pragma unroll
    for (int nt = 0; nt < 4; ++nt) {
      int cc = col0 + wn * 64 + nt * 16 + l15;
      float bv = bias ? bias[cc] : 0.0f;
#pragma unroll
      for (int j = 0; j < 4; ++j) {
        int rr = row0 + wm * 64 + mt * 16 + g * 4 + j;
        float v = acc[mt][nt][j] + bv;
        if (MODE == 1) v = gelu_f(v);
        if (MODE == 2) {
          ((float*)Cout)[(size_t)rr * ldc + cc] = v + res[(size_t)rr * ldc + cc];
        } else {
          ((u16*)Cout)[(size_t)rr * ldc + cc] = f2bf(v);
        }
      }
    }
  }
  (void)Cout2;
}

// ---- gemm8 (R7 schedule): 256x256, BK=64, 2-slot dbuf, stage interleaved ---
// MODE 1: bf16 gelu(v+bias) -> Cb. MODE 4: split-K, all z -> bf16 partials.
template <int MODE>
__global__ __launch_bounds__(512, 2) void gemm8(
    const u16* __restrict__ A, const u16* __restrict__ Bt,
    int lda, int ldb, int nk,
    const float* __restrict__ bias,
    u16* __restrict__ Cb,
    u16* __restrict__ P0, u16* __restrict__ P1,
    u16* __restrict__ P2, u16* __restrict__ P3,
    int ldc) {
  extern __shared__ __align__(16) char smem[];
  int tid = threadIdx.x;
  int lane = tid & 63, wid = tid >> 6;
  int wm = wid >> 2, wn = wid & 3;
  int l15 = lane & 15, g = lane >> 4;
  int bid = blockIdx.x + gridDim.x * blockIdx.y;
  int nwg = gridDim.x * gridDim.y;
  int swz = (bid & 7) * (nwg >> 3) + (bid >> 3);
  int tbx = swz % gridDim.x, tby = swz / gridDim.x;
  int row0 = tby * 256, col0 = tbx * 256;
  int koff = (MODE == 4) ? blockIdx.z * (nk * 64) : 0;
  const u16* Ap = A + (size_t)row0 * lda + koff;
  const u16* Bp = Bt + (size_t)col0 * ldb + koff;
  int trow = tid >> 3;
  int sbyte = ((tid & 7) * 16) ^ ((trow & 7) << 4);
  int xr = (l15 & 7) << 4;

  f32x4 acc[8][4] = {};

  auto STAGE_A = [&](int buf, int kt) {
#pragma unroll
    for (int l = 0; l < 4; ++l)
      gload_lds16((const char*)(Ap + (size_t)(l * 64 + trow) * lda + kt) + sbyte,
                  smem + buf * 65536 + (l * 64 + wid * 8) * 128);
  };
  auto STAGE_B = [&](int buf, int kt) {
#pragma unroll
    for (int l = 0; l < 4; ++l)
      gload_lds16((const char*)(Bp + (size_t)(l * 64 + trow) * ldb + kt) + sbyte,
                  smem + buf * 65536 + 32768 + (l * 64 + wid * 8) * 128);
  };

  STAGE_A(0, 0);
  STAGE_B(0, 0);
  asm volatile("s_waitcnt vmcnt(0)" ::: "memory");
  __builtin_amdgcn_sched_barrier(0);
  __builtin_amdgcn_s_barrier();

  int cur = 0;
  for (int it = 0; it < nk; ++it) {
    const char* Ab = smem + cur * 65536 + (size_t)(wm * 128 + l15) * 128;
    const char* Bb = smem + cur * 65536 + 32768 + (size_t)(wn * 64 + l15) * 128;
    bool nxt = (it + 1 < nk);
#pragma unroll
    for (int kk = 0; kk < 2; ++kk) {
      int kq = (kk * 64 + g * 16) ^ xr;
      bf16x8 bfr[4], af[8];
#pragma unroll
      for (int nt = 0; nt < 4; ++nt)
        bfr[nt] = *(const bf16x8*)(Bb + nt * 2048 + kq);
#pragma unroll
      for (int mt = 0; mt < 8; ++mt)
        af[mt] = *(const bf16x8*)(Ab + mt * 2048 + kq);
      if (nxt) {
        if (kk == 0) STAGE_A(cur ^ 1, (it + 1) * 64);
        else         STAGE_B(cur ^ 1, (it + 1) * 64);
      }
      __builtin_amdgcn_s_setprio(1);
#pragma unroll
      for (int mt = 0; mt < 8; ++mt)
#pragma unroll
        for (int nt = 0; nt < 4; ++nt)
          acc[mt][nt] = __builtin_amdgcn_mfma_f32_16x16x32_bf16(af[mt], bfr[nt],
                                                                acc[mt][nt], 0, 0, 0);
      __builtin_amdgcn_s_setprio(0);
    }
    asm volatile("s_waitcnt vmcnt(0)" ::: "memory");
    __builtin_amdgcn_sched_barrier(0);
    __builtin_amdgcn_s_barrier();
    cur ^= 1;
  }

  u16* pp = Cb;
  if (MODE == 4)
    pp = (blockIdx.z == 0) ? P0
       : (blockIdx.z == 1) ? P1
       : (blockIdx.z == 2) ? P2 : P3;
#pragma unroll
  for (int mt = 0; mt < 8; ++mt) {
#pragma unroll
    for (int nt = 0; nt < 4; ++nt) {
      int cc = col0 + wn * 64 + nt * 16 + l15;
      float bv = (MODE == 1) ? bias[cc] : 0.0f;
#pragma unroll
      for (int j = 0; j < 4; ++j) {
        int rr = row0 + wm * 128 + mt * 16 + g * 4 + j;
        float v = acc[mt][nt][j] + bv;
        if (MODE == 1) {
          pp[(size_t)rr * ldc + cc] = f2bf(gelu_f(v));
        } else {
          pp[(size_t)rr * ldc + cc] = f2bf(v);
        }
      }
    }
  }
}

// ---- split-K reduce: out = p0+p1+p2+p3 (bf16) + b2[col] + x2 (bf16) --------
__global__ __launch_bounds__(256) void reduce2(float* __restrict__ out,
                                               const u16* __restrict__ p0,
                                               const u16* __restrict__ p1,
                                               const u16* __restrict__ p2,
                                               const u16* __restrict__ p3,
                                               const float* __restrict__ b2,
                                               const u16* __restrict__ x2) {
  int i = (blockIdx.x * 256 + threadIdx.x) * 4;
  ushort4 a0 = *(const ushort4*)&p0[i];
  ushort4 a = *(const ushort4*)&p1[i];
  ushort4 b = *(const ushort4*)&p2[i];
  ushort4 c = *(const ushort4*)&p3[i];
  ushort4 r = *(const ushort4*)&x2[i];
  int cix = i & (D_ - 1);
  float4 o;
  o.x = bf2f(a0.x) + bf2f(a.x) + bf2f(b.x) + bf2f(c.x) + b2[cix + 0] + bf2f(r.x);
  o.y = bf2f(a0.y) + bf2f(a.y) + bf2f(b.y) + bf2f(c.y) + b2[cix + 1] + bf2f(r.y);
  o.z = bf2f(a0.z) + bf2f(a.z) + bf2f(b.z) + bf2f(c.z) + b2[cix + 2] + bf2f(r.z);
  o.w = bf2f(a0.w) + bf2f(a.w) + bf2f(b.w) + bf2f(c.w) + b2[cix + 3] + bf2f(r.w);
  *(float4*)&out[i] = o;
}

// ---- low-rank V up-proj -> V^T [b,h][e][t] bf16 ----------------------------
__global__ __launch_bounds__(256) void vu_kernel(const u16* __restrict__ vd,
                                                 const u16* __restrict__ wvu,
                                                 const float* __restrict__ bvu,
                                                 u16* __restrict__ v_t) {
  int t0 = blockIdx.x * 64, h = blockIdx.y, b = blockIdx.z;
  __shared__ u16 vds[64][32];
  __shared__ u16 vt[64][65];
  int tid = threadIdx.x;
  {
    int rr2 = tid >> 2, c8 = (tid & 3) * 8;
    *(bf16x8*)&vds[rr2][c8] =
        *(const bf16x8*)&vd[(size_t)(b * S_ + t0 + rr2) * NQKV + 2048 + h * R_ + c8];
  }
  __syncthreads();
  int e = tid & 63, tg = (tid >> 6) * 16;
  float wcol[32];
#pragma unroll
  for (int r = 0; r < 32; ++r) wcol[r] = bf2f(wvu[((size_t)h * R_ + r) * HD_ + e]);
  float bb = bvu[h * HD_ + e];
  for (int i = 0; i < 16; ++i) {
    int t = tg + i;
    float acc = bb;
#pragma unroll
    for (int r = 0; r < 32; ++r) acc += bf2f(vds[t][r]) * wcol[r];
    vt[t][e] = f2bf(acc);
  }
  __syncthreads();
  for (int idx = tid; idx < 64 * 64; idx += 256) {
    int e2 = idx >> 6, t2 = idx & 63;
    v_t[((size_t)(b * H_ + h) * HD_ + e2) * S_ + t0 + t2] = vt[t2][e2];
  }
}

// ---- attention v4.1 + T13 defer-max: reversed-causal (key t >= query s) ----
// grid (H, B, 16) = 512 blocks (2 blocks/CU, 16 waves/CU). Each block does
// ONE q-tile; z-map t = z<8 ? z : 23-z pairs complementary step counts on
// blocks id/id+256. 8 waves x 16 q; counted-vmcnt 3-buffer ring; bf16 out.
__global__ __launch_bounds__(512, 2) void attn_kernel(const u16* __restrict__ cqkv,
                                                      const u16* __restrict__ v_t,
                                                      u16* __restrict__ o) {
  extern __shared__ __align__(16) u16 kv[];  // 3 bufs x (K 4096 + V 4096) u16
  __shared__ u16 Pl[8][16 * 64];             // per-wave Q then P^T tile
  int tid = threadIdx.x;
  int lane = tid & 63, w = tid >> 6;
  int h = blockIdx.x, b = blockIdx.y;
  int zz = blockIdx.z;
  int tq = (zz < 8) ? zz : 23 - zz;          // q-tile index 0..15
  int r = lane & 15, g = lane >> 4;
  const u16* qp = cqkv + (size_t)(b * S_) * NQKV + h * HD_;
  const u16* kp = cqkv + (size_t)(b * S_) * NQKV + 1024 + h * HD_;
  const u16* vp = v_t + (size_t)(b * H_ + h) * HD_ * S_;
  u16* Pw = Pl[w];

  int srow = w * 8 + (lane >> 3);
  int ssw = ((lane & 7) * 16) ^ (((lane >> 3) & 7) << 4);  // pre-swz byte in row

  int xr = (r & 7) << 4;                // read-side XOR (rows = ..*16 + r)
  int kq0 = ((g * 16) ^ xr) >> 1;       // elem offset, k-group 0
  int kq1 = ((64 + g * 16) ^ xr) >> 1;  // elem offset, k-group 1

  auto STAGE = [&](int buf, int kt) {
    u16* base = kv + buf * 8192;
    gload_lds16((const char*)(kp + (size_t)(kt + srow) * NQKV) + ssw,
                base + w * 512);
    gload_lds16((const char*)(vp + (size_t)srow * S_ + kt) + ssw,
                base + 4096 + w * 512);
  };

  {
    int qb = tq * 128;
    int s0 = qb + w * 16;
    int qrow = s0 + r;

    gload_lds16((const char*)(qp + (size_t)(s0 + (lane >> 3)) * NQKV) + ssw, Pw);
    gload_lds16((const char*)(qp + (size_t)(s0 + 8 + (lane >> 3)) * NQKV) + ssw,
                Pw + 512);
    asm volatile("s_waitcnt vmcnt(0)" ::: "memory");
    __builtin_amdgcn_sched_barrier(0);
    __builtin_amdgcn_s_barrier();
    __builtin_amdgcn_sched_barrier(0);
    bf16x8 aq0 = *(const bf16x8*)&Pw[(r << 6) + kq0];
    bf16x8 aq1 = *(const bf16x8*)&Pw[(r << 6) + kq1];

    f32x4 oa[4] = {};
    float m_ = -1e30f, l_ = 0.0f;

    int nt = (S_ - qb) >> 6;
    STAGE(0, qb);
    STAGE(1, qb + 64);

    for (int it = 0; it < nt; ++it) {
      int kt = qb + it * 64;
      if (it + 1 < nt) {
        asm volatile("s_waitcnt vmcnt(2)" ::: "memory");
      } else {
        asm volatile("s_waitcnt vmcnt(0)" ::: "memory");
      }
      __builtin_amdgcn_sched_barrier(0);
      __builtin_amdgcn_s_barrier();
      __builtin_amdgcn_sched_barrier(0);
      if (it + 2 < nt) STAGE((it + 2) % 3, qb + (it + 2) * 64);

      if (kt + 64 > s0) {
        const u16* Kb = kv + (it % 3) * 8192;
        const u16* Vb = Kb + 4096;

        f32x4 sc[4] = {};
#pragma unroll
        for (int blk = 0; blk < 4; ++blk) {
          bf16x8 a0 = *(const bf16x8*)&Kb[((blk * 16 + r) << 6) + kq0];
          bf16x8 a1 = *(const bf16x8*)&Kb[((blk * 16 + r) << 6) + kq1];
          sc[blk] = __builtin_amdgcn_mfma_f32_16x16x32_bf16(a0, aq0, sc[blk], 0, 0, 0);
          sc[blk] = __builtin_amdgcn_mfma_f32_16x16x32_bf16(a1, aq1, sc[blk], 0, 0, 0);
        }

        float p[16];
        if ((qrow & ~63) == kt) {
#pragma unroll
          for (int blk = 0; blk < 4; ++blk)
#pragma unroll
            for (int j = 0; j < 4; ++j) {
              int kk = kt + blk * 16 + g * 4 + j;
              p[blk * 4 + j] = (kk < qrow) ? -1e30f : sc[blk][j];
            }
        } else {
#pragma unroll
          for (int blk = 0; blk < 4; ++blk)
#pragma unroll
            for (int j = 0; j < 4; ++j) p[blk * 4 + j] = sc[blk][j];
        }
        float mx = p[0];
#pragma unroll
        for (int i = 1; i < 16; ++i) mx = fmaxf(mx, p[i]);
        mx = fmaxf(mx, __shfl_xor(mx, 16));
        mx = fmaxf(mx, __shfl_xor(mx, 32));
        // T13 defer-max: only rescale when max grew by > 8 (exp2 domain)
        if (!__all(mx <= m_ + 8.0f)) {
          float mn = fmaxf(m_, mx);
          float scl = __builtin_amdgcn_exp2f(m_ - mn);
          m_ = mn;
          l_ *= scl;
#pragma unroll
          for (int et = 0; et < 4; ++et) oa[et] *= scl;
        }
        float sm = 0.0f;
#pragma unroll
        for (int i = 0; i < 16; ++i) {
          p[i] = __builtin_amdgcn_exp2f(p[i] - m_);
          sm += p[i];
        }
        sm += __shfl_xor(sm, 16);
        sm += __shfl_xor(sm, 32);
        l_ += sm;

#pragma unroll
        for (int blk = 0; blk < 4; ++blk) {
          uint2 pk;
          pk.x = pk_bf16(p[blk * 4 + 0], p[blk * 4 + 1]);
          pk.y = pk_bf16(p[blk * 4 + 2], p[blk * 4 + 3]);
          *(uint2*)&Pw[(r << 6) + ((((blk << 5) + (g << 3)) ^ xr) >> 1)] = pk;
        }
        asm volatile("s_waitcnt lgkmcnt(0)" ::: "memory");
        __builtin_amdgcn_sched_barrier(0);
        bf16x8 pb0 = *(const bf16x8*)&Pw[(r << 6) + kq0];
        bf16x8 pb1 = *(const bf16x8*)&Pw[(r << 6) + kq1];
#pragma unroll
        for (int et = 0; et < 4; ++et) {
          bf16x8 v0 = *(const bf16x8*)&Vb[((et * 16 + r) << 6) + kq0];
          bf16x8 v1 = *(const bf16x8*)&Vb[((et * 16 + r) << 6) + kq1];
          oa[et] = __builtin_amdgcn_mfma_f32_16x16x32_bf16(v0, pb0, oa[et], 0, 0, 0);
          oa[et] = __builtin_amdgcn_mfma_f32_16x16x32_bf16(v1, pb1, oa[et], 0, 0, 0);
        }
      }
    }

    float inv = 1.0f / l_;
#pragma unroll
    for (int et = 0; et < 4; ++et)
#pragma unroll
      for (int j = 0; j < 4; ++j)
        o[(size_t)(b * S_ + s0 + r) * D_ + h * HD_ + et * 16 + g * 4 + j] =
            f2bf(oa[et][j] * inv);
  }
}

// one-time (dlopen) LDS-limit raise for dynamic-shared kernels
namespace {
struct GemmAttrInit {
  GemmAttrInit() {
    hipFuncSetAttribute((const void*)gemm8<1>,
                        hipFuncAttributeMaxDynamicSharedMemorySize, 131072);
    hipFuncSetAttribute((const void*)gemm8<4>,
                        hipFuncAttributeMaxDynamicSharedMemorySize, 131072);
    hipFuncSetAttribute((const void*)attn_kernel,
                        hipFuncAttributeMaxDynamicSharedMemorySize, 49152);
  }
};
GemmAttrInit _gemm_attr_init;
}  // namespace

extern "C" void kernel_launch(void* const* d_in, const int* in_sizes, int n_in,
                              void* d_out, int out_size, void* d_ws, size_t ws_size,
                              hipStream_t stream) {
  const float* x = (const float*)d_in[0];
  const float* ln1_g = (const float*)d_in[1];
  const float* ln1_b = (const float*)d_in[2];
  const float* Wq = (const float*)d_in[3];
  const float* bq = (const float*)d_in[4];
  const float* Wk = (const float*)d_in[5];
  const float* bk = (const float*)d_in[6];
  const float* Wvd = (const float*)d_in[7];
  const float* bvd = (const float*)d_in[8];
  const float* Wvu = (const float*)d_in[9];
  const float* bvu = (const float*)d_in[10];
  const float* ln2_g = (const float*)d_in[11];
  const float* ln2_b = (const float*)d_in[12];
  const float* W1 = (const float*)d_in[13];
  const float* b1 = (const float*)d_in[14];
  const float* W2 = (const float*)d_in[15];
  const float* b2 = (const float*)d_in[16];
  float* out = (float*)d_out;
  (void)in_sizes; (void)n_in; (void)out_size; (void)ws_size;

  char* ws = (char*)d_ws;
  const size_t MB = 1024 * 1024;
  const size_t KB = 1024;
  u16* wqkvT = (u16*)(ws + 0);                    // [2560x1024] bf16, 5 MB
  u16* wvuB = (u16*)(ws + 5 * MB);                // 64 KB
  float* bqkv = (float*)(ws + 5 * MB + 64 * KB);  // 10 KB
  u16* w1T = (u16*)(ws + 5 * MB + 384 * KB);      // 8 MB -> 13.375
  u16* w2T = (u16*)(ws + 13 * MB + 384 * KB);     // 8 MB -> 21.375
  u16* hbuf = (u16*)(ws + 21 * MB + 384 * KB);    // 8 MB -> 29.375
  u16* cqkv = (u16*)(ws + 29 * MB + 384 * KB);    // 20 MB -> 49.375
  u16* vT = (u16*)(ws + 49 * MB + 384 * KB);      // 8 MB -> 57.375
  u16* ob16 = (u16*)(ws + 57 * MB + 384 * KB);    // 8 MB (bf16) -> 65.375
  u16* p3 = (u16*)(ws + 65 * MB + 384 * KB);      // 8 MB -> 73.375 (outside ubuf)
  u16* x2 = (u16*)(ws + 73 * MB + 384 * KB);      // 8 MB (bf16) -> 81.375
  u16* p0 = (u16*)(ws + 81 * MB + 384 * KB);      // 8 MB -> 89.375
  // lifetime-disjoint reuses:
  u16* ubuf = cqkv;            // 32 MB (cqkv+vT+ob16[0:4MB]), dead by FFN1
  u16* p1 = (u16*)(ws + 0);    // 8 MB over wqkvT+..., dead by FFN2
  u16* p2 = (u16*)hbuf;        // 8 MB, hbuf dead after FFN1

  dim3 blk(256);
  // merged prologue: 3 launches (QKV transposes, conv+concat, FFN transposes)
  wtrans_qkv<<<dim3(2, 32, 48), blk, 0, stream>>>(Wq, Wk, Wvd, wqkvT);
  wconv_bconcat<<<dim3(42), blk, 0, stream>>>(Wvu, wvuB, bq, bk, bvd, bqkv);
  wtrans_ffn<<<dim3(128, 32, 2), blk, 0, stream>>>(W1, W2, w1T, w2T);
  ln_kernel<<<dim3(M_), blk, 0, stream>>>(x, (const u16*)nullptr, ln1_g, ln1_b,
                                          hbuf, (u16*)nullptr);
  // fused QKV projection (2-phase 128² — 640 blocks, 2.5/CU, T1-swizzled)
  gemm_nt<0><<<dim3(20, 32), blk, 0, stream>>>(hbuf, wqkvT, 1024, 1024, 1024, bqkv,
                                               (const float*)nullptr, (void*)cqkv,
                                               (void*)nullptr, NQKV);
  vu_kernel<<<dim3(S_ / 64, H_, B_), blk, 0, stream>>>(cqkv, wvuB, bvu, vT);
  // attention v4.1: grid (H, B, 16) = 512 blocks (2/CU), 48KB dynamic LDS
  attn_kernel<<<dim3(H_, B_, 16), dim3(512), 49152, stream>>>(cqkv, vT, ob16);
  ln_kernel<<<dim3(M_), blk, 0, stream>>>(x, ob16, ln2_g, ln2_b, hbuf, x2);
  // FFN1: 256² R7 pipeline, grid 16x16 = 1 block/CU, T1-swizzled
  gemm8<1><<<dim3(16, 16, 1), dim3(512), 131072, stream>>>(
      hbuf, w1T, 1024, 1024, 16, b1, ubuf,
      (u16*)nullptr, (u16*)nullptr, (u16*)nullptr, (u16*)nullptr, 4096);
  // FFN2: split-K=4, grid 4x16x4, T1-swizzled per z; all z -> bf16 partials
  gemm8<4><<<dim3(4, 16, 4), dim3(512), 131072, stream>>>(
      ubuf, w2T, 4096, 4096, 16, (const float*)nullptr, (u16*)nullptr,
      p0, p1, p2, p3, 1024);
  // out = p0+p1+p2+p3 + b2 + x2
  reduce2<<<dim3(M_ * D_ / 1024), blk, 0, stream>>>(out, p0, p1, p2, p3, b2, x2);
}

// Round 24
// 205.016 us; speedup vs baseline: 1.1824x; 1.0291x over previous
//
#include <hip/hip_runtime.h>

// ---------------------------------------------------------------------------
// TransformerBlock: LN1 -> QKV proj (fused) -> reversed-causal attention
// (scale 1/sqrt(D)=1/32) -> residual -> LN2 -> GELU FFN -> residual.
// B=2 S=2048 D=1024 H=16 HD=64 R=32 F=4096. All d_in/d_out fp32; internal
// compute bf16 MFMA.
// R23: mega-prologue — wtrans_qkv + wconv_bconcat + wtrans_ffn + LN1 merged
// into ONE launch (block-range dispatch; all bodies verbatim). 10 -> 7
// launches. Rest = R23 verified composite (attn v4.1 2-blocks/CU +
// defer-max, gemm8 256² R7-schedule FFNs, gemm_nt 128² QKV, T1 swizzles,
// bf16 intermediate streams).
// ---------------------------------------------------------------------------

typedef unsigned short u16;
typedef __attribute__((ext_vector_type(4))) float f32x4;
typedef __attribute__((ext_vector_type(8))) __bf16 bf16x8;

#define B_ 2
#define S_ 2048
#define D_ 1024
#define H_ 16
#define HD_ 64
#define R_ 32
#define F_ 4096
#define M_ (B_ * S_)   // 4096 rows
#define NQKV 2560      // 1024 q + 1024 k + 512 vd
// (1/sqrt(D)) * log2(e): folded into Wq/bq so QK^T scores are exp2-ready
#define C2F 0.04508422002778011f

__device__ __forceinline__ u16 f2bf(float f) {
  union { float f; unsigned u; } v; v.f = f;
  unsigned u = v.u;
  return (u16)((u + 0x7FFFu + ((u >> 16) & 1u)) >> 16);  // RNE
}
__device__ __forceinline__ float bf2f(u16 h) {
  union { unsigned u; float f; } v; v.u = ((unsigned)h) << 16;
  return v.f;
}
__device__ __forceinline__ unsigned pk_bf16(float lo, float hi) {
  unsigned r;
  asm volatile("v_cvt_pk_bf16_f32 %0, %1, %2" : "=v"(r) : "v"(lo), "v"(hi));
  return r;
}

typedef __attribute__((address_space(1))) void gvoid;
typedef __attribute__((address_space(3))) void lvoid;
// async global->LDS, 16B/lane; lds base must be wave-uniform (lane*16 implicit)
__device__ __forceinline__ void gload_lds16(const void* g, void* l) {
  __builtin_amdgcn_global_load_lds((gvoid*)(void*)g, (lvoid*)l, 16, 0, 0);
}

__device__ __forceinline__ float gelu_f(float x) {
  float t = tanhf(0.7978845608028654f * (x + 0.044715f * x * x * x));
  return 0.5f * x * (1.0f + t);
}

// ---- mega-prologue: one launch, block-range dispatch -----------------------
// [0,3072):      wtrans_qkv  (x=bid&1, y=(bid>>1)&31, z=bid>>6)
// [3072,3114):   wconv_bconcat (bid-3072)
// [3114,11306):  wtrans_ffn  (flat=bid-3114: x=flat&127, y=(flat>>7)&31, z=flat>>12)
// [11306,15402): LN1 row = bid-11306
__global__ __launch_bounds__(256) void prologue(
    const float* __restrict__ Wq, const float* __restrict__ Wk,
    const float* __restrict__ Wvd, u16* __restrict__ wqkvT,
    const float* __restrict__ Wvu, u16* __restrict__ wvuB,
    const float* __restrict__ bq, const float* __restrict__ bk,
    const float* __restrict__ bvd, float* __restrict__ bqkv,
    const float* __restrict__ W1, const float* __restrict__ W2,
    u16* __restrict__ w1T, u16* __restrict__ w2T,
    const float* __restrict__ x, const float* __restrict__ ln1_g,
    const float* __restrict__ ln1_b, u16* __restrict__ hbuf) {
  __shared__ float tile[32][33];
  __shared__ float red[8];
  int bid = blockIdx.x;
  int tid = threadIdx.x;

  if (bid < 3072) {
    // ---- wtrans_qkv ----
    int bx = bid & 1, by = (bid >> 1) & 31, z = bid >> 6;
    const float* ip;
    u16* op;
    int Cc;
    float scale;
    if (z < 16) {
      ip = Wq + (size_t)z * 65536;
      op = wqkvT + (size_t)z * 65536;
      Cc = 64; scale = C2F;
    } else if (z < 32) {
      ip = Wk + (size_t)(z - 16) * 65536;
      op = wqkvT + 1048576 + (size_t)(z - 16) * 65536;
      Cc = 64; scale = 1.0f;
    } else {
      if (bx != 0) return;
      ip = Wvd + (size_t)(z - 32) * 32768;
      op = wqkvT + 2097152 + (size_t)(z - 32) * 32768;
      Cc = 32; scale = 1.0f;
    }
    int c0 = bx * 32, r0 = by * 32;
    int tx = tid & 31, ty = tid >> 5;
#pragma unroll
    for (int j = 0; j < 32; j += 8)
      tile[ty + j][tx] = ip[(size_t)(r0 + ty + j) * Cc + c0 + tx];
    __syncthreads();
#pragma unroll
    for (int j = 0; j < 32; j += 8)
      op[(size_t)(c0 + ty + j) * 1024 + r0 + tx] = f2bf(tile[tx][ty + j] * scale);
  } else if (bid < 3114) {
    // ---- wconv_bconcat ----
    int b2id = bid - 3072;
    if (b2id < 32) {
      int i = (b2id * 256 + tid) * 4;
      if (i < H_ * R_ * HD_) {
        float4 v = *(const float4*)&Wvu[i];
        ushort4 o;
        o.x = f2bf(v.x); o.y = f2bf(v.y); o.z = f2bf(v.z); o.w = f2bf(v.w);
        *(ushort4*)&wvuB[i] = o;
      }
    } else {
      int i = (b2id - 32) * 256 + tid;
      if (i < NQKV) {
        float v = (i < 1024) ? bq[i] * C2F : (i < 2048 ? bk[i - 1024] : bvd[i - 2048]);
        bqkv[i] = v;
      }
    }
  } else if (bid < 11306) {
    // ---- wtrans_ffn ----
    int flat = bid - 3114;
    int fx = flat & 127, fy = (flat >> 7) & 31, fz = flat >> 12;
    const float* ip;
    u16* op;
    int Rr, Cc, bx, by;
    if (fz == 0) {
      ip = W1; op = w1T; Rr = 1024; Cc = 4096;
      bx = fx; by = fy;
    } else {
      ip = W2; op = w2T; Rr = 4096; Cc = 1024;
      bx = fx & 31; by = fy * 4 + (fx >> 5);
    }
    int c0 = bx * 32, r0 = by * 32;
    int tx = tid & 31, ty = tid >> 5;
#pragma unroll
    for (int j = 0; j < 32; j += 8)
      tile[ty + j][tx] = ip[(size_t)(r0 + ty + j) * Cc + c0 + tx];
    __syncthreads();
#pragma unroll
    for (int j = 0; j < 32; j += 8)
      op[(size_t)(c0 + ty + j) * Rr + r0 + tx] = f2bf(tile[tx][ty + j]);
  } else {
    // ---- LN1 (no addin, no x2out) ----
    int row = bid - 11306;
    size_t base = (size_t)row * D_ + tid * 4;
    float4 v = *(const float4*)&x[base];
    float s = v.x + v.y + v.z + v.w;
    float ss = v.x * v.x + v.y * v.y + v.z * v.z + v.w * v.w;
#pragma unroll
    for (int off = 32; off > 0; off >>= 1) {
      s += __shfl_down(s, off);
      ss += __shfl_down(ss, off);
    }
    int wv = tid >> 6;
    if ((tid & 63) == 0) { red[wv] = s; red[4 + wv] = ss; }
    __syncthreads();
    if (tid == 0) {
      float s1 = red[0] + red[1] + red[2] + red[3];
      float s2 = red[4] + red[5] + red[6] + red[7];
      float mu = s1 * (1.0f / D_);
      red[0] = mu;
      red[1] = s2 * (1.0f / D_) - mu * mu;
    }
    __syncthreads();
    float mu = red[0];
    float rstd = rsqrtf(red[1] + 1e-5f);
    int ci = tid * 4;
    ushort4 o;
    o.x = f2bf((v.x - mu) * rstd * ln1_g[ci + 0] + ln1_b[ci + 0]);
    o.y = f2bf((v.y - mu) * rstd * ln1_g[ci + 1] + ln1_b[ci + 1]);
    o.z = f2bf((v.z - mu) * rstd * ln1_g[ci + 2] + ln1_b[ci + 2]);
    o.w = f2bf((v.w - mu) * rstd * ln1_g[ci + 3] + ln1_b[ci + 3]);
    *(ushort4*)&hbuf[base] = o;
  }
}

// ---- LayerNorm (optional bf16 residual addin + bf16 x2 passthrough) --------
__global__ __launch_bounds__(256) void ln_kernel(const float* __restrict__ xin,
                                                 const u16* __restrict__ addin,
                                                 const float* __restrict__ gam,
                                                 const float* __restrict__ bet,
                                                 u16* __restrict__ hout,
                                                 u16* __restrict__ x2out) {
  int row = blockIdx.x, tid = threadIdx.x;
  size_t base = (size_t)row * D_ + tid * 4;
  float4 v = *(const float4*)&xin[base];
  if (addin) {
    ushort4 a = *(const ushort4*)&addin[base];
    v.x += bf2f(a.x); v.y += bf2f(a.y); v.z += bf2f(a.z); v.w += bf2f(a.w);
  }
  if (x2out) {
    ushort4 xo;
    xo.x = f2bf(v.x); xo.y = f2bf(v.y); xo.z = f2bf(v.z); xo.w = f2bf(v.w);
    *(ushort4*)&x2out[base] = xo;
  }
  float s = v.x + v.y + v.z + v.w;
  float ss = v.x * v.x + v.y * v.y + v.z * v.z + v.w * v.w;
#pragma unroll
  for (int off = 32; off > 0; off >>= 1) {
    s += __shfl_down(s, off);
    ss += __shfl_down(ss, off);
  }
  __shared__ float red[8];
  int wv = tid >> 6;
  if ((tid & 63) == 0) { red[wv] = s; red[4 + wv] = ss; }
  __syncthreads();
  if (tid == 0) {
    float s1 = red[0] + red[1] + red[2] + red[3];
    float s2 = red[4] + red[5] + red[6] + red[7];
    float mu = s1 * (1.0f / D_);
    red[0] = mu;
    red[1] = s2 * (1.0f / D_) - mu * mu;
  }
  __syncthreads();
  float mu = red[0];
  float rstd = rsqrtf(red[1] + 1e-5f);
  int ci = tid * 4;
  ushort4 o;
  o.x = f2bf((v.x - mu) * rstd * gam[ci + 0] + bet[ci + 0]);
  o.y = f2bf((v.y - mu) * rstd * gam[ci + 1] + bet[ci + 1]);
  o.z = f2bf((v.z - mu) * rstd * gam[ci + 2] + bet[ci + 2]);
  o.w = f2bf((v.w - mu) * rstd * gam[ci + 3] + bet[ci + 3]);
  *(ushort4*)&hout[base] = o;
}

// ---- NT GEMM (128x128, 2-phase dbuf): used for the fused QKV projection ---
// T1: XCD-aware block swizzle (nwg = 20*32 = 640, %8==0 -> bijective).
template <int MODE>
__global__ __launch_bounds__(256) void gemm_nt(const u16* __restrict__ A,
                                               const u16* __restrict__ Bt,
                                               int K, int lda, int ldb,
                                               const float* __restrict__ bias,
                                               const float* __restrict__ res,
                                               void* __restrict__ Cout,
                                               void* __restrict__ Cout2, int ldc) {
  __shared__ __align__(16) u16 As0[128 * 32];
  __shared__ __align__(16) u16 Bs0[128 * 32];
  __shared__ __align__(16) u16 As1[128 * 32];
  __shared__ __align__(16) u16 Bs1[128 * 32];
  int tid = threadIdx.x;
  int lane = tid & 63, wid = tid >> 6;
  int wm = wid >> 1, wn = wid & 1;
  int bid = blockIdx.x + gridDim.x * blockIdx.y;
  int nwg = gridDim.x * gridDim.y;
  int swz = (bid & 7) * (nwg >> 3) + (bid >> 3);
  int tbx = swz % gridDim.x, tby = swz / gridDim.x;
  int row0 = tby * 128, col0 = tbx * 128;
  int l15 = lane & 15, g = lane >> 4;
  int srow = lane >> 2, scol = (lane & 3) * 8;
  f32x4 acc[4][4] = {};
  const u16* Ap = A + (size_t)row0 * lda;
  const u16* Bp = Bt + (size_t)col0 * ldb;

  auto STAGE = [&](u16* AS, u16* BS, int kk) {
#pragma unroll
    for (int i = 0; i < 2; ++i) {
      int c = wid * 2 + i;
      gload_lds16(Ap + (size_t)(c * 16 + srow) * lda + kk + scol, &AS[c * 512]);
      gload_lds16(Bp + (size_t)(c * 16 + srow) * ldb + kk + scol, &BS[c * 512]);
    }
  };
  auto COMPUTE = [&](const u16* AS, const u16* BS) {
    bf16x8 af[4], bfr[4];
#pragma unroll
    for (int t = 0; t < 4; ++t) {
      af[t] = *(const bf16x8*)&AS[(wm * 64 + t * 16 + l15) * 32 + g * 8];
      bfr[t] = *(const bf16x8*)&BS[(wn * 64 + t * 16 + l15) * 32 + g * 8];
    }
#pragma unroll
    for (int mt = 0; mt < 4; ++mt)
#pragma unroll
      for (int nt = 0; nt < 4; ++nt)
        acc[mt][nt] = __builtin_amdgcn_mfma_f32_16x16x32_bf16(af[mt], bfr[nt],
                                                              acc[mt][nt], 0, 0, 0);
  };

  STAGE(As0, Bs0, 0);
  __syncthreads();
  for (int k0 = 0; k0 < K; k0 += 64) {
    if (k0 + 32 < K) STAGE(As1, Bs1, k0 + 32);
    COMPUTE(As0, Bs0);
    __syncthreads();
    if (k0 + 64 < K) STAGE(As0, Bs0, k0 + 64);
    COMPUTE(As1, Bs1);
    __syncthreads();
  }

#pragma unroll
  for (int mt = 0; mt < 4; ++mt) {
#pragma unroll
    for (int nt = 0; nt < 4; ++nt) {
      int cc = col0 + wn * 64 + nt * 16 + l15;
      float bv = bias ? bias[cc] : 0.0f;
#pragma unroll
      for (int j = 0; j < 4; ++j) {
        int rr = row0 + wm * 64 + mt * 16 + g * 4 + j;
        float v = acc[mt][nt][j] + bv;
        if (MODE == 1) v = gelu_f(v);
        if (MODE == 2) {
          ((float*)Cout)[(size_t)rr * ldc + cc] = v + res[(size_t)rr * ldc + cc];
        } else {
          ((u16*)Cout)[(size_t)rr * ldc + cc] = f2bf(v);
        }
      }
    }
  }
  (void)Cout2;
}

// ---- gemm8 (R7 schedule): 256x256, BK=64, 2-slot dbuf, stage interleaved ---
// MODE 1: bf16 gelu(v+bias) -> Cb. MODE 4: split-K, all z -> bf16 partials.
template <int MODE>
__global__ __launch_bounds__(512, 2) void gemm8(
    const u16* __restrict__ A, const u16* __restrict__ Bt,
    int lda, int ldb, int nk,
    const float* __restrict__ bias,
    u16* __restrict__ Cb,
    u16* __restrict__ P0, u16* __restrict__ P1,
    u16* __restrict__ P2, u16* __restrict__ P3,
    int ldc) {
  extern __shared__ __align__(16) char smem[];
  int tid = threadIdx.x;
  int lane = tid & 63, wid = tid >> 6;
  int wm = wid >> 2, wn = wid & 3;
  int l15 = lane & 15, g = lane >> 4;
  int bid = blockIdx.x + gridDim.x * blockIdx.y;
  int nwg = gridDim.x * gridDim.y;
  int swz = (bid & 7) * (nwg >> 3) + (bid >> 3);
  int tbx = swz % gridDim.x, tby = swz / gridDim.x;
  int row0 = tby * 256, col0 = tbx * 256;
  int koff = (MODE == 4) ? blockIdx.z * (nk * 64) : 0;
  const u16* Ap = A + (size_t)row0 * lda + koff;
  const u16* Bp = Bt + (size_t)col0 * ldb + koff;
  int trow = tid >> 3;
  int sbyte = ((tid & 7) * 16) ^ ((trow & 7) << 4);
  int xr = (l15 & 7) << 4;

  f32x4 acc[8][4] = {};

  auto STAGE_A = [&](int buf, int kt) {
#pragma unroll
    for (int l = 0; l < 4; ++l)
      gload_lds16((const char*)(Ap + (size_t)(l * 64 + trow) * lda + kt) + sbyte,
                  smem + buf * 65536 + (l * 64 + wid * 8) * 128);
  };
  auto STAGE_B = [&](int buf, int kt) {
#pragma unroll
    for (int l = 0; l < 4; ++l)
      gload_lds16((const char*)(Bp + (size_t)(l * 64 + trow) * ldb + kt) + sbyte,
                  smem + buf * 65536 + 32768 + (l * 64 + wid * 8) * 128);
  };

  STAGE_A(0, 0);
  STAGE_B(0, 0);
  asm volatile("s_waitcnt vmcnt(0)" ::: "memory");
  __builtin_amdgcn_sched_barrier(0);
  __builtin_amdgcn_s_barrier();

  int cur = 0;
  for (int it = 0; it < nk; ++it) {
    const char* Ab = smem + cur * 65536 + (size_t)(wm * 128 + l15) * 128;
    const char* Bb = smem + cur * 65536 + 32768 + (size_t)(wn * 64 + l15) * 128;
    bool nxt = (it + 1 < nk);
#pragma unroll
    for (int kk = 0; kk < 2; ++kk) {
      int kq = (kk * 64 + g * 16) ^ xr;
      bf16x8 bfr[4], af[8];
#pragma unroll
      for (int nt = 0; nt < 4; ++nt)
        bfr[nt] = *(const bf16x8*)(Bb + nt * 2048 + kq);
#pragma unroll
      for (int mt = 0; mt < 8; ++mt)
        af[mt] = *(const bf16x8*)(Ab + mt * 2048 + kq);
      if (nxt) {
        if (kk == 0) STAGE_A(cur ^ 1, (it + 1) * 64);
        else         STAGE_B(cur ^ 1, (it + 1) * 64);
      }
      __builtin_amdgcn_s_setprio(1);
#pragma unroll
      for (int mt = 0; mt < 8; ++mt)
#pragma unroll
        for (int nt = 0; nt < 4; ++nt)
          acc[mt][nt] = __builtin_amdgcn_mfma_f32_16x16x32_bf16(af[mt], bfr[nt],
                                                                acc[mt][nt], 0, 0, 0);
      __builtin_amdgcn_s_setprio(0);
    }
    asm volatile("s_waitcnt vmcnt(0)" ::: "memory");
    __builtin_amdgcn_sched_barrier(0);
    __builtin_amdgcn_s_barrier();
    cur ^= 1;
  }

  u16* pp = Cb;
  if (MODE == 4)
    pp = (blockIdx.z == 0) ? P0
       : (blockIdx.z == 1) ? P1
       : (blockIdx.z == 2) ? P2 : P3;
#pragma unroll
  for (int mt = 0; mt < 8; ++mt) {
#pragma unroll
    for (int nt = 0; nt < 4; ++nt) {
      int cc = col0 + wn * 64 + nt * 16 + l15;
      float bv = (MODE == 1) ? bias[cc] : 0.0f;
#pragma unroll
      for (int j = 0; j < 4; ++j) {
        int rr = row0 + wm * 128 + mt * 16 + g * 4 + j;
        float v = acc[mt][nt][j] + bv;
        if (MODE == 1) {
          pp[(size_t)rr * ldc + cc] = f2bf(gelu_f(v));
        } else {
          pp[(size_t)rr * ldc + cc] = f2bf(v);
        }
      }
    }
  }
}

// ---- split-K reduce: out = p0+p1+p2+p3 (bf16) + b2[col] + x2 (bf16) --------
__global__ __launch_bounds__(256) void reduce2(float* __restrict__ out,
                                               const u16* __restrict__ p0,
                                               const u16* __restrict__ p1,
                                               const u16* __restrict__ p2,
                                               const u16* __restrict__ p3,
                                               const float* __restrict__ b2,
                                               const u16* __restrict__ x2) {
  int i = (blockIdx.x * 256 + threadIdx.x) * 4;
  ushort4 a0 = *(const ushort4*)&p0[i];
  ushort4 a = *(const ushort4*)&p1[i];
  ushort4 b = *(const ushort4*)&p2[i];
  ushort4 c = *(const ushort4*)&p3[i];
  ushort4 r = *(const ushort4*)&x2[i];
  int cix = i & (D_ - 1);
  float4 o;
  o.x = bf2f(a0.x) + bf2f(a.x) + bf2f(b.x) + bf2f(c.x) + b2[cix + 0] + bf2f(r.x);
  o.y = bf2f(a0.y) + bf2f(a.y) + bf2f(b.y) + bf2f(c.y) + b2[cix + 1] + bf2f(r.y);
  o.z = bf2f(a0.z) + bf2f(a.z) + bf2f(b.z) + bf2f(c.z) + b2[cix + 2] + bf2f(r.z);
  o.w = bf2f(a0.w) + bf2f(a.w) + bf2f(b.w) + bf2f(c.w) + b2[cix + 3] + bf2f(r.w);
  *(float4*)&out[i] = o;
}

// ---- low-rank V up-proj -> V^T [b,h][e][t] bf16 ----------------------------
__global__ __launch_bounds__(256) void vu_kernel(const u16* __restrict__ vd,
                                                 const u16* __restrict__ wvu,
                                                 const float* __restrict__ bvu,
                                                 u16* __restrict__ v_t) {
  int t0 = blockIdx.x * 64, h = blockIdx.y, b = blockIdx.z;
  __shared__ u16 vds[64][32];
  __shared__ u16 vt[64][65];
  int tid = threadIdx.x;
  {
    int rr2 = tid >> 2, c8 = (tid & 3) * 8;
    *(bf16x8*)&vds[rr2][c8] =
        *(const bf16x8*)&vd[(size_t)(b * S_ + t0 + rr2) * NQKV + 2048 + h * R_ + c8];
  }
  __syncthreads();
  int e = tid & 63, tg = (tid >> 6) * 16;
  float wcol[32];
#pragma unroll
  for (int r = 0; r < 32; ++r) wcol[r] = bf2f(wvu[((size_t)h * R_ + r) * HD_ + e]);
  float bb = bvu[h * HD_ + e];
  for (int i = 0; i < 16; ++i) {
    int t = tg + i;
    float acc = bb;
#pragma unroll
    for (int r = 0; r < 32; ++r) acc += bf2f(vds[t][r]) * wcol[r];
    vt[t][e] = f2bf(acc);
  }
  __syncthreads();
  for (int idx = tid; idx < 64 * 64; idx += 256) {
    int e2 = idx >> 6, t2 = idx & 63;
    v_t[((size_t)(b * H_ + h) * HD_ + e2) * S_ + t0 + t2] = vt[t2][e2];
  }
}

// ---- attention v4.1 + T13 defer-max: reversed-causal (key t >= query s) ----
// grid (H, B, 16) = 512 blocks (2 blocks/CU, 16 waves/CU). Each block does
// ONE q-tile; z-map t = z<8 ? z : 23-z pairs complementary step counts on
// blocks id/id+256. 8 waves x 16 q; counted-vmcnt 3-buffer ring; bf16 out.
__global__ __launch_bounds__(512, 2) void attn_kernel(const u16* __restrict__ cqkv,
                                                      const u16* __restrict__ v_t,
                                                      u16* __restrict__ o) {
  extern __shared__ __align__(16) u16 kv[];  // 3 bufs x (K 4096 + V 4096) u16
  __shared__ u16 Pl[8][16 * 64];             // per-wave Q then P^T tile
  int tid = threadIdx.x;
  int lane = tid & 63, w = tid >> 6;
  int h = blockIdx.x, b = blockIdx.y;
  int zz = blockIdx.z;
  int tq = (zz < 8) ? zz : 23 - zz;          // q-tile index 0..15
  int r = lane & 15, g = lane >> 4;
  const u16* qp = cqkv + (size_t)(b * S_) * NQKV + h * HD_;
  const u16* kp = cqkv + (size_t)(b * S_) * NQKV + 1024 + h * HD_;
  const u16* vp = v_t + (size_t)(b * H_ + h) * HD_ * S_;
  u16* Pw = Pl[w];

  int srow = w * 8 + (lane >> 3);
  int ssw = ((lane & 7) * 16) ^ (((lane >> 3) & 7) << 4);  // pre-swz byte in row

  int xr = (r & 7) << 4;                // read-side XOR (rows = ..*16 + r)
  int kq0 = ((g * 16) ^ xr) >> 1;       // elem offset, k-group 0
  int kq1 = ((64 + g * 16) ^ xr) >> 1;  // elem offset, k-group 1

  auto STAGE = [&](int buf, int kt) {
    u16* base = kv + buf * 8192;
    gload_lds16((const char*)(kp + (size_t)(kt + srow) * NQKV) + ssw,
                base + w * 512);
    gload_lds16((const char*)(vp + (size_t)srow * S_ + kt) + ssw,
                base + 4096 + w * 512);
  };

  {
    int qb = tq * 128;
    int s0 = qb + w * 16;
    int qrow = s0 + r;

    gload_lds16((const char*)(qp + (size_t)(s0 + (lane >> 3)) * NQKV) + ssw, Pw);
    gload_lds16((const char*)(qp + (size_t)(s0 + 8 + (lane >> 3)) * NQKV) + ssw,
                Pw + 512);
    asm volatile("s_waitcnt vmcnt(0)" ::: "memory");
    __builtin_amdgcn_sched_barrier(0);
    __builtin_amdgcn_s_barrier();
    __builtin_amdgcn_sched_barrier(0);
    bf16x8 aq0 = *(const bf16x8*)&Pw[(r << 6) + kq0];
    bf16x8 aq1 = *(const bf16x8*)&Pw[(r << 6) + kq1];

    f32x4 oa[4] = {};
    float m_ = -1e30f, l_ = 0.0f;

    int nt = (S_ - qb) >> 6;
    STAGE(0, qb);
    STAGE(1, qb + 64);

    for (int it = 0; it < nt; ++it) {
      int kt = qb + it * 64;
      if (it + 1 < nt) {
        asm volatile("s_waitcnt vmcnt(2)" ::: "memory");
      } else {
        asm volatile("s_waitcnt vmcnt(0)" ::: "memory");
      }
      __builtin_amdgcn_sched_barrier(0);
      __builtin_amdgcn_s_barrier();
      __builtin_amdgcn_sched_barrier(0);
      if (it + 2 < nt) STAGE((it + 2) % 3, qb + (it + 2) * 64);

      if (kt + 64 > s0) {
        const u16* Kb = kv + (it % 3) * 8192;
        const u16* Vb = Kb + 4096;

        f32x4 sc[4] = {};
#pragma unroll
        for (int blk = 0; blk < 4; ++blk) {
          bf16x8 a0 = *(const bf16x8*)&Kb[((blk * 16 + r) << 6) + kq0];
          bf16x8 a1 = *(const bf16x8*)&Kb[((blk * 16 + r) << 6) + kq1];
          sc[blk] = __builtin_amdgcn_mfma_f32_16x16x32_bf16(a0, aq0, sc[blk], 0, 0, 0);
          sc[blk] = __builtin_amdgcn_mfma_f32_16x16x32_bf16(a1, aq1, sc[blk], 0, 0, 0);
        }

        float p[16];
        if ((qrow & ~63) == kt) {
#pragma unroll
          for (int blk = 0; blk < 4; ++blk)
#pragma unroll
            for (int j = 0; j < 4; ++j) {
              int kk = kt + blk * 16 + g * 4 + j;
              p[blk * 4 + j] = (kk < qrow) ? -1e30f : sc[blk][j];
            }
        } else {
#pragma unroll
          for (int blk = 0; blk < 4; ++blk)
#pragma unroll
            for (int j = 0; j < 4; ++j) p[blk * 4 + j] = sc[blk][j];
        }
        float mx = p[0];
#pragma unroll
        for (int i = 1; i < 16; ++i) mx = fmaxf(mx, p[i]);
        mx = fmaxf(mx, __shfl_xor(mx, 16));
        mx = fmaxf(mx, __shfl_xor(mx, 32));
        // T13 defer-max: only rescale when max grew by > 8 (exp2 domain)
        if (!__all(mx <= m_ + 8.0f)) {
          float mn = fmaxf(m_, mx);
          float scl = __builtin_amdgcn_exp2f(m_ - mn);
          m_ = mn;
          l_ *= scl;
#pragma unroll
          for (int et = 0; et < 4; ++et) oa[et] *= scl;
        }
        float sm = 0.0f;
#pragma unroll
        for (int i = 0; i < 16; ++i) {
          p[i] = __builtin_amdgcn_exp2f(p[i] - m_);
          sm += p[i];
        }
        sm += __shfl_xor(sm, 16);
        sm += __shfl_xor(sm, 32);
        l_ += sm;

#pragma unroll
        for (int blk = 0; blk < 4; ++blk) {
          uint2 pk;
          pk.x = pk_bf16(p[blk * 4 + 0], p[blk * 4 + 1]);
          pk.y = pk_bf16(p[blk * 4 + 2], p[blk * 4 + 3]);
          *(uint2*)&Pw[(r << 6) + ((((blk << 5) + (g << 3)) ^ xr) >> 1)] = pk;
        }
        asm volatile("s_waitcnt lgkmcnt(0)" ::: "memory");
        __builtin_amdgcn_sched_barrier(0);
        bf16x8 pb0 = *(const bf16x8*)&Pw[(r << 6) + kq0];
        bf16x8 pb1 = *(const bf16x8*)&Pw[(r << 6) + kq1];
#pragma unroll
        for (int et = 0; et < 4; ++et) {
          bf16x8 v0 = *(const bf16x8*)&Vb[((et * 16 + r) << 6) + kq0];
          bf16x8 v1 = *(const bf16x8*)&Vb[((et * 16 + r) << 6) + kq1];
          oa[et] = __builtin_amdgcn_mfma_f32_16x16x32_bf16(v0, pb0, oa[et], 0, 0, 0);
          oa[et] = __builtin_amdgcn_mfma_f32_16x16x32_bf16(v1, pb1, oa[et], 0, 0, 0);
        }
      }
    }

    float inv = 1.0f / l_;
#pragma unroll
    for (int et = 0; et < 4; ++et)
#pragma unroll
      for (int j = 0; j < 4; ++j)
        o[(size_t)(b * S_ + s0 + r) * D_ + h * HD_ + et * 16 + g * 4 + j] =
            f2bf(oa[et][j] * inv);
  }
}

// one-time (dlopen) LDS-limit raise for dynamic-shared kernels
namespace {
struct GemmAttrInit {
  GemmAttrInit() {
    hipFuncSetAttribute((const void*)gemm8<1>,
                        hipFuncAttributeMaxDynamicSharedMemorySize, 131072);
    hipFuncSetAttribute((const void*)gemm8<4>,
                        hipFuncAttributeMaxDynamicSharedMemorySize, 131072);
    hipFuncSetAttribute((const void*)attn_kernel,
                        hipFuncAttributeMaxDynamicSharedMemorySize, 49152);
  }
};
GemmAttrInit _gemm_attr_init;
}  // namespace

extern "C" void kernel_launch(void* const* d_in, const int* in_sizes, int n_in,
                              void* d_out, int out_size, void* d_ws, size_t ws_size,
                              hipStream_t stream) {
  const float* x = (const float*)d_in[0];
  const float* ln1_g = (const float*)d_in[1];
  const float* ln1_b = (const float*)d_in[2];
  const float* Wq = (const float*)d_in[3];
  const float* bq = (const float*)d_in[4];
  const float* Wk = (const float*)d_in[5];
  const float* bk = (const float*)d_in[6];
  const float* Wvd = (const float*)d_in[7];
  const float* bvd = (const float*)d_in[8];
  const float* Wvu = (const float*)d_in[9];
  const float* bvu = (const float*)d_in[10];
  const float* ln2_g = (const float*)d_in[11];
  const float* ln2_b = (const float*)d_in[12];
  const float* W1 = (const float*)d_in[13];
  const float* b1 = (const float*)d_in[14];
  const float* W2 = (const float*)d_in[15];
  const float* b2 = (const float*)d_in[16];
  float* out = (float*)d_out;
  (void)in_sizes; (void)n_in; (void)out_size; (void)ws_size;

  char* ws = (char*)d_ws;
  const size_t MB = 1024 * 1024;
  const size_t KB = 1024;
  u16* wqkvT = (u16*)(ws + 0);                    // [2560x1024] bf16, 5 MB
  u16* wvuB = (u16*)(ws + 5 * MB);                // 64 KB
  float* bqkv = (float*)(ws + 5 * MB + 64 * KB);  // 10 KB
  u16* w1T = (u16*)(ws + 5 * MB + 384 * KB);      // 8 MB -> 13.375
  u16* w2T = (u16*)(ws + 13 * MB + 384 * KB);     // 8 MB -> 21.375
  u16* hbuf = (u16*)(ws + 21 * MB + 384 * KB);    // 8 MB -> 29.375
  u16* cqkv = (u16*)(ws + 29 * MB + 384 * KB);    // 20 MB -> 49.375
  u16* vT = (u16*)(ws + 49 * MB + 384 * KB);      // 8 MB -> 57.375
  u16* ob16 = (u16*)(ws + 57 * MB + 384 * KB);    // 8 MB (bf16) -> 65.375
  u16* p3 = (u16*)(ws + 65 * MB + 384 * KB);      // 8 MB -> 73.375 (outside ubuf)
  u16* x2 = (u16*)(ws + 73 * MB + 384 * KB);      // 8 MB (bf16) -> 81.375
  u16* p0 = (u16*)(ws + 81 * MB + 384 * KB);      // 8 MB -> 89.375
  // lifetime-disjoint reuses:
  u16* ubuf = cqkv;            // 32 MB (cqkv+vT+ob16[0:4MB]), dead by FFN1
  u16* p1 = (u16*)(ws + 0);    // 8 MB over wqkvT+..., dead by FFN2
  u16* p2 = (u16*)hbuf;        // 8 MB, hbuf dead after FFN1

  dim3 blk(256);
  // mega-prologue: weight prep + LN1 in ONE launch (15402 blocks)
  prologue<<<dim3(15402), blk, 0, stream>>>(Wq, Wk, Wvd, wqkvT, Wvu, wvuB,
                                            bq, bk, bvd, bqkv, W1, W2, w1T, w2T,
                                            x, ln1_g, ln1_b, hbuf);
  // fused QKV projection (2-phase 128² — 640 blocks, 2.5/CU, T1-swizzled)
  gemm_nt<0><<<dim3(20, 32), blk, 0, stream>>>(hbuf, wqkvT, 1024, 1024, 1024, bqkv,
                                               (const float*)nullptr, (void*)cqkv,
                                               (void*)nullptr, NQKV);
  vu_kernel<<<dim3(S_ / 64, H_, B_), blk, 0, stream>>>(cqkv, wvuB, bvu, vT);
  // attention v4.1: grid (H, B, 16) = 512 blocks (2/CU), 48KB dynamic LDS
  attn_kernel<<<dim3(H_, B_, 16), dim3(512), 49152, stream>>>(cqkv, vT, ob16);
  ln_kernel<<<dim3(M_), blk, 0, stream>>>(x, ob16, ln2_g, ln2_b, hbuf, x2);
  // FFN1: 256² R7 pipeline, grid 16x16 = 1 block/CU, T1-swizzled
  gemm8<1><<<dim3(16, 16, 1), dim3(512), 131072, stream>>>(
      hbuf, w1T, 1024, 1024, 16, b1, ubuf,
      (u16*)nullptr, (u16*)nullptr, (u16*)nullptr, (u16*)nullptr, 4096);
  // FFN2: split-K=4, grid 4x16x4, T1-swizzled per z; all z -> bf16 partials
  gemm8<4><<<dim3(4, 16, 4), dim3(512), 131072, stream>>>(
      ubuf, w2T, 4096, 4096, 16, (const float*)nullptr, (u16*)nullptr,
      p0, p1, p2, p3, 1024);
  // out = p0+p1+p2+p3 + b2 + x2
  reduce2<<<dim3(M_ * D_ / 1024), blk, 0, stream>>>(out, p0, p1, p2, p3, b2, x2);
}